// Round 1
// baseline (3225.588 us; speedup 1.0000x reference)
//
#include <hip/hip_runtime.h>
#include <hip/hip_bf16.h>

// ---------------- problem constants ----------------
#define SQ   64        // seq len
#define NN   1000      // nodes per graph
#define NT   64000     // total nodes
#define FF   64        // node feature dim
#define EE   128       // emb dim
#define EG   512000    // graph edges (no self loops)
#define ET   576000    // edges + self loops

// ---------------- workspace layout (bytes) ----------------
#define WS_XA      0ull          // 32,768,000  float[NT*128]  x ping (mu lives here)
#define WS_XB      33000000ull   // 32,768,000  float[NT*128]  x pong (xl / la)
#define WS_ROWPTR  66000000ull   // 256,004     int[NT+1]
#define WS_CURSOR  66300000ull   // 256,000     int[NT]   (also used as deg)
#define WS_EIDS    66600000ull   // 2,304,000   int[ET]
#define WS_INCL    69000000ull   // 256,000     int[NT]
#define WS_BSUM    69300000ull   // 1,024       int[250]
#define WS_BOFF    69302048ull   // 1,024       int[250]
#define WS_MODE    69304096ull   // 4           int
#define WS_LOGIT   70000000ull   // 4,608,000   float[ET*2]
#define WS_WT2     75000000ull   // 524,288     float2[128*512]
#define WS_AS      75600000ull   // 256         float[64]
#define WS_LOGIT2  75700000ull   // 256,000     float[NT]
// total ~76 MB

// ---------------- helpers ----------------
__device__ __forceinline__ float rdlane(float v, int l) {
    return __int_as_float(__builtin_amdgcn_readlane(__float_as_int(v), l));
}
__device__ __forceinline__ float sigm(float x) { return 1.0f / (1.0f + __expf(-x)); }
__device__ __forceinline__ float tanh_f(float x) {
    x = fminf(fmaxf(x, -30.0f), 30.0f);
    float e = __expf(2.0f * x);
    return (e - 1.0f) / (e + 1.0f);
}

// ---------------- reachable dtype detection ----------------
// bool bytes: nonzero at byte%4==0 AND byte%4==3 positions (80% ones)
// int32 0/1 : nonzero only at byte%4==0
// float 1.0 : nonzero only at byte%4==3 (0x3F800000 -> low bytes 0)
__global__ void detect_mode_k(const unsigned char* __restrict__ p, int* __restrict__ mode) {
    __shared__ int f0, f3;
    const int t = threadIdx.x;
    if (t == 0) { f0 = 0; f3 = 0; }
    __syncthreads();
    int l0 = 0, l3 = 0;
    for (int i = t; i < 16000; i += 256) {
        if (p[4 * i])     l0 = 1;
        if (p[4 * i + 3]) l3 = 1;
    }
    if (l0) atomicOr(&f0, 1);
    if (l3) atomicOr(&f3, 1);
    __syncthreads();
    if (t == 0) {
        int m;
        if (f0 && f3)      m = 1;  // bool bytes
        else if (f0)       m = 0;  // int32
        else               m = 2;  // float32
        *mode = m;
    }
}

// ---------------- CSR construction (done once; reused by all 5 layers) ----------------
__global__ void zero_ints_k(int* __restrict__ p, int n) {
    int i = blockIdx.x * 256 + threadIdx.x;
    if (i < n) p[i] = 0;
}
__global__ void hist_k(const int* __restrict__ ei, int* __restrict__ deg) {
    int e = blockIdx.x * 256 + threadIdx.x;
    if (e < ET) {
        int d = (e < EG) ? ei[EG + e] : (e - EG);
        atomicAdd(deg + d, 1);
    }
}
__global__ void scan1_k(const int* __restrict__ deg, int* __restrict__ incl, int* __restrict__ bsum) {
    __shared__ int sh[256];
    const int t = threadIdx.x;
    const int i = blockIdx.x * 256 + t;
    sh[t] = deg[i];
    __syncthreads();
    for (int o = 1; o < 256; o <<= 1) {
        int add = (t >= o) ? sh[t - o] : 0;
        __syncthreads();
        sh[t] += add;
        __syncthreads();
    }
    incl[i] = sh[t];
    if (t == 255) bsum[blockIdx.x] = sh[255];
}
__global__ void scan2_k(const int* __restrict__ bsum, int* __restrict__ boff) {
    __shared__ int sh[256];
    const int t = threadIdx.x;
    int v = (t < 250) ? bsum[t] : 0;
    sh[t] = v;
    __syncthreads();
    for (int o = 1; o < 256; o <<= 1) {
        int add = (t >= o) ? sh[t - o] : 0;
        __syncthreads();
        sh[t] += add;
        __syncthreads();
    }
    if (t < 250) boff[t] = sh[t] - v;   // exclusive
}
__global__ void scan3_k(const int* __restrict__ incl, const int* __restrict__ boff,
                        int* __restrict__ rowptr, int* __restrict__ cursor_deg) {
    const int i = blockIdx.x * 256 + threadIdx.x;
    int total = incl[i] + boff[blockIdx.x];
    int excl  = total - cursor_deg[i];    // cursor_deg currently holds deg
    rowptr[i] = excl;
    cursor_deg[i] = excl;                 // becomes fill cursor
    if (i == NT - 1) rowptr[NT] = total;
}
__global__ void fill_k(const int* __restrict__ ei, int* __restrict__ cursor, int* __restrict__ eids) {
    int e = blockIdx.x * 256 + threadIdx.x;
    if (e < ET) {
        int d = (e < EG) ? ei[EG + e] : (e - EG);
        int p = atomicAdd(cursor + d, 1);
        eids[p] = e;
    }
}

// ---------------- fp32 GEMM: out[M x 128] = x[M x K] @ W[K x 128] + b ----------------
// grid = M/64 blocks of 256. W chunked 64 k's at a time into LDS (32KB) + x tile (16.9KB).
template <int K>
__global__ __launch_bounds__(256) void gemm_xw(
    const float* __restrict__ x, const float* __restrict__ W,
    const float* __restrict__ b, float* __restrict__ out)
{
    __shared__ float Wsh[64 * 128];
    __shared__ float xsh[64 * 66];
    const int t = threadIdx.x;
    const int row0 = blockIdx.x * 64;
    const int cg = t & 31;   // cols cg*4 .. +3
    const int rg = t >> 5;   // rows rg*8 .. +7
    float4 acc[8];
#pragma unroll
    for (int r = 0; r < 8; r++) acc[r] = make_float4(0.f, 0.f, 0.f, 0.f);

    for (int k0 = 0; k0 < K; k0 += 64) {
        for (int i = t * 4; i < 64 * 128; i += 1024)
            *(float4*)(Wsh + i) = *(const float4*)(W + (size_t)k0 * 128 + i);
        for (int i = t * 4; i < 64 * 64; i += 1024) {
            int r = i >> 6, k = i & 63;
            float4 v = *(const float4*)(x + (size_t)(row0 + r) * K + k0 + k);
            float* d = xsh + r * 66 + k;
            d[0] = v.x; d[1] = v.y; d[2] = v.z; d[3] = v.w;
        }
        __syncthreads();
        for (int k = 0; k < 64; k += 2) {
            float4 w0 = *(const float4*)(Wsh + k * 128 + cg * 4);
            float4 w1 = *(const float4*)(Wsh + (k + 1) * 128 + cg * 4);
#pragma unroll
            for (int r = 0; r < 8; r++) {
                float2 xv = *(const float2*)(xsh + (rg * 8 + r) * 66 + k);
                acc[r].x += xv.x * w0.x + xv.y * w1.x;
                acc[r].y += xv.x * w0.y + xv.y * w1.y;
                acc[r].z += xv.x * w0.z + xv.y * w1.z;
                acc[r].w += xv.x * w0.w + xv.y * w1.w;
            }
        }
        __syncthreads();
    }
    float4 bv = *(const float4*)(b + cg * 4);
#pragma unroll
    for (int r = 0; r < 8; r++) {
        float4 o;
        o.x = acc[r].x + bv.x; o.y = acc[r].y + bv.y;
        o.z = acc[r].z + bv.z; o.w = acc[r].w + bv.w;
        *(float4*)(out + (size_t)(row0 + rg * 8 + r) * 128 + cg * 4) = o;
    }
}

// ---------------- GATv2 edge logits ----------------
// one wave per edge (grid-stride). lanes 0..31 -> head0 (ch 0..63), 32..63 -> head1.
__global__ __launch_bounds__(256) void edge_logit_k(
    const float* __restrict__ xl, const int* __restrict__ ei,
    const float* __restrict__ att, float* __restrict__ logit)
{
    const int lane = threadIdx.x & 63;
    const int wid  = blockIdx.x * 4 + (threadIdx.x >> 6);
    const int nw   = gridDim.x * 4;
    const float2 a = *(const float2*)(att + lane * 2);
    for (int e = wid; e < ET; e += nw) {
        int s_, d_;
        if (e < EG) { s_ = ei[e]; d_ = ei[EG + e]; }
        else        { s_ = e - EG; d_ = s_; }
        float2 xs = *(const float2*)(xl + (size_t)s_ * 128 + lane * 2);
        float2 xd = *(const float2*)(xl + (size_t)d_ * 128 + lane * 2);
        float u = xs.x + xd.x, v = xs.y + xd.y;
        u = (u > 0.f) ? u : 0.2f * u;
        v = (v > 0.f) ? v : 0.2f * v;
        float sum = u * a.x + v * a.y;
        sum += __shfl_down(sum, 16, 32);
        sum += __shfl_down(sum, 8, 32);
        sum += __shfl_down(sum, 4, 32);
        sum += __shfl_down(sum, 2, 32);
        sum += __shfl_down(sum, 1, 32);
        if ((lane & 31) == 0) logit[2 * e + (lane >> 5)] = sum;
    }
}

// ---------------- GATv2 aggregation (gather via CSR) ----------------
// one wave per dst node. lane holds channels 2*lane, 2*lane+1.
__global__ __launch_bounds__(256) void gat_aggr_k(
    const float* __restrict__ xl, const float* __restrict__ logit,
    const int* __restrict__ ei, const int* __restrict__ rowptr,
    const int* __restrict__ eids, const float* __restrict__ bias,
    float* __restrict__ out, const int do_relu)
{
    const int lane = threadIdx.x & 63;
    const int n = blockIdx.x * 4 + (threadIdx.x >> 6);
    const int beg = rowptr[n], end = rowptr[n + 1];
    float m0 = -1e30f, m1 = -1e30f;
    for (int i = beg; i < end; i++) {
        float2 lv = *(const float2*)(logit + 2 * (size_t)eids[i]);
        m0 = fmaxf(m0, lv.x); m1 = fmaxf(m1, lv.y);
    }
    float d0 = 0.f, d1 = 0.f, ax = 0.f, ay = 0.f;
    const bool h1 = lane >= 32;
    for (int i = beg; i < end; i++) {
        int e = eids[i];
        float2 lv = *(const float2*)(logit + 2 * (size_t)e);
        float e0 = __expf(lv.x - m0), e1 = __expf(lv.y - m1);
        int s_ = (e < EG) ? ei[e] : (e - EG);
        float2 xv = *(const float2*)(xl + (size_t)s_ * 128 + lane * 2);
        float w = h1 ? e1 : e0;
        ax += w * xv.x; ay += w * xv.y;
        d0 += e0; d1 += e1;
    }
    float ds = h1 ? d1 : d0;
    float2 bv = *(const float2*)(bias + lane * 2);
    float ox = ax / ds + bv.x, oy = ay / ds + bv.y;
    if (do_relu) { ox = fmaxf(ox, 0.f); oy = fmaxf(oy, 0.f); }
    *(float2*)(out + (size_t)n * 128 + lane * 2) = make_float2(ox, oy);
}

// ---------------- LSTM: transpose weights to [k][j] interleaved (ih,hh) ----------------
__global__ void build_wt2_k(const float* __restrict__ Wih, const float* __restrict__ Whh,
                            float2* __restrict__ Wt2) {
    int id = blockIdx.x * 256 + threadIdx.x;    // 128*512 ids
    if (id < 128 * 512) {
        int k = id >> 9, j = id & 511;
        Wt2[id] = make_float2(Wih[(size_t)j * 128 + k], Whh[(size_t)j * 128 + k]);
    }
}

// ---------------- persistent LSTM scan ----------------
// 125 blocks x 256 threads; block owns 8 nodes (independent chains -> no grid sync).
// thread t computes gate rows j=t and j=t+256; x/h broadcast via v_readlane.
__global__ __launch_bounds__(256) void lstm_k(
    float* __restrict__ mu, const float2* __restrict__ Wt2,
    const float* __restrict__ bih, const float* __restrict__ bhh,
    const float* __restrict__ h0, const float* __restrict__ c0,
    float* __restrict__ hT, float* __restrict__ cT)
{
    const int t = threadIdx.x, lane = t & 63;
    const int n0 = blockIdx.x * 8;
    __shared__ float hsh[8][128];
    __shared__ float gsh[8][512];
    const int j1 = t, j2 = t + 256;
    const float b1 = bih[j1] + bhh[j1];
    const float b2 = bih[j2] + bhh[j2];
    float creg[4];
#pragma unroll
    for (int q = 0; q < 4; q++) {
        int id = t + 256 * q;
        creg[q] = c0[(size_t)(n0 + (id >> 7)) * 128 + (id & 127)];
    }
    for (int i = t; i < 1024; i += 256)
        hsh[i >> 7][i & 127] = h0[(size_t)(n0 + (i >> 7)) * 128 + (i & 127)];
    __syncthreads();

    for (int s = 0; s < SQ; s++) {
        float* xrow = mu + ((size_t)s * NN + n0) * 128;
        float2 xr[8], hr[8];
#pragma unroll
        for (int n = 0; n < 8; n++) {
            xr[n] = *(const float2*)(xrow + n * 128 + lane * 2);
            hr[n] = *(const float2*)(&hsh[n][lane * 2]);
        }
        float acc1[8], acc2[8];
#pragma unroll
        for (int n = 0; n < 8; n++) { acc1[n] = b1; acc2[n] = b2; }

#pragma unroll 2
        for (int kp = 0; kp < 64; kp++) {
            float2 wa1 = Wt2[(2 * kp) * 512 + j1];
            float2 wb1 = Wt2[(2 * kp + 1) * 512 + j1];
            float2 wa2 = Wt2[(2 * kp) * 512 + j2];
            float2 wb2 = Wt2[(2 * kp + 1) * 512 + j2];
#pragma unroll
            for (int n = 0; n < 8; n++) {
                float sx0 = rdlane(xr[n].x, kp), sx1 = rdlane(xr[n].y, kp);
                float sh0 = rdlane(hr[n].x, kp), sh1 = rdlane(hr[n].y, kp);
                acc1[n] += sx0 * wa1.x + sh0 * wa1.y + sx1 * wb1.x + sh1 * wb1.y;
                acc2[n] += sx0 * wa2.x + sh0 * wa2.y + sx1 * wb2.x + sh1 * wb2.y;
            }
        }
#pragma unroll
        for (int n = 0; n < 8; n++) { gsh[n][j1] = acc1[n]; gsh[n][j2] = acc2[n]; }
        __syncthreads();
#pragma unroll
        for (int q = 0; q < 4; q++) {
            int id = t + 256 * q;
            int n = id >> 7, e = id & 127;
            float iv = gsh[n][e], fv = gsh[n][128 + e];
            float gv = gsh[n][256 + e], ov = gsh[n][384 + e];
            float c = sigm(fv) * creg[q] + sigm(iv) * tanh_f(gv);
            float h = sigm(ov) * tanh_f(c);
            creg[q] = c;
            hsh[n][e] = h;
            xrow[n * 128 + e] = h;        // mu <- h_t (scan output)
            if (s == SQ - 1) {
                hT[(size_t)(n0 + n) * 128 + e] = h;
                cT[(size_t)(n0 + n) * 128 + e] = c;
            }
        }
        __syncthreads();
    }
}

// ---------------- head: meanpool -> gs -> A[s] = sum_j relu(gs)*w5[j] ----------------
__global__ __launch_bounds__(256) void meanpool_gs_k(
    const float* __restrict__ mu, const float* __restrict__ W6,
    const float* __restrict__ b6, const float* __restrict__ w5,
    float* __restrict__ A)
{
    const int s = blockIdx.x, t = threadIdx.x;
    const int ch = t & 127, half = t >> 7;
    __shared__ float mp[128];
    __shared__ float red[256];
    float acc = 0.f;
    for (int n = half * 500; n < (half + 1) * 500; n++)
        acc += mu[((size_t)s * NN + n) * 128 + ch];
    red[t] = acc;
    __syncthreads();
    if (t < 128) mp[t] = (red[t] + red[t + 128]) * 0.001f;
    __syncthreads();
    float g = 0.f;
    if (t < 128) {
        g = b6[t];
        for (int k = 0; k < 128; k++) g += mp[k] * W6[(size_t)k * 128 + t];
        g = fmaxf(g, 0.f) * w5[t];
    }
    red[t] = g;
    __syncthreads();
    for (int o = 128; o > 0; o >>= 1) {
        if (t < o) red[t] += red[t + o];
        __syncthreads();
    }
    if (t == 0) A[s] = red[0];
}

// ---------------- head: logit2[row] = A[s] + b5 + sum_j relu(la[row][j]) * w5[128+j] ----------------
__global__ __launch_bounds__(256) void rowdot_k(
    const float* __restrict__ la, const float* __restrict__ w5,
    const float* __restrict__ b5, const float* __restrict__ A,
    float* __restrict__ out)
{
    const int lane = threadIdx.x & 63;
    const int row = blockIdx.x * 4 + (threadIdx.x >> 6);
    float2 v = *(const float2*)(la + (size_t)row * 128 + lane * 2);
    float2 w = *(const float2*)(w5 + 128 + lane * 2);
    float x = fmaxf(v.x, 0.f) * w.x + fmaxf(v.y, 0.f) * w.y;
#pragma unroll
    for (int o = 32; o; o >>= 1) x += __shfl_down(x, o);
    if (lane == 0) out[row] = x + A[row / NN] + b5[0];
}

// ---------------- masked softmax per sequence step ----------------
__device__ __forceinline__ bool reach_at(const void* reach, int mode, int idx) {
    if (mode == 0) return ((const int*)reach)[idx] != 0;
    if (mode == 1) return ((const unsigned char*)reach)[idx] != 0;
    return ((const float*)reach)[idx] != 0.f;
}
__global__ __launch_bounds__(256) void softmax_k(
    const float* __restrict__ lg, const void* __restrict__ reach,
    const int* __restrict__ mode, float* __restrict__ prob)
{
    const int s = blockIdx.x, t = threadIdx.x;
    const int m = *mode;
    __shared__ float red[256];
    float mx = -1e30f;
    for (int i = t; i < NN; i += 256) {
        int idx = s * NN + i;
        if (reach_at(reach, m, idx)) mx = fmaxf(mx, lg[idx]);
    }
    red[t] = mx;
    __syncthreads();
    for (int o = 128; o; o >>= 1) {
        if (t < o) red[t] = fmaxf(red[t], red[t + o]);
        __syncthreads();
    }
    mx = red[0];
    __syncthreads();
    float sum = 0.f;
    for (int i = t; i < NN; i += 256) {
        int idx = s * NN + i;
        float v = reach_at(reach, m, idx) ? __expf(lg[idx] - mx) : 0.f;
        prob[idx] = v;
        sum += v;
    }
    red[t] = sum;
    __syncthreads();
    for (int o = 128; o; o >>= 1) {
        if (t < o) red[t] += red[t + o];
        __syncthreads();
    }
    float inv = 1.f / red[0];
    for (int i = t; i < NN; i += 256) prob[s * NN + i] *= inv;
}

// ---------------- driver ----------------
extern "C" void kernel_launch(void* const* d_in, const int* in_sizes, int n_in,
                              void* d_out, int out_size, void* d_ws, size_t ws_size,
                              hipStream_t stream) {
    const float* nfm   = (const float*)d_in[0];
    const int*   ei    = (const int*)d_in[1];
    const void*  reach = d_in[2];
    const float* h0    = (const float*)d_in[3];
    const float* c0    = (const float*)d_in[4];
    const float* W1    = (const float*)d_in[5];
    const float* b1    = (const float*)d_in[6];
    const float* att1  = (const float*)d_in[7];
    const float* bias1 = (const float*)d_in[8];
    const float* Wl    = (const float*)d_in[9];
    const float* bl    = (const float*)d_in[10];
    const float* attl  = (const float*)d_in[11];
    const float* biasl = (const float*)d_in[12];
    const float* Wih   = (const float*)d_in[13];
    const float* Whh   = (const float*)d_in[14];
    const float* bih   = (const float*)d_in[15];
    const float* bhh   = (const float*)d_in[16];
    const float* W6    = (const float*)d_in[17];
    const float* b6    = (const float*)d_in[18];
    const float* W7    = (const float*)d_in[19];
    const float* b7    = (const float*)d_in[20];
    const float* w5    = (const float*)d_in[21];
    const float* b5    = (const float*)d_in[22];

    char* ws = (char*)d_ws;
    float*  xA     = (float*)(ws + WS_XA);
    float*  xB     = (float*)(ws + WS_XB);
    int*    rowptr = (int*)(ws + WS_ROWPTR);
    int*    cursor = (int*)(ws + WS_CURSOR);   // doubles as deg
    int*    eids   = (int*)(ws + WS_EIDS);
    int*    incl   = (int*)(ws + WS_INCL);
    int*    bsum   = (int*)(ws + WS_BSUM);
    int*    boff   = (int*)(ws + WS_BOFF);
    int*    modep  = (int*)(ws + WS_MODE);
    float*  logitb = (float*)(ws + WS_LOGIT);
    float2* Wt2    = (float2*)(ws + WS_WT2);
    float*  As     = (float*)(ws + WS_AS);
    float*  logit2 = (float*)(ws + WS_LOGIT2);

    float* prob = (float*)d_out;
    float* hT   = (float*)d_out + 64000;
    float* cT   = (float*)d_out + 192000;

    // setup
    detect_mode_k<<<1, 256, 0, stream>>>((const unsigned char*)reach, modep);
    zero_ints_k<<<250, 256, 0, stream>>>(cursor, NT);            // deg = 0
    hist_k<<<2250, 256, 0, stream>>>(ei, cursor);                // deg histogram
    scan1_k<<<250, 256, 0, stream>>>(cursor, incl, bsum);
    scan2_k<<<1, 256, 0, stream>>>(bsum, boff);
    scan3_k<<<250, 256, 0, stream>>>(incl, boff, rowptr, cursor);
    fill_k<<<2250, 256, 0, stream>>>(ei, cursor, eids);
    build_wt2_k<<<256, 256, 0, stream>>>(Wih, Whh, Wt2);

    // 5 GATv2 layers: gemm (x->xB), edge logits, aggregate (xB->xA)
    for (int l = 0; l < 5; l++) {
        if (l == 0)
            gemm_xw<64><<<1000, 256, 0, stream>>>(nfm, W1, b1, xB);
        else
            gemm_xw<128><<<1000, 256, 0, stream>>>(xA, Wl + (size_t)(l - 1) * 128 * 128,
                                                   bl + (l - 1) * 128, xB);
        const float* att  = (l == 0) ? att1  : attl  + (l - 1) * 128;
        const float* bias = (l == 0) ? bias1 : biasl + (l - 1) * 128;
        edge_logit_k<<<2048, 256, 0, stream>>>(xB, ei, att, logitb);
        gat_aggr_k<<<16000, 256, 0, stream>>>(xB, logitb, ei, rowptr, eids, bias, xA,
                                              (l < 4) ? 1 : 0);
    }

    // LSTM scan (in-place: xA becomes mu = h sequence), writes hT/cT
    lstm_k<<<125, 256, 0, stream>>>(xA, Wt2, bih, bhh, h0, c0, hT, cT);

    // head
    meanpool_gs_k<<<64, 256, 0, stream>>>(xA, W6, b6, w5, As);
    gemm_xw<128><<<1000, 256, 0, stream>>>(xA, W7, b7, xB);      // la
    rowdot_k<<<16000, 256, 0, stream>>>(xB, w5, b5, As, logit2);
    softmax_k<<<64, 256, 0, stream>>>(logit2, reach, modep, prob);
}

// Round 2
// 1419.931 us; speedup vs baseline: 2.2717x; 2.2717x over previous
//
#include <hip/hip_runtime.h>
#include <hip/hip_bf16.h>

// ---------------- problem constants ----------------
#define SQ   64        // seq len
#define NN   1000      // nodes per graph
#define NT   64000     // total nodes
#define EE   128       // emb dim
#define EG   512000    // graph edges (no self loops)
#define ET   576000    // edges + self loops

// ---------------- workspace layout (bytes) ----------------
#define WS_XA      0ull          // 32,768,000  float[NT*128]  x ping (mu lives here)
#define WS_XB      33000000ull   // 32,768,000  float[NT*128]  x pong (xl / la)
#define WS_ROWPTR  66000000ull   // 256,004     int[NT+1]
#define WS_CURSOR  66300000ull   // 256,000     int[NT]   (also used as deg)
#define WS_SRCS    66600000ull   // 2,304,000   int[ET]  (src node id, dst-grouped)
#define WS_INCL    69000000ull   // 256,000     int[NT]
#define WS_BSUM    69300000ull   // 1,024       int[250]
#define WS_BOFF    69302048ull   // 1,024       int[250]
#define WS_MODE    69304096ull   // 4           int
#define WS_WT2     70000000ull   // 524,288     float2[128*512]
#define WS_AS      70600000ull   // 256         float[64]
#define WS_LOGIT2  70700000ull   // 256,000     float[NT]
// total ~71 MB

// ---------------- helpers ----------------
__device__ __forceinline__ float rdlane(float v, int l) {
    return __int_as_float(__builtin_amdgcn_readlane(__float_as_int(v), l));
}
__device__ __forceinline__ float sigm(float x) { return 1.0f / (1.0f + __expf(-x)); }
__device__ __forceinline__ float tanh_f(float x) {
    x = fminf(fmaxf(x, -30.0f), 30.0f);
    float e = __expf(2.0f * x);
    return (e - 1.0f) / (e + 1.0f);
}

// ---------------- reachable dtype detection ----------------
__global__ void detect_mode_k(const unsigned char* __restrict__ p, int* __restrict__ mode) {
    __shared__ int f0, f3;
    const int t = threadIdx.x;
    if (t == 0) { f0 = 0; f3 = 0; }
    __syncthreads();
    int l0 = 0, l3 = 0;
    for (int i = t; i < 16000; i += 256) {
        if (p[4 * i])     l0 = 1;
        if (p[4 * i + 3]) l3 = 1;
    }
    if (l0) atomicOr(&f0, 1);
    if (l3) atomicOr(&f3, 1);
    __syncthreads();
    if (t == 0) {
        int m;
        if (f0 && f3)      m = 1;  // bool bytes
        else if (f0)       m = 0;  // int32
        else               m = 2;  // float32
        *mode = m;
    }
}

// ---------------- CSR construction (dst-grouped src list; built once) ----------------
__global__ void zero_ints_k(int* __restrict__ p, int n) {
    int i = blockIdx.x * 256 + threadIdx.x;
    if (i < n) p[i] = 0;
}
__global__ void hist_k(const int* __restrict__ ei, int* __restrict__ deg) {
    int e = blockIdx.x * 256 + threadIdx.x;
    if (e < ET) {
        int d = (e < EG) ? ei[EG + e] : (e - EG);
        atomicAdd(deg + d, 1);
    }
}
__global__ void scan1_k(const int* __restrict__ deg, int* __restrict__ incl, int* __restrict__ bsum) {
    __shared__ int sh[256];
    const int t = threadIdx.x;
    const int i = blockIdx.x * 256 + t;
    sh[t] = deg[i];
    __syncthreads();
    for (int o = 1; o < 256; o <<= 1) {
        int add = (t >= o) ? sh[t - o] : 0;
        __syncthreads();
        sh[t] += add;
        __syncthreads();
    }
    incl[i] = sh[t];
    if (t == 255) bsum[blockIdx.x] = sh[255];
}
__global__ void scan2_k(const int* __restrict__ bsum, int* __restrict__ boff) {
    __shared__ int sh[256];
    const int t = threadIdx.x;
    int v = (t < 250) ? bsum[t] : 0;
    sh[t] = v;
    __syncthreads();
    for (int o = 1; o < 256; o <<= 1) {
        int add = (t >= o) ? sh[t - o] : 0;
        __syncthreads();
        sh[t] += add;
        __syncthreads();
    }
    if (t < 250) boff[t] = sh[t] - v;   // exclusive
}
__global__ void scan3_k(const int* __restrict__ incl, const int* __restrict__ boff,
                        int* __restrict__ rowptr, int* __restrict__ cursor_deg) {
    const int i = blockIdx.x * 256 + threadIdx.x;
    int total = incl[i] + boff[blockIdx.x];
    int excl  = total - cursor_deg[i];
    rowptr[i] = excl;
    cursor_deg[i] = excl;                 // becomes fill cursor
    if (i == NT - 1) rowptr[NT] = total;
}
__global__ void fill_k(const int* __restrict__ ei, int* __restrict__ cursor, int* __restrict__ srcs) {
    int e = blockIdx.x * 256 + threadIdx.x;
    if (e < ET) {
        int s_, d_;
        if (e < EG) { s_ = ei[e]; d_ = ei[EG + e]; }
        else        { s_ = e - EG; d_ = s_; }
        int p = atomicAdd(cursor + d_, 1);
        srcs[p] = s_;
    }
}

// ---------------- fp32 GEMM: out[M x 128] = x[M x K] @ W[K x 128] + b ----------------
// k-major x tile in LDS: inner loop is 3 LDS reads per 32 FMAs (was 10).
template <int K>
__global__ __launch_bounds__(256) void gemm2(
    const float* __restrict__ x, const float* __restrict__ W,
    const float* __restrict__ b, float* __restrict__ out)
{
    __shared__ float Wsh[64 * 128];     // [k][col]
    __shared__ float xT[64 * 68];       // [k][row], pad 68 keeps b128 alignment
    const int t = threadIdx.x;
    const int row0 = blockIdx.x * 64;
    const int cg = t & 31;   // cols cg*4 .. +3
    const int rg = t >> 5;   // rows rg*8 .. +7
    float4 acc[8];
#pragma unroll
    for (int r = 0; r < 8; r++) acc[r] = make_float4(0.f, 0.f, 0.f, 0.f);

    for (int k0 = 0; k0 < K; k0 += 64) {
        for (int i = t * 4; i < 64 * 128; i += 1024)
            *(float4*)(Wsh + i) = *(const float4*)(W + (size_t)k0 * 128 + i);
        for (int i = t * 4; i < 64 * 64; i += 1024) {
            int r = i >> 6, k = i & 63;
            float4 v = *(const float4*)(x + (size_t)(row0 + r) * K + k0 + k);
            xT[(k + 0) * 68 + r] = v.x;
            xT[(k + 1) * 68 + r] = v.y;
            xT[(k + 2) * 68 + r] = v.z;
            xT[(k + 3) * 68 + r] = v.w;
        }
        __syncthreads();
#pragma unroll 4
        for (int k = 0; k < 64; k++) {
            float4 w  = *(const float4*)(Wsh + k * 128 + cg * 4);
            float4 xa = *(const float4*)(xT + k * 68 + rg * 8);
            float4 xb = *(const float4*)(xT + k * 68 + rg * 8 + 4);
            acc[0].x += xa.x * w.x; acc[0].y += xa.x * w.y; acc[0].z += xa.x * w.z; acc[0].w += xa.x * w.w;
            acc[1].x += xa.y * w.x; acc[1].y += xa.y * w.y; acc[1].z += xa.y * w.z; acc[1].w += xa.y * w.w;
            acc[2].x += xa.z * w.x; acc[2].y += xa.z * w.y; acc[2].z += xa.z * w.z; acc[2].w += xa.z * w.w;
            acc[3].x += xa.w * w.x; acc[3].y += xa.w * w.y; acc[3].z += xa.w * w.z; acc[3].w += xa.w * w.w;
            acc[4].x += xb.x * w.x; acc[4].y += xb.x * w.y; acc[4].z += xb.x * w.z; acc[4].w += xb.x * w.w;
            acc[5].x += xb.y * w.x; acc[5].y += xb.y * w.y; acc[5].z += xb.y * w.z; acc[5].w += xb.y * w.w;
            acc[6].x += xb.z * w.x; acc[6].y += xb.z * w.y; acc[6].z += xb.z * w.z; acc[6].w += xb.z * w.w;
            acc[7].x += xb.w * w.x; acc[7].y += xb.w * w.y; acc[7].z += xb.w * w.z; acc[7].w += xb.w * w.w;
        }
        __syncthreads();
    }
    float4 bv = *(const float4*)(b + cg * 4);
#pragma unroll
    for (int r = 0; r < 8; r++) {
        float4 o;
        o.x = acc[r].x + bv.x; o.y = acc[r].y + bv.y;
        o.z = acc[r].z + bv.z; o.w = acc[r].w + bv.w;
        *(float4*)(out + (size_t)(row0 + rg * 8 + r) * 128 + cg * 4) = o;
    }
}

// ---------------- fused GATv2: logits + online softmax + aggregate ----------------
// one wave per dst node; lane -> channel pair; half-waves -> heads.
// each edge's xl[src] row is read exactly once.
__global__ __launch_bounds__(256) void gat_fused_k(
    const float* __restrict__ xl, const int* __restrict__ rowptr,
    const int* __restrict__ srcs, const float* __restrict__ att,
    const float* __restrict__ bias, float* __restrict__ out, const int do_relu)
{
    const int lane = threadIdx.x & 63;
    const int n = blockIdx.x * 4 + (threadIdx.x >> 6);
    const float2 a = *(const float2*)(att + lane * 2);
    const float2 xd = *(const float2*)(xl + (size_t)n * 128 + lane * 2);
    const int i0 = rowptr[n], i1 = rowptr[n + 1];

    float m = -1e30f, den = 0.f, ax = 0.f, ay = 0.f;
    int sv = srcs[i0];
    for (int i = i0; i < i1; i++) {
        int snx = (i + 1 < i1) ? srcs[i + 1] : 0;   // prefetch next src id
        const float2 xs = *(const float2*)(xl + (size_t)sv * 128 + lane * 2);
        float u = xs.x + xd.x, v = xs.y + xd.y;
        u = (u > 0.f) ? u : 0.2f * u;
        v = (v > 0.f) ? v : 0.2f * v;
        float p = u * a.x + v * a.y;
        p += __shfl_xor(p, 1, 32);
        p += __shfl_xor(p, 2, 32);
        p += __shfl_xor(p, 4, 32);
        p += __shfl_xor(p, 8, 32);
        p += __shfl_xor(p, 16, 32);     // all 32 lanes of the head hold the logit
        float mn = fmaxf(m, p);
        float sc = __expf(m - mn);
        float w  = __expf(p - mn);
        den = den * sc + w;
        ax = ax * sc + w * xs.x;
        ay = ay * sc + w * xs.y;
        m = mn;
        sv = snx;
    }
    float2 bv = *(const float2*)(bias + lane * 2);
    float inv = 1.f / den;
    float ox = ax * inv + bv.x, oy = ay * inv + bv.y;
    if (do_relu) { ox = fmaxf(ox, 0.f); oy = fmaxf(oy, 0.f); }
    *(float2*)(out + (size_t)n * 128 + lane * 2) = make_float2(ox, oy);
}

// ---------------- LSTM weight transpose: Wt2[k][j] = (Wih[j][k], Whh[j][k]) ----------------
__global__ void build_wt2_k(const float* __restrict__ Wih, const float* __restrict__ Whh,
                            float2* __restrict__ Wt2) {
    int id = blockIdx.x * 256 + threadIdx.x;    // 128*512 ids
    if (id < 128 * 512) {
        int k = id >> 9, j = id & 511;
        Wt2[id] = make_float2(Wih[(size_t)j * 128 + k], Whh[(size_t)j * 128 + k]);
    }
}

// ---------------- persistent LSTM scan ----------------
// 250 blocks x 256 threads; block owns 4 nodes (independent chains, no grid sync).
// thread t computes gate rows j=t and j=t+256; x/h broadcast via v_readlane.
__global__ __launch_bounds__(256) void lstm_k(
    float* __restrict__ mu, const float2* __restrict__ Wt2,
    const float* __restrict__ bih, const float* __restrict__ bhh,
    const float* __restrict__ h0, const float* __restrict__ c0,
    float* __restrict__ hT, float* __restrict__ cT)
{
    const int t = threadIdx.x, lane = t & 63;
    const int n0 = blockIdx.x * 4;
    __shared__ float hsh[4][128];
    __shared__ float gsh[4][512];
    const int j1 = t, j2 = t + 256;
    const float b1 = bih[j1] + bhh[j1];
    const float b2 = bih[j2] + bhh[j2];
    float creg[2];
#pragma unroll
    for (int q = 0; q < 2; q++) {
        int id = t + 256 * q;
        creg[q] = c0[(size_t)(n0 + (id >> 7)) * 128 + (id & 127)];
    }
    for (int i = t; i < 512; i += 256)
        hsh[i >> 7][i & 127] = h0[(size_t)(n0 + (i >> 7)) * 128 + (i & 127)];
    __syncthreads();

    for (int s = 0; s < SQ; s++) {
        float* xrow = mu + ((size_t)s * NN + n0) * 128;
        float2 xr[4], hr[4];
#pragma unroll
        for (int n = 0; n < 4; n++) {
            xr[n] = *(const float2*)(xrow + n * 128 + lane * 2);
            hr[n] = *(const float2*)(&hsh[n][lane * 2]);
        }
        float acc1[4], acc2[4];
#pragma unroll
        for (int n = 0; n < 4; n++) { acc1[n] = b1; acc2[n] = b2; }

#pragma unroll 2
        for (int kp = 0; kp < 64; kp++) {
            float2 wa1 = Wt2[(2 * kp) * 512 + j1];
            float2 wb1 = Wt2[(2 * kp + 1) * 512 + j1];
            float2 wa2 = Wt2[(2 * kp) * 512 + j2];
            float2 wb2 = Wt2[(2 * kp + 1) * 512 + j2];
#pragma unroll
            for (int n = 0; n < 4; n++) {
                float sx0 = rdlane(xr[n].x, kp), sx1 = rdlane(xr[n].y, kp);
                float sh0 = rdlane(hr[n].x, kp), sh1 = rdlane(hr[n].y, kp);
                acc1[n] += sx0 * wa1.x + sh0 * wa1.y + sx1 * wb1.x + sh1 * wb1.y;
                acc2[n] += sx0 * wa2.x + sh0 * wa2.y + sx1 * wb2.x + sh1 * wb2.y;
            }
        }
#pragma unroll
        for (int n = 0; n < 4; n++) { gsh[n][j1] = acc1[n]; gsh[n][j2] = acc2[n]; }
        __syncthreads();
#pragma unroll
        for (int q = 0; q < 2; q++) {
            int id = t + 256 * q;
            int n = id >> 7, e = id & 127;
            float iv = gsh[n][e], fv = gsh[n][128 + e];
            float gv = gsh[n][256 + e], ov = gsh[n][384 + e];
            float c = sigm(fv) * creg[q] + sigm(iv) * tanh_f(gv);
            float h = sigm(ov) * tanh_f(c);
            creg[q] = c;
            hsh[n][e] = h;
            xrow[n * 128 + e] = h;        // mu <- h_t (scan output)
            if (s == SQ - 1) {
                hT[(size_t)(n0 + n) * 128 + e] = h;
                cT[(size_t)(n0 + n) * 128 + e] = c;
            }
        }
        __syncthreads();
    }
}

// ---------------- head: meanpool -> gs -> A[s] = sum_j relu(gs)*w5[j] ----------------
__global__ __launch_bounds__(256) void meanpool_gs_k(
    const float* __restrict__ mu, const float* __restrict__ W6,
    const float* __restrict__ b6, const float* __restrict__ w5,
    float* __restrict__ A)
{
    const int s = blockIdx.x, t = threadIdx.x;
    const int ch = t & 127, half = t >> 7;
    __shared__ float mp[128];
    __shared__ float red[256];
    float acc = 0.f;
    for (int n = half * 500; n < (half + 1) * 500; n++)
        acc += mu[((size_t)s * NN + n) * 128 + ch];
    red[t] = acc;
    __syncthreads();
    if (t < 128) mp[t] = (red[t] + red[t + 128]) * 0.001f;
    __syncthreads();
    float g = 0.f;
    if (t < 128) {
        g = b6[t];
        for (int k = 0; k < 128; k++) g += mp[k] * W6[(size_t)k * 128 + t];
        g = fmaxf(g, 0.f) * w5[t];
    }
    red[t] = g;
    __syncthreads();
    for (int o = 128; o > 0; o >>= 1) {
        if (t < o) red[t] += red[t + o];
        __syncthreads();
    }
    if (t == 0) A[s] = red[0];
}

// ---------------- head: logit2[row] = A[s] + b5 + sum_j relu(la[row][j]) * w5[128+j] ----------------
__global__ __launch_bounds__(256) void rowdot_k(
    const float* __restrict__ la, const float* __restrict__ w5,
    const float* __restrict__ b5, const float* __restrict__ A,
    float* __restrict__ out)
{
    const int lane = threadIdx.x & 63;
    const int row = blockIdx.x * 4 + (threadIdx.x >> 6);
    float2 v = *(const float2*)(la + (size_t)row * 128 + lane * 2);
    float2 w = *(const float2*)(w5 + 128 + lane * 2);
    float x = fmaxf(v.x, 0.f) * w.x + fmaxf(v.y, 0.f) * w.y;
#pragma unroll
    for (int o = 32; o; o >>= 1) x += __shfl_down(x, o);
    if (lane == 0) out[row] = x + A[row / NN] + b5[0];
}

// ---------------- masked softmax per sequence step ----------------
__device__ __forceinline__ bool reach_at(const void* reach, int mode, int idx) {
    if (mode == 0) return ((const int*)reach)[idx] != 0;
    if (mode == 1) return ((const unsigned char*)reach)[idx] != 0;
    return ((const float*)reach)[idx] != 0.f;
}
__global__ __launch_bounds__(256) void softmax_k(
    const float* __restrict__ lg, const void* __restrict__ reach,
    const int* __restrict__ mode, float* __restrict__ prob)
{
    const int s = blockIdx.x, t = threadIdx.x;
    const int m = *mode;
    __shared__ float red[256];
    float mx = -1e30f;
    for (int i = t; i < NN; i += 256) {
        int idx = s * NN + i;
        if (reach_at(reach, m, idx)) mx = fmaxf(mx, lg[idx]);
    }
    red[t] = mx;
    __syncthreads();
    for (int o = 128; o; o >>= 1) {
        if (t < o) red[t] = fmaxf(red[t], red[t + o]);
        __syncthreads();
    }
    mx = red[0];
    __syncthreads();
    float sum = 0.f;
    for (int i = t; i < NN; i += 256) {
        int idx = s * NN + i;
        float v = reach_at(reach, m, idx) ? __expf(lg[idx] - mx) : 0.f;
        prob[idx] = v;
        sum += v;
    }
    red[t] = sum;
    __syncthreads();
    for (int o = 128; o; o >>= 1) {
        if (t < o) red[t] += red[t + o];
        __syncthreads();
    }
    float inv = 1.f / red[0];
    for (int i = t; i < NN; i += 256) prob[s * NN + i] *= inv;
}

// ---------------- driver ----------------
extern "C" void kernel_launch(void* const* d_in, const int* in_sizes, int n_in,
                              void* d_out, int out_size, void* d_ws, size_t ws_size,
                              hipStream_t stream) {
    const float* nfm   = (const float*)d_in[0];
    const int*   ei    = (const int*)d_in[1];
    const void*  reach = d_in[2];
    const float* h0    = (const float*)d_in[3];
    const float* c0    = (const float*)d_in[4];
    const float* W1    = (const float*)d_in[5];
    const float* b1    = (const float*)d_in[6];
    const float* att1  = (const float*)d_in[7];
    const float* bias1 = (const float*)d_in[8];
    const float* Wl    = (const float*)d_in[9];
    const float* bl    = (const float*)d_in[10];
    const float* attl  = (const float*)d_in[11];
    const float* biasl = (const float*)d_in[12];
    const float* Wih   = (const float*)d_in[13];
    const float* Whh   = (const float*)d_in[14];
    const float* bih   = (const float*)d_in[15];
    const float* bhh   = (const float*)d_in[16];
    const float* W6    = (const float*)d_in[17];
    const float* b6    = (const float*)d_in[18];
    const float* W7    = (const float*)d_in[19];
    const float* b7    = (const float*)d_in[20];
    const float* w5    = (const float*)d_in[21];
    const float* b5    = (const float*)d_in[22];

    char* ws = (char*)d_ws;
    float*  xA     = (float*)(ws + WS_XA);
    float*  xB     = (float*)(ws + WS_XB);
    int*    rowptr = (int*)(ws + WS_ROWPTR);
    int*    cursor = (int*)(ws + WS_CURSOR);
    int*    srcs   = (int*)(ws + WS_SRCS);
    int*    incl   = (int*)(ws + WS_INCL);
    int*    bsum   = (int*)(ws + WS_BSUM);
    int*    boff   = (int*)(ws + WS_BOFF);
    int*    modep  = (int*)(ws + WS_MODE);
    float2* Wt2    = (float2*)(ws + WS_WT2);
    float*  As     = (float*)(ws + WS_AS);
    float*  logit2 = (float*)(ws + WS_LOGIT2);

    float* prob = (float*)d_out;
    float* hT   = (float*)d_out + 64000;
    float* cT   = (float*)d_out + 192000;

    // setup
    detect_mode_k<<<1, 256, 0, stream>>>((const unsigned char*)reach, modep);
    zero_ints_k<<<250, 256, 0, stream>>>(cursor, NT);
    hist_k<<<2250, 256, 0, stream>>>(ei, cursor);
    scan1_k<<<250, 256, 0, stream>>>(cursor, incl, bsum);
    scan2_k<<<1, 256, 0, stream>>>(bsum, boff);
    scan3_k<<<250, 256, 0, stream>>>(incl, boff, rowptr, cursor);
    fill_k<<<2250, 256, 0, stream>>>(ei, cursor, srcs);
    build_wt2_k<<<256, 256, 0, stream>>>(Wih, Whh, Wt2);

    // 5 GATv2 layers: gemm (x->xB), fused logits+softmax+aggregate (xB->xA)
    for (int l = 0; l < 5; l++) {
        if (l == 0)
            gemm2<64><<<1000, 256, 0, stream>>>(nfm, W1, b1, xB);
        else
            gemm2<128><<<1000, 256, 0, stream>>>(xA, Wl + (size_t)(l - 1) * 128 * 128,
                                                 bl + (l - 1) * 128, xB);
        const float* att  = (l == 0) ? att1  : attl  + (l - 1) * 128;
        const float* bias = (l == 0) ? bias1 : biasl + (l - 1) * 128;
        gat_fused_k<<<16000, 256, 0, stream>>>(xB, rowptr, srcs, att, bias, xA,
                                               (l < 4) ? 1 : 0);
    }

    // LSTM scan (in-place: xA becomes mu = h sequence), writes hT/cT
    lstm_k<<<250, 256, 0, stream>>>(xA, Wt2, bih, bhh, h0, c0, hT, cT);

    // head
    meanpool_gs_k<<<64, 256, 0, stream>>>(xA, W6, b6, w5, As);
    gemm2<128><<<1000, 256, 0, stream>>>(xA, W7, b7, xB);      // la
    rowdot_k<<<16000, 256, 0, stream>>>(xB, w5, b5, As, logit2);
    softmax_k<<<64, 256, 0, stream>>>(logit2, reach, modep, prob);
}

// Round 3
// 1293.129 us; speedup vs baseline: 2.4944x; 1.0981x over previous
//
#include <hip/hip_runtime.h>
#include <hip/hip_bf16.h>

// ---------------- problem constants ----------------
#define SQ   64        // seq len
#define NN   1000      // nodes per graph
#define NT   64000     // total nodes
#define EE   128       // emb dim
#define EG   512000    // graph edges (no self loops)
#define ET   576000    // edges + self loops

// ---------------- workspace layout (bytes) ----------------
#define WS_XA      0ull          // 32,768,000  float[NT*128]  x ping (mu lives here)
#define WS_XB      33000000ull   // 32,768,000  float[NT*128]  x pong (xl / la)
#define WS_ROWPTR  66000000ull   // 256,004     int[NT+1]
#define WS_CURSOR  66300000ull   // 256,000     int[NT]   (also used as deg)
#define WS_SRCS    66600000ull   // 2,304,000   int[ET]  (src node id, dst-grouped)
#define WS_INCL    69000000ull   // 256,000     int[NT]
#define WS_BSUM    69300000ull   // 1,024       int[250]
#define WS_BOFF    69302048ull   // 1,024       int[250]
#define WS_MODE    69304096ull   // 4           int
#define WS_WQA     70000000ull   // 262,144     float4[64*256]  LSTM weights, j1 rows
#define WS_WQB     70262144ull   // 262,144     float4[64*256]  LSTM weights, j2 rows
#define WS_AS      70600000ull   // 256         float[64]
#define WS_LOGIT2  70700000ull   // 256,000     float[NT]
// total ~71 MB

// ---------------- helpers ----------------
__device__ __forceinline__ float rdlane(float v, int l) {
    return __int_as_float(__builtin_amdgcn_readlane(__float_as_int(v), l));
}
__device__ __forceinline__ float sigm(float x) { return 1.0f / (1.0f + __expf(-x)); }
__device__ __forceinline__ float tanh_f(float x) {
    x = fminf(fmaxf(x, -30.0f), 30.0f);
    float e = __expf(2.0f * x);
    return (e - 1.0f) / (e + 1.0f);
}

// ---------------- reachable dtype detection ----------------
__global__ void detect_mode_k(const unsigned char* __restrict__ p, int* __restrict__ mode) {
    __shared__ int f0, f3;
    const int t = threadIdx.x;
    if (t == 0) { f0 = 0; f3 = 0; }
    __syncthreads();
    int l0 = 0, l3 = 0;
    for (int i = t; i < 16000; i += 256) {
        if (p[4 * i])     l0 = 1;
        if (p[4 * i + 3]) l3 = 1;
    }
    if (l0) atomicOr(&f0, 1);
    if (l3) atomicOr(&f3, 1);
    __syncthreads();
    if (t == 0) {
        int m;
        if (f0 && f3)      m = 1;  // bool bytes
        else if (f0)       m = 0;  // int32
        else               m = 2;  // float32
        *mode = m;
    }
}

// ---------------- CSR construction (dst-grouped src list; built once) ----------------
__global__ void zero_ints_k(int* __restrict__ p, int n) {
    int i = blockIdx.x * 256 + threadIdx.x;
    if (i < n) p[i] = 0;
}
__global__ void hist_k(const int* __restrict__ ei, int* __restrict__ deg) {
    int e = blockIdx.x * 256 + threadIdx.x;
    if (e < ET) {
        int d = (e < EG) ? ei[EG + e] : (e - EG);
        atomicAdd(deg + d, 1);
    }
}
__global__ void scan1_k(const int* __restrict__ deg, int* __restrict__ incl, int* __restrict__ bsum) {
    __shared__ int sh[256];
    const int t = threadIdx.x;
    const int i = blockIdx.x * 256 + t;
    sh[t] = deg[i];
    __syncthreads();
    for (int o = 1; o < 256; o <<= 1) {
        int add = (t >= o) ? sh[t - o] : 0;
        __syncthreads();
        sh[t] += add;
        __syncthreads();
    }
    incl[i] = sh[t];
    if (t == 255) bsum[blockIdx.x] = sh[255];
}
__global__ void scan2_k(const int* __restrict__ bsum, int* __restrict__ boff) {
    __shared__ int sh[256];
    const int t = threadIdx.x;
    int v = (t < 250) ? bsum[t] : 0;
    sh[t] = v;
    __syncthreads();
    for (int o = 1; o < 256; o <<= 1) {
        int add = (t >= o) ? sh[t - o] : 0;
        __syncthreads();
        sh[t] += add;
        __syncthreads();
    }
    if (t < 250) boff[t] = sh[t] - v;   // exclusive
}
__global__ void scan3_k(const int* __restrict__ incl, const int* __restrict__ boff,
                        int* __restrict__ rowptr, int* __restrict__ cursor_deg) {
    const int i = blockIdx.x * 256 + threadIdx.x;
    int total = incl[i] + boff[blockIdx.x];
    int excl  = total - cursor_deg[i];
    rowptr[i] = excl;
    cursor_deg[i] = excl;                 // becomes fill cursor
    if (i == NT - 1) rowptr[NT] = total;
}
__global__ void fill_k(const int* __restrict__ ei, int* __restrict__ cursor, int* __restrict__ srcs) {
    int e = blockIdx.x * 256 + threadIdx.x;
    if (e < ET) {
        int s_, d_;
        if (e < EG) { s_ = ei[e]; d_ = ei[EG + e]; }
        else        { s_ = e - EG; d_ = s_; }
        int p = atomicAdd(cursor + d_, 1);
        srcs[p] = s_;
    }
}

// ---------------- fp32 GEMM: out[M x 128] = x[M x K] @ W[K x 128] + b ----------------
template <int K>
__global__ __launch_bounds__(256) void gemm2(
    const float* __restrict__ x, const float* __restrict__ W,
    const float* __restrict__ b, float* __restrict__ out)
{
    __shared__ float Wsh[64 * 128];     // [k][col]
    __shared__ float xT[64 * 68];       // [k][row], pad 68 keeps b128 alignment
    const int t = threadIdx.x;
    const int row0 = blockIdx.x * 64;
    const int cg = t & 31;   // cols cg*4 .. +3
    const int rg = t >> 5;   // rows rg*8 .. +7
    float4 acc[8];
#pragma unroll
    for (int r = 0; r < 8; r++) acc[r] = make_float4(0.f, 0.f, 0.f, 0.f);

    for (int k0 = 0; k0 < K; k0 += 64) {
        for (int i = t * 4; i < 64 * 128; i += 1024)
            *(float4*)(Wsh + i) = *(const float4*)(W + (size_t)k0 * 128 + i);
        for (int i = t * 4; i < 64 * 64; i += 1024) {
            int r = i >> 6, k = i & 63;
            float4 v = *(const float4*)(x + (size_t)(row0 + r) * K + k0 + k);
            xT[(k + 0) * 68 + r] = v.x;
            xT[(k + 1) * 68 + r] = v.y;
            xT[(k + 2) * 68 + r] = v.z;
            xT[(k + 3) * 68 + r] = v.w;
        }
        __syncthreads();
#pragma unroll 4
        for (int k = 0; k < 64; k++) {
            float4 w  = *(const float4*)(Wsh + k * 128 + cg * 4);
            float4 xa = *(const float4*)(xT + k * 68 + rg * 8);
            float4 xb = *(const float4*)(xT + k * 68 + rg * 8 + 4);
            acc[0].x += xa.x * w.x; acc[0].y += xa.x * w.y; acc[0].z += xa.x * w.z; acc[0].w += xa.x * w.w;
            acc[1].x += xa.y * w.x; acc[1].y += xa.y * w.y; acc[1].z += xa.y * w.z; acc[1].w += xa.y * w.w;
            acc[2].x += xa.z * w.x; acc[2].y += xa.z * w.y; acc[2].z += xa.z * w.z; acc[2].w += xa.z * w.w;
            acc[3].x += xa.w * w.x; acc[3].y += xa.w * w.y; acc[3].z += xa.w * w.z; acc[3].w += xa.w * w.w;
            acc[4].x += xb.x * w.x; acc[4].y += xb.x * w.y; acc[4].z += xb.x * w.z; acc[4].w += xb.x * w.w;
            acc[5].x += xb.y * w.x; acc[5].y += xb.y * w.y; acc[5].z += xb.y * w.z; acc[5].w += xb.y * w.w;
            acc[6].x += xb.z * w.x; acc[6].y += xb.z * w.y; acc[6].z += xb.z * w.z; acc[6].w += xb.z * w.w;
            acc[7].x += xb.w * w.x; acc[7].y += xb.w * w.y; acc[7].z += xb.w * w.z; acc[7].w += xb.w * w.w;
        }
        __syncthreads();
    }
    float4 bv = *(const float4*)(b + cg * 4);
#pragma unroll
    for (int r = 0; r < 8; r++) {
        float4 o;
        o.x = acc[r].x + bv.x; o.y = acc[r].y + bv.y;
        o.z = acc[r].z + bv.z; o.w = acc[r].w + bv.w;
        *(float4*)(out + (size_t)(row0 + rg * 8 + r) * 128 + cg * 4) = o;
    }
}

// ---------------- fused GATv2: logits + online softmax + aggregate ----------------
__global__ __launch_bounds__(256) void gat_fused_k(
    const float* __restrict__ xl, const int* __restrict__ rowptr,
    const int* __restrict__ srcs, const float* __restrict__ att,
    const float* __restrict__ bias, float* __restrict__ out, const int do_relu)
{
    const int lane = threadIdx.x & 63;
    const int n = blockIdx.x * 4 + (threadIdx.x >> 6);
    const float2 a = *(const float2*)(att + lane * 2);
    const float2 xd = *(const float2*)(xl + (size_t)n * 128 + lane * 2);
    const int i0 = rowptr[n], i1 = rowptr[n + 1];

    float m = -1e30f, den = 0.f, ax = 0.f, ay = 0.f;
    int sv = srcs[i0];
    for (int i = i0; i < i1; i++) {
        int snx = (i + 1 < i1) ? srcs[i + 1] : 0;   // prefetch next src id
        const float2 xs = *(const float2*)(xl + (size_t)sv * 128 + lane * 2);
        float u = xs.x + xd.x, v = xs.y + xd.y;
        u = (u > 0.f) ? u : 0.2f * u;
        v = (v > 0.f) ? v : 0.2f * v;
        float p = u * a.x + v * a.y;
        p += __shfl_xor(p, 1, 32);
        p += __shfl_xor(p, 2, 32);
        p += __shfl_xor(p, 4, 32);
        p += __shfl_xor(p, 8, 32);
        p += __shfl_xor(p, 16, 32);     // all 32 lanes of the head hold the logit
        float mn = fmaxf(m, p);
        float sc = __expf(m - mn);
        float w  = __expf(p - mn);
        den = den * sc + w;
        ax = ax * sc + w * xs.x;
        ay = ay * sc + w * xs.y;
        m = mn;
        sv = snx;
    }
    float2 bv = *(const float2*)(bias + lane * 2);
    float inv = 1.f / den;
    float ox = ax * inv + bv.x, oy = ay * inv + bv.y;
    if (do_relu) { ox = fmaxf(ox, 0.f); oy = fmaxf(oy, 0.f); }
    *(float2*)(out + (size_t)n * 128 + lane * 2) = make_float2(ox, oy);
}

// ---------------- LSTM weight packing ----------------
// WQa[kp*256+t] = (Wih[t][2kp],     Whh[t][2kp],     Wih[t][2kp+1],     Whh[t][2kp+1])
// WQb[kp*256+t] = same for row t+256.  One float4 load per (kp, gate-row).
__global__ void build_wq_k(const float* __restrict__ Wih, const float* __restrict__ Whh,
                           float4* __restrict__ WQa, float4* __restrict__ WQb) {
    int id = blockIdx.x * 256 + threadIdx.x;    // 64*256 ids
    if (id < 64 * 256) {
        int kp = id >> 8, t = id & 255;
        int j1 = t, j2 = t + 256;
        WQa[id] = make_float4(Wih[(size_t)j1 * 128 + 2 * kp], Whh[(size_t)j1 * 128 + 2 * kp],
                              Wih[(size_t)j1 * 128 + 2 * kp + 1], Whh[(size_t)j1 * 128 + 2 * kp + 1]);
        WQb[id] = make_float4(Wih[(size_t)j2 * 128 + 2 * kp], Whh[(size_t)j2 * 128 + 2 * kp],
                              Wih[(size_t)j2 * 128 + 2 * kp + 1], Whh[(size_t)j2 * 128 + 2 * kp + 1]);
    }
}

// group of 4 kp's worth of FMAs against a prefetched register buffer
#define LSTM_GROUP(buf, gbase)                                                     \
    _Pragma("unroll")                                                              \
    for (int i_ = 0; i_ < 4; i_++) {                                               \
        const int kp_ = (gbase) * 4 + i_;                                          \
        const float4 qa_ = buf[i_];                                                \
        const float4 qb_ = buf[4 + i_];                                            \
        _Pragma("unroll")                                                          \
        for (int n_ = 0; n_ < 4; n_++) {                                           \
            const float sx0_ = rdlane(xr[n_].x, kp_);                              \
            const float sh0_ = rdlane(hr[n_].x, kp_);                              \
            const float sx1_ = rdlane(xr[n_].y, kp_);                              \
            const float sh1_ = rdlane(hr[n_].y, kp_);                              \
            acc1[n_] += sx0_ * qa_.x + sh0_ * qa_.y + sx1_ * qa_.z + sh1_ * qa_.w; \
            acc2[n_] += sx0_ * qb_.x + sh0_ * qb_.y + sx1_ * qb_.z + sh1_ * qb_.w; \
        }                                                                          \
    }

// ---------------- persistent LSTM scan ----------------
// 250 blocks x 256 threads; block owns 4 nodes (independent chains, no grid sync).
// thread t computes gate rows j=t and j=t+256; x/h broadcast via v_readlane.
// Weight loads software-pipelined: double-buffered groups of 4 kp (8 float4 in
// flight while 384 compute cycles retire) — hides the ~200-300cy L2 latency
// that dominated round 2 (470 cyc/kp measured vs ~100 issue).
__global__ __launch_bounds__(256, 1) void lstm_k(
    float* __restrict__ mu, const float4* __restrict__ WQa, const float4* __restrict__ WQb,
    const float* __restrict__ bih, const float* __restrict__ bhh,
    const float* __restrict__ h0, const float* __restrict__ c0,
    float* __restrict__ hT, float* __restrict__ cT)
{
    const int t = threadIdx.x, lane = t & 63;
    const int n0 = blockIdx.x * 4;
    __shared__ float hsh[4][128];
    __shared__ float gsh[4][512];
    const float b1 = bih[t] + bhh[t];
    const float b2 = bih[t + 256] + bhh[t + 256];
    float creg[2];
#pragma unroll
    for (int q = 0; q < 2; q++) {
        int id = t + 256 * q;
        creg[q] = c0[(size_t)(n0 + (id >> 7)) * 128 + (id & 127)];
    }
    for (int i = t; i < 512; i += 256)
        hsh[i >> 7][i & 127] = h0[(size_t)(n0 + (i >> 7)) * 128 + (i & 127)];

    const float4* pA = WQa + t;   // stride 256 float4 per kp
    const float4* pB = WQb + t;

    // prefetch step-0 x rows
    float2 xr[4], xnx[4];
#pragma unroll
    for (int n = 0; n < 4; n++)
        xr[n] = *(const float2*)(mu + (size_t)n0 * 128 + n * 128 + lane * 2);
    __syncthreads();

    for (int s = 0; s < SQ; s++) {
        float* xrow = mu + ((size_t)s * NN + n0) * 128;
        float2 hr[4];
#pragma unroll
        for (int n = 0; n < 4; n++) hr[n] = *(const float2*)(&hsh[n][lane * 2]);

        float4 bufA[8], bufB[8];
#pragma unroll
        for (int i = 0; i < 4; i++) { bufA[i] = pA[i * 256]; bufA[4 + i] = pB[i * 256]; }

        // prefetch next step's x during compute
        if (s + 1 < SQ) {
            const float* xrow2 = mu + ((size_t)(s + 1) * NN + n0) * 128;
#pragma unroll
            for (int n = 0; n < 4; n++) xnx[n] = *(const float2*)(xrow2 + n * 128 + lane * 2);
        }

        float acc1[4], acc2[4];
#pragma unroll
        for (int n = 0; n < 4; n++) { acc1[n] = b1; acc2[n] = b2; }

        for (int g = 0; g < 16; g += 2) {
#pragma unroll
            for (int i = 0; i < 4; i++) {
                bufB[i]     = pA[((g + 1) * 4 + i) * 256];
                bufB[4 + i] = pB[((g + 1) * 4 + i) * 256];
            }
            LSTM_GROUP(bufA, g)
            if (g < 14) {
#pragma unroll
                for (int i = 0; i < 4; i++) {
                    bufA[i]     = pA[((g + 2) * 4 + i) * 256];
                    bufA[4 + i] = pB[((g + 2) * 4 + i) * 256];
                }
            }
            LSTM_GROUP(bufB, g + 1)
        }

#pragma unroll
        for (int n = 0; n < 4; n++) { gsh[n][t] = acc1[n]; gsh[n][t + 256] = acc2[n]; }
        __syncthreads();
#pragma unroll
        for (int q = 0; q < 2; q++) {
            int id = t + 256 * q;
            int n = id >> 7, e = id & 127;
            float iv = gsh[n][e], fv = gsh[n][128 + e];
            float gv = gsh[n][256 + e], ov = gsh[n][384 + e];
            float c = sigm(fv) * creg[q] + sigm(iv) * tanh_f(gv);
            float h = sigm(ov) * tanh_f(c);
            creg[q] = c;
            hsh[n][e] = h;
            xrow[n * 128 + e] = h;        // mu <- h_t (scan output)
            if (s == SQ - 1) {
                hT[(size_t)(n0 + n) * 128 + e] = h;
                cT[(size_t)(n0 + n) * 128 + e] = c;
            }
        }
#pragma unroll
        for (int n = 0; n < 4; n++) xr[n] = xnx[n];
        __syncthreads();
    }
}

// ---------------- head: meanpool -> gs -> A[s] = sum_j relu(gs)*w5[j] ----------------
__global__ __launch_bounds__(256) void meanpool_gs_k(
    const float* __restrict__ mu, const float* __restrict__ W6,
    const float* __restrict__ b6, const float* __restrict__ w5,
    float* __restrict__ A)
{
    const int s = blockIdx.x, t = threadIdx.x;
    const int ch = t & 127, half = t >> 7;
    __shared__ float mp[128];
    __shared__ float red[256];
    float acc = 0.f;
    for (int n = half * 500; n < (half + 1) * 500; n++)
        acc += mu[((size_t)s * NN + n) * 128 + ch];
    red[t] = acc;
    __syncthreads();
    if (t < 128) mp[t] = (red[t] + red[t + 128]) * 0.001f;
    __syncthreads();
    float g = 0.f;
    if (t < 128) {
        g = b6[t];
        for (int k = 0; k < 128; k++) g += mp[k] * W6[(size_t)k * 128 + t];
        g = fmaxf(g, 0.f) * w5[t];
    }
    red[t] = g;
    __syncthreads();
    for (int o = 128; o > 0; o >>= 1) {
        if (t < o) red[t] += red[t + o];
        __syncthreads();
    }
    if (t == 0) A[s] = red[0];
}

// ---------------- head: logit2[row] = A[s] + b5 + sum_j relu(la[row][j]) * w5[128+j] ----------------
__global__ __launch_bounds__(256) void rowdot_k(
    const float* __restrict__ la, const float* __restrict__ w5,
    const float* __restrict__ b5, const float* __restrict__ A,
    float* __restrict__ out)
{
    const int lane = threadIdx.x & 63;
    const int row = blockIdx.x * 4 + (threadIdx.x >> 6);
    float2 v = *(const float2*)(la + (size_t)row * 128 + lane * 2);
    float2 w = *(const float2*)(w5 + 128 + lane * 2);
    float x = fmaxf(v.x, 0.f) * w.x + fmaxf(v.y, 0.f) * w.y;
#pragma unroll
    for (int o = 32; o; o >>= 1) x += __shfl_down(x, o);
    if (lane == 0) out[row] = x + A[row / NN] + b5[0];
}

// ---------------- masked softmax per sequence step ----------------
__device__ __forceinline__ bool reach_at(const void* reach, int mode, int idx) {
    if (mode == 0) return ((const int*)reach)[idx] != 0;
    if (mode == 1) return ((const unsigned char*)reach)[idx] != 0;
    return ((const float*)reach)[idx] != 0.f;
}
__global__ __launch_bounds__(256) void softmax_k(
    const float* __restrict__ lg, const void* __restrict__ reach,
    const int* __restrict__ mode, float* __restrict__ prob)
{
    const int s = blockIdx.x, t = threadIdx.x;
    const int m = *mode;
    __shared__ float red[256];
    float mx = -1e30f;
    for (int i = t; i < NN; i += 256) {
        int idx = s * NN + i;
        if (reach_at(reach, m, idx)) mx = fmaxf(mx, lg[idx]);
    }
    red[t] = mx;
    __syncthreads();
    for (int o = 128; o; o >>= 1) {
        if (t < o) red[t] = fmaxf(red[t], red[t + o]);
        __syncthreads();
    }
    mx = red[0];
    __syncthreads();
    float sum = 0.f;
    for (int i = t; i < NN; i += 256) {
        int idx = s * NN + i;
        float v = reach_at(reach, m, idx) ? __expf(lg[idx] - mx) : 0.f;
        prob[idx] = v;
        sum += v;
    }
    red[t] = sum;
    __syncthreads();
    for (int o = 128; o; o >>= 1) {
        if (t < o) red[t] += red[t + o];
        __syncthreads();
    }
    float inv = 1.f / red[0];
    for (int i = t; i < NN; i += 256) prob[s * NN + i] *= inv;
}

// ---------------- driver ----------------
extern "C" void kernel_launch(void* const* d_in, const int* in_sizes, int n_in,
                              void* d_out, int out_size, void* d_ws, size_t ws_size,
                              hipStream_t stream) {
    const float* nfm   = (const float*)d_in[0];
    const int*   ei    = (const int*)d_in[1];
    const void*  reach = d_in[2];
    const float* h0    = (const float*)d_in[3];
    const float* c0    = (const float*)d_in[4];
    const float* W1    = (const float*)d_in[5];
    const float* b1    = (const float*)d_in[6];
    const float* att1  = (const float*)d_in[7];
    const float* bias1 = (const float*)d_in[8];
    const float* Wl    = (const float*)d_in[9];
    const float* bl    = (const float*)d_in[10];
    const float* attl  = (const float*)d_in[11];
    const float* biasl = (const float*)d_in[12];
    const float* Wih   = (const float*)d_in[13];
    const float* Whh   = (const float*)d_in[14];
    const float* bih   = (const float*)d_in[15];
    const float* bhh   = (const float*)d_in[16];
    const float* W6    = (const float*)d_in[17];
    const float* b6    = (const float*)d_in[18];
    const float* W7    = (const float*)d_in[19];
    const float* b7    = (const float*)d_in[20];
    const float* w5    = (const float*)d_in[21];
    const float* b5    = (const float*)d_in[22];

    char* ws = (char*)d_ws;
    float*  xA     = (float*)(ws + WS_XA);
    float*  xB     = (float*)(ws + WS_XB);
    int*    rowptr = (int*)(ws + WS_ROWPTR);
    int*    cursor = (int*)(ws + WS_CURSOR);
    int*    srcs   = (int*)(ws + WS_SRCS);
    int*    incl   = (int*)(ws + WS_INCL);
    int*    bsum   = (int*)(ws + WS_BSUM);
    int*    boff   = (int*)(ws + WS_BOFF);
    int*    modep  = (int*)(ws + WS_MODE);
    float4* WQa    = (float4*)(ws + WS_WQA);
    float4* WQb    = (float4*)(ws + WS_WQB);
    float*  As     = (float*)(ws + WS_AS);
    float*  logit2 = (float*)(ws + WS_LOGIT2);

    float* prob = (float*)d_out;
    float* hT   = (float*)d_out + 64000;
    float* cT   = (float*)d_out + 192000;

    // setup
    detect_mode_k<<<1, 256, 0, stream>>>((const unsigned char*)reach, modep);
    zero_ints_k<<<250, 256, 0, stream>>>(cursor, NT);
    hist_k<<<2250, 256, 0, stream>>>(ei, cursor);
    scan1_k<<<250, 256, 0, stream>>>(cursor, incl, bsum);
    scan2_k<<<1, 256, 0, stream>>>(bsum, boff);
    scan3_k<<<250, 256, 0, stream>>>(incl, boff, rowptr, cursor);
    fill_k<<<2250, 256, 0, stream>>>(ei, cursor, srcs);
    build_wq_k<<<64, 256, 0, stream>>>(Wih, Whh, WQa, WQb);

    // 5 GATv2 layers: gemm (x->xB), fused logits+softmax+aggregate (xB->xA)
    for (int l = 0; l < 5; l++) {
        if (l == 0)
            gemm2<64><<<1000, 256, 0, stream>>>(nfm, W1, b1, xB);
        else
            gemm2<128><<<1000, 256, 0, stream>>>(xA, Wl + (size_t)(l - 1) * 128 * 128,
                                                 bl + (l - 1) * 128, xB);
        const float* att  = (l == 0) ? att1  : attl  + (l - 1) * 128;
        const float* bias = (l == 0) ? bias1 : biasl + (l - 1) * 128;
        gat_fused_k<<<16000, 256, 0, stream>>>(xB, rowptr, srcs, att, bias, xA,
                                               (l < 4) ? 1 : 0);
    }

    // LSTM scan (in-place: xA becomes mu = h sequence), writes hT/cT
    lstm_k<<<250, 256, 0, stream>>>(xA, WQa, WQb, bih, bhh, h0, c0, hT, cT);

    // head
    meanpool_gs_k<<<64, 256, 0, stream>>>(xA, W6, b6, w5, As);
    gemm2<128><<<1000, 256, 0, stream>>>(xA, W7, b7, xB);      // la
    rowdot_k<<<16000, 256, 0, stream>>>(xB, w5, b5, As, logit2);
    softmax_k<<<64, 256, 0, stream>>>(logit2, reach, modep, prob);
}

// Round 4
// 1127.480 us; speedup vs baseline: 2.8609x; 1.1469x over previous
//
#include <hip/hip_runtime.h>
#include <hip/hip_bf16.h>

// ---------------- problem constants ----------------
#define SQ   64        // seq len
#define NN   1000      // nodes per graph
#define NT   64000     // total nodes
#define EE   128       // emb dim
#define EG   512000    // graph edges (no self loops)
#define ET   576000    // edges + self loops

// ---------------- workspace layout (bytes) ----------------
// common / fallback region (<71 MB)
#define WS_XA      0ull          // 32,768,000  float[NT*128]  x ping (mu lives here)
#define WS_XB      33000000ull   // 32,768,000  float[NT*128]  x pong (xl / la)
#define WS_ROWPTR  66000000ull   // 256,004     int[NT+1]
#define WS_CURSOR  66300000ull   // 256,000     int[NT]   (also used as deg)
#define WS_SRCS    66600000ull   // 2,304,000   int[ET]  (src node id, dst-grouped)
#define WS_INCL    69000000ull   // 256,000     int[NT]
#define WS_BSUM    69300000ull   // 1,024       int[250]
#define WS_BOFF    69302048ull   // 1,024       int[250]
#define WS_MODE    69304096ull   // 4           int
#define WS_WQA     70000000ull   // 262,144     float4[64*256]  (fallback LSTM)
#define WS_WQB     70262144ull   // 262,144     float4[64*256]  (fallback LSTM)
#define WS_AS      70600000ull   // 256         float[64]
#define WS_LOGIT2  70700000ull   // 256,000     float[NT]
// big-ws region: xC aliases xB + CSR (disjoint lifetimes: CSR/xB dead before
// gemm_proj writes xC; xB reused for la only after lstm2 consumed xC)
#define WS2_XC     33000000ull   // 131,072,000 float[NT*512]  gate preacts (x part)
#define WS2_WQ4    164100000ull  // 262,144     float4[64*256] packed Whh
#define WS2_WIHT   164400000ull  // 262,144     float[128*512] Wih^T
#define WS2_B512   164700000ull  // 2,048       float[512]     bih+bhh
#define WS2_MODE   164710000ull  // 4
#define WS2_AS     164720000ull  // 256
#define WS2_LOGIT2 164800000ull  // 256,000
#define WS2_NEED   165100000ull

// ---------------- helpers ----------------
__device__ __forceinline__ float rdlane(float v, int l) {
    return __int_as_float(__builtin_amdgcn_readlane(__float_as_int(v), l));
}
__device__ __forceinline__ float sigm(float x) { return 1.0f / (1.0f + __expf(-x)); }
__device__ __forceinline__ float tanh_f(float x) {
    x = fminf(fmaxf(x, -30.0f), 30.0f);
    float e = __expf(2.0f * x);
    return (e - 1.0f) / (e + 1.0f);
}

// ---------------- reachable dtype detection ----------------
__global__ void detect_mode_k(const unsigned char* __restrict__ p, int* __restrict__ mode) {
    __shared__ int f0, f3;
    const int t = threadIdx.x;
    if (t == 0) { f0 = 0; f3 = 0; }
    __syncthreads();
    int l0 = 0, l3 = 0;
    for (int i = t; i < 16000; i += 256) {
        if (p[4 * i])     l0 = 1;
        if (p[4 * i + 3]) l3 = 1;
    }
    if (l0) atomicOr(&f0, 1);
    if (l3) atomicOr(&f3, 1);
    __syncthreads();
    if (t == 0) {
        int m;
        if (f0 && f3)      m = 1;  // bool bytes
        else if (f0)       m = 0;  // int32
        else               m = 2;  // float32
        *mode = m;
    }
}

// ---------------- CSR construction (dst-grouped src list; built once) ----------------
__global__ void zero_ints_k(int* __restrict__ p, int n) {
    int i = blockIdx.x * 256 + threadIdx.x;
    if (i < n) p[i] = 0;
}
__global__ void hist_k(const int* __restrict__ ei, int* __restrict__ deg) {
    int e = blockIdx.x * 256 + threadIdx.x;
    if (e < ET) {
        int d = (e < EG) ? ei[EG + e] : (e - EG);
        atomicAdd(deg + d, 1);
    }
}
__global__ void scan1_k(const int* __restrict__ deg, int* __restrict__ incl, int* __restrict__ bsum) {
    __shared__ int sh[256];
    const int t = threadIdx.x;
    const int i = blockIdx.x * 256 + t;
    sh[t] = deg[i];
    __syncthreads();
    for (int o = 1; o < 256; o <<= 1) {
        int add = (t >= o) ? sh[t - o] : 0;
        __syncthreads();
        sh[t] += add;
        __syncthreads();
    }
    incl[i] = sh[t];
    if (t == 255) bsum[blockIdx.x] = sh[255];
}
__global__ void scan2_k(const int* __restrict__ bsum, int* __restrict__ boff) {
    __shared__ int sh[256];
    const int t = threadIdx.x;
    int v = (t < 250) ? bsum[t] : 0;
    sh[t] = v;
    __syncthreads();
    for (int o = 1; o < 256; o <<= 1) {
        int add = (t >= o) ? sh[t - o] : 0;
        __syncthreads();
        sh[t] += add;
        __syncthreads();
    }
    if (t < 250) boff[t] = sh[t] - v;   // exclusive
}
__global__ void scan3_k(const int* __restrict__ incl, const int* __restrict__ boff,
                        int* __restrict__ rowptr, int* __restrict__ cursor_deg) {
    const int i = blockIdx.x * 256 + threadIdx.x;
    int total = incl[i] + boff[blockIdx.x];
    int excl  = total - cursor_deg[i];
    rowptr[i] = excl;
    cursor_deg[i] = excl;                 // becomes fill cursor
    if (i == NT - 1) rowptr[NT] = total;
}
__global__ void fill_k(const int* __restrict__ ei, int* __restrict__ cursor, int* __restrict__ srcs) {
    int e = blockIdx.x * 256 + threadIdx.x;
    if (e < ET) {
        int s_, d_;
        if (e < EG) { s_ = ei[e]; d_ = ei[EG + e]; }
        else        { s_ = e - EG; d_ = s_; }
        int p = atomicAdd(cursor + d_, 1);
        srcs[p] = s_;
    }
}

// ---------------- fp32 GEMM: out[M x 128] = x[M x K] @ W[K x 128] + b ----------------
template <int K>
__global__ __launch_bounds__(256) void gemm2(
    const float* __restrict__ x, const float* __restrict__ W,
    const float* __restrict__ b, float* __restrict__ out)
{
    __shared__ float Wsh[64 * 128];     // [k][col]
    __shared__ float xT[64 * 68];       // [k][row], pad 68 keeps b128 alignment
    const int t = threadIdx.x;
    const int row0 = blockIdx.x * 64;
    const int cg = t & 31;   // cols cg*4 .. +3
    const int rg = t >> 5;   // rows rg*8 .. +7
    float4 acc[8];
#pragma unroll
    for (int r = 0; r < 8; r++) acc[r] = make_float4(0.f, 0.f, 0.f, 0.f);

    for (int k0 = 0; k0 < K; k0 += 64) {
        for (int i = t * 4; i < 64 * 128; i += 1024)
            *(float4*)(Wsh + i) = *(const float4*)(W + (size_t)k0 * 128 + i);
        for (int i = t * 4; i < 64 * 64; i += 1024) {
            int r = i >> 6, k = i & 63;
            float4 v = *(const float4*)(x + (size_t)(row0 + r) * K + k0 + k);
            xT[(k + 0) * 68 + r] = v.x;
            xT[(k + 1) * 68 + r] = v.y;
            xT[(k + 2) * 68 + r] = v.z;
            xT[(k + 3) * 68 + r] = v.w;
        }
        __syncthreads();
#pragma unroll 4
        for (int k = 0; k < 64; k++) {
            float4 w  = *(const float4*)(Wsh + k * 128 + cg * 4);
            float4 xa = *(const float4*)(xT + k * 68 + rg * 8);
            float4 xb = *(const float4*)(xT + k * 68 + rg * 8 + 4);
            acc[0].x += xa.x * w.x; acc[0].y += xa.x * w.y; acc[0].z += xa.x * w.z; acc[0].w += xa.x * w.w;
            acc[1].x += xa.y * w.x; acc[1].y += xa.y * w.y; acc[1].z += xa.y * w.z; acc[1].w += xa.y * w.w;
            acc[2].x += xa.z * w.x; acc[2].y += xa.z * w.y; acc[2].z += xa.z * w.z; acc[2].w += xa.z * w.w;
            acc[3].x += xa.w * w.x; acc[3].y += xa.w * w.y; acc[3].z += xa.w * w.z; acc[3].w += xa.w * w.w;
            acc[4].x += xb.x * w.x; acc[4].y += xb.x * w.y; acc[4].z += xb.x * w.z; acc[4].w += xb.x * w.w;
            acc[5].x += xb.y * w.x; acc[5].y += xb.y * w.y; acc[5].z += xb.y * w.z; acc[5].w += xb.y * w.w;
            acc[6].x += xb.z * w.x; acc[6].y += xb.z * w.y; acc[6].z += xb.z * w.z; acc[6].w += xb.z * w.w;
            acc[7].x += xb.w * w.x; acc[7].y += xb.w * w.y; acc[7].z += xb.w * w.z; acc[7].w += xb.w * w.w;
        }
        __syncthreads();
    }
    float4 bv = *(const float4*)(b + cg * 4);
#pragma unroll
    for (int r = 0; r < 8; r++) {
        float4 o;
        o.x = acc[r].x + bv.x; o.y = acc[r].y + bv.y;
        o.z = acc[r].z + bv.z; o.w = acc[r].w + bv.w;
        *(float4*)(out + (size_t)(row0 + rg * 8 + r) * 128 + cg * 4) = o;
    }
}

// ---------------- fp32 GEMM (projection): out[M x 512] = x[M x 128] @ WT[128 x 512] + b512 ----------------
// grid (M/64, 4): 64-row x 128-col tiles. Same inner loop as gemm2.
__global__ __launch_bounds__(256) void gemm_proj(
    const float* __restrict__ x, const float* __restrict__ WT,
    const float* __restrict__ b512, float* __restrict__ out)
{
    __shared__ float Wsh[64 * 128];
    __shared__ float xT[64 * 68];
    const int t = threadIdx.x;
    const int row0 = blockIdx.x * 64;
    const int col0 = blockIdx.y * 128;
    const int cg = t & 31;
    const int rg = t >> 5;
    float4 acc[8];
#pragma unroll
    for (int r = 0; r < 8; r++) acc[r] = make_float4(0.f, 0.f, 0.f, 0.f);

    for (int k0 = 0; k0 < 128; k0 += 64) {
        for (int i = t * 4; i < 64 * 128; i += 1024) {
            int k = i >> 7, c = i & 127;
            *(float4*)(Wsh + i) = *(const float4*)(WT + (size_t)(k0 + k) * 512 + col0 + c);
        }
        for (int i = t * 4; i < 64 * 64; i += 1024) {
            int r = i >> 6, k = i & 63;
            float4 v = *(const float4*)(x + (size_t)(row0 + r) * 128 + k0 + k);
            xT[(k + 0) * 68 + r] = v.x;
            xT[(k + 1) * 68 + r] = v.y;
            xT[(k + 2) * 68 + r] = v.z;
            xT[(k + 3) * 68 + r] = v.w;
        }
        __syncthreads();
#pragma unroll 4
        for (int k = 0; k < 64; k++) {
            float4 w  = *(const float4*)(Wsh + k * 128 + cg * 4);
            float4 xa = *(const float4*)(xT + k * 68 + rg * 8);
            float4 xb = *(const float4*)(xT + k * 68 + rg * 8 + 4);
            acc[0].x += xa.x * w.x; acc[0].y += xa.x * w.y; acc[0].z += xa.x * w.z; acc[0].w += xa.x * w.w;
            acc[1].x += xa.y * w.x; acc[1].y += xa.y * w.y; acc[1].z += xa.y * w.z; acc[1].w += xa.y * w.w;
            acc[2].x += xa.z * w.x; acc[2].y += xa.z * w.y; acc[2].z += xa.z * w.z; acc[2].w += xa.z * w.w;
            acc[3].x += xa.w * w.x; acc[3].y += xa.w * w.y; acc[3].z += xa.w * w.z; acc[3].w += xa.w * w.w;
            acc[4].x += xb.x * w.x; acc[4].y += xb.x * w.y; acc[4].z += xb.x * w.z; acc[4].w += xb.x * w.w;
            acc[5].x += xb.y * w.x; acc[5].y += xb.y * w.y; acc[5].z += xb.y * w.z; acc[5].w += xb.y * w.w;
            acc[6].x += xb.z * w.x; acc[6].y += xb.z * w.y; acc[6].z += xb.z * w.z; acc[6].w += xb.z * w.w;
            acc[7].x += xb.w * w.x; acc[7].y += xb.w * w.y; acc[7].z += xb.w * w.z; acc[7].w += xb.w * w.w;
        }
        __syncthreads();
    }
    float4 bv = *(const float4*)(b512 + col0 + cg * 4);
#pragma unroll
    for (int r = 0; r < 8; r++) {
        float4 o;
        o.x = acc[r].x + bv.x; o.y = acc[r].y + bv.y;
        o.z = acc[r].z + bv.z; o.w = acc[r].w + bv.w;
        *(float4*)(out + (size_t)(row0 + rg * 8 + r) * 512 + col0 + cg * 4) = o;
    }
}

// ---------------- fused GATv2: logits + online softmax + aggregate ----------------
__global__ __launch_bounds__(256) void gat_fused_k(
    const float* __restrict__ xl, const int* __restrict__ rowptr,
    const int* __restrict__ srcs, const float* __restrict__ att,
    const float* __restrict__ bias, float* __restrict__ out, const int do_relu)
{
    const int lane = threadIdx.x & 63;
    const int n = blockIdx.x * 4 + (threadIdx.x >> 6);
    const float2 a = *(const float2*)(att + lane * 2);
    const float2 xd = *(const float2*)(xl + (size_t)n * 128 + lane * 2);
    const int i0 = rowptr[n], i1 = rowptr[n + 1];

    float m = -1e30f, den = 0.f, ax = 0.f, ay = 0.f;
    int sv = srcs[i0];
    for (int i = i0; i < i1; i++) {
        int snx = (i + 1 < i1) ? srcs[i + 1] : 0;   // prefetch next src id
        const float2 xs = *(const float2*)(xl + (size_t)sv * 128 + lane * 2);
        float u = xs.x + xd.x, v = xs.y + xd.y;
        u = (u > 0.f) ? u : 0.2f * u;
        v = (v > 0.f) ? v : 0.2f * v;
        float p = u * a.x + v * a.y;
        p += __shfl_xor(p, 1, 32);
        p += __shfl_xor(p, 2, 32);
        p += __shfl_xor(p, 4, 32);
        p += __shfl_xor(p, 8, 32);
        p += __shfl_xor(p, 16, 32);     // all 32 lanes of the head hold the logit
        float mn = fmaxf(m, p);
        float sc = __expf(m - mn);
        float w  = __expf(p - mn);
        den = den * sc + w;
        ax = ax * sc + w * xs.x;
        ay = ay * sc + w * xs.y;
        m = mn;
        sv = snx;
    }
    float2 bv = *(const float2*)(bias + lane * 2);
    float inv = 1.f / den;
    float ox = ax * inv + bv.x, oy = ay * inv + bv.y;
    if (do_relu) { ox = fmaxf(ox, 0.f); oy = fmaxf(oy, 0.f); }
    *(float2*)(out + (size_t)n * 128 + lane * 2) = make_float2(ox, oy);
}

// ---------------- LSTM weight packing (fallback path: Wih+Whh fused) ----------------
__global__ void build_wq_k(const float* __restrict__ Wih, const float* __restrict__ Whh,
                           float4* __restrict__ WQa, float4* __restrict__ WQb) {
    int id = blockIdx.x * 256 + threadIdx.x;    // 64*256 ids
    if (id < 64 * 256) {
        int kp = id >> 8, t = id & 255;
        int j1 = t, j2 = t + 256;
        WQa[id] = make_float4(Wih[(size_t)j1 * 128 + 2 * kp], Whh[(size_t)j1 * 128 + 2 * kp],
                              Wih[(size_t)j1 * 128 + 2 * kp + 1], Whh[(size_t)j1 * 128 + 2 * kp + 1]);
        WQb[id] = make_float4(Wih[(size_t)j2 * 128 + 2 * kp], Whh[(size_t)j2 * 128 + 2 * kp],
                              Wih[(size_t)j2 * 128 + 2 * kp + 1], Whh[(size_t)j2 * 128 + 2 * kp + 1]);
    }
}

// ---------------- big-ws packing: Wih^T + combined bias, Whh-only quad ----------------
__global__ void build_wiht_k(const float* __restrict__ Wih, const float* __restrict__ bih,
                             const float* __restrict__ bhh,
                             float* __restrict__ WihT, float* __restrict__ b512) {
    int id = blockIdx.x * 256 + threadIdx.x;    // 128*512 ids
    if (id < 128 * 512) {
        int k = id >> 9, j = id & 511;
        WihT[id] = Wih[(size_t)j * 128 + k];
        if (id < 512) b512[id] = bih[id] + bhh[id];
    }
}
// WQ4[kp*256+t] = (Whh[t][2kp], Whh[t][2kp+1], Whh[t+256][2kp], Whh[t+256][2kp+1])
__global__ void build_wq4_k(const float* __restrict__ Whh, float4* __restrict__ WQ4) {
    int id = blockIdx.x * 256 + threadIdx.x;    // 64*256 ids
    if (id < 64 * 256) {
        int kp = id >> 8, t = id & 255;
        WQ4[id] = make_float4(Whh[(size_t)t * 128 + 2 * kp],
                              Whh[(size_t)t * 128 + 2 * kp + 1],
                              Whh[(size_t)(t + 256) * 128 + 2 * kp],
                              Whh[(size_t)(t + 256) * 128 + 2 * kp + 1]);
    }
}

// ---- fallback kernel pieces (round-3 lstm) ----
#define LSTM_GROUP(buf, gbase)                                                     \
    _Pragma("unroll")                                                              \
    for (int i_ = 0; i_ < 4; i_++) {                                               \
        const int kp_ = (gbase) * 4 + i_;                                          \
        const float4 qa_ = buf[i_];                                                \
        const float4 qb_ = buf[4 + i_];                                            \
        _Pragma("unroll")                                                          \
        for (int n_ = 0; n_ < 4; n_++) {                                           \
            const float sx0_ = rdlane(xr[n_].x, kp_);                              \
            const float sh0_ = rdlane(hr[n_].x, kp_);                              \
            const float sx1_ = rdlane(xr[n_].y, kp_);                              \
            const float sh1_ = rdlane(hr[n_].y, kp_);                              \
            acc1[n_] += sx0_ * qa_.x + sh0_ * qa_.y + sx1_ * qa_.z + sh1_ * qa_.w; \
            acc2[n_] += sx0_ * qb_.x + sh0_ * qb_.y + sx1_ * qb_.z + sh1_ * qb_.w; \
        }                                                                          \
    }

__global__ __launch_bounds__(256, 1) void lstm_k(
    float* __restrict__ mu, const float4* __restrict__ WQa, const float4* __restrict__ WQb,
    const float* __restrict__ bih, const float* __restrict__ bhh,
    const float* __restrict__ h0, const float* __restrict__ c0,
    float* __restrict__ hT, float* __restrict__ cT)
{
    const int t = threadIdx.x, lane = t & 63;
    const int n0 = blockIdx.x * 4;
    __shared__ float hsh[4][128];
    __shared__ float gsh[4][512];
    const float b1 = bih[t] + bhh[t];
    const float b2 = bih[t + 256] + bhh[t + 256];
    float creg[2];
#pragma unroll
    for (int q = 0; q < 2; q++) {
        int id = t + 256 * q;
        creg[q] = c0[(size_t)(n0 + (id >> 7)) * 128 + (id & 127)];
    }
    for (int i = t; i < 512; i += 256)
        hsh[i >> 7][i & 127] = h0[(size_t)(n0 + (i >> 7)) * 128 + (i & 127)];

    const float4* pA = WQa + t;
    const float4* pB = WQb + t;

    float2 xr[4], xnx[4];
#pragma unroll
    for (int n = 0; n < 4; n++)
        xr[n] = *(const float2*)(mu + (size_t)n0 * 128 + n * 128 + lane * 2);
    __syncthreads();

    for (int s = 0; s < SQ; s++) {
        float* xrow = mu + ((size_t)s * NN + n0) * 128;
        float2 hr[4];
#pragma unroll
        for (int n = 0; n < 4; n++) hr[n] = *(const float2*)(&hsh[n][lane * 2]);

        float4 bufA[8], bufB[8];
#pragma unroll
        for (int i = 0; i < 4; i++) { bufA[i] = pA[i * 256]; bufA[4 + i] = pB[i * 256]; }

        if (s + 1 < SQ) {
            const float* xrow2 = mu + ((size_t)(s + 1) * NN + n0) * 128;
#pragma unroll
            for (int n = 0; n < 4; n++) xnx[n] = *(const float2*)(xrow2 + n * 128 + lane * 2);
        }

        float acc1[4], acc2[4];
#pragma unroll
        for (int n = 0; n < 4; n++) { acc1[n] = b1; acc2[n] = b2; }

        for (int g = 0; g < 16; g += 2) {
#pragma unroll
            for (int i = 0; i < 4; i++) {
                bufB[i]     = pA[((g + 1) * 4 + i) * 256];
                bufB[4 + i] = pB[((g + 1) * 4 + i) * 256];
            }
            LSTM_GROUP(bufA, g)
            if (g < 14) {
#pragma unroll
                for (int i = 0; i < 4; i++) {
                    bufA[i]     = pA[((g + 2) * 4 + i) * 256];
                    bufA[4 + i] = pB[((g + 2) * 4 + i) * 256];
                }
            }
            LSTM_GROUP(bufB, g + 1)
        }

#pragma unroll
        for (int n = 0; n < 4; n++) { gsh[n][t] = acc1[n]; gsh[n][t + 256] = acc2[n]; }
        __syncthreads();
#pragma unroll
        for (int q = 0; q < 2; q++) {
            int id = t + 256 * q;
            int n = id >> 7, e = id & 127;
            float iv = gsh[n][e], fv = gsh[n][128 + e];
            float gv = gsh[n][256 + e], ov = gsh[n][384 + e];
            float c = sigm(fv) * creg[q] + sigm(iv) * tanh_f(gv);
            float h = sigm(ov) * tanh_f(c);
            creg[q] = c;
            hsh[n][e] = h;
            xrow[n * 128 + e] = h;
            if (s == SQ - 1) {
                hT[(size_t)(n0 + n) * 128 + e] = h;
                cT[(size_t)(n0 + n) * 128 + e] = c;
            }
        }
#pragma unroll
        for (int n = 0; n < 4; n++) xr[n] = xnx[n];
        __syncthreads();
    }
}

// ---------------- recurrent-only LSTM (big-ws path) ----------------
// g = xC (precomputed x@Wih^T + biases) + h@Whh^T.  Per kp: 1 float4 load,
// 8 readlane, 16 FMA — half the instructions of the fused version.
#define LSTM2_GROUP(buf, gbase)                                \
    _Pragma("unroll")                                          \
    for (int i_ = 0; i_ < 8; i_++) {                           \
        const int kp_ = (gbase) * 8 + i_;                      \
        const float4 q_ = buf[i_];                             \
        _Pragma("unroll")                                      \
        for (int n_ = 0; n_ < 4; n_++) {                       \
            const float sh0_ = rdlane(hr[n_].x, kp_);          \
            const float sh1_ = rdlane(hr[n_].y, kp_);          \
            acc1[n_] += sh0_ * q_.x + sh1_ * q_.y;             \
            acc2[n_] += sh0_ * q_.z + sh1_ * q_.w;             \
        }                                                      \
    }

__global__ __launch_bounds__(256, 1) void lstm2_k(
    float* __restrict__ mu, const float* __restrict__ xC,
    const float4* __restrict__ WQ4,
    const float* __restrict__ h0, const float* __restrict__ c0,
    float* __restrict__ hT, float* __restrict__ cT)
{
    const int t = threadIdx.x, lane = t & 63;
    const int n0 = blockIdx.x * 4;
    __shared__ float hsh[4][128];
    __shared__ float gsh[4][512];
    float creg[2];
#pragma unroll
    for (int q = 0; q < 2; q++) {
        int id = t + 256 * q;
        creg[q] = c0[(size_t)(n0 + (id >> 7)) * 128 + (id & 127)];
    }
    for (int i = t; i < 512; i += 256)
        hsh[i >> 7][i & 127] = h0[(size_t)(n0 + (i >> 7)) * 128 + (i & 127)];

    const float4* pW = WQ4 + t;

    // prefetch step-0 gate preacts
    float g1[4], g2[4], g1n[4], g2n[4];
#pragma unroll
    for (int n = 0; n < 4; n++) {
        const float* gb = xC + (size_t)(n0 + n) * 512;
        g1[n] = gb[t]; g2[n] = gb[t + 256];
    }
    __syncthreads();

    for (int s = 0; s < SQ; s++) {
        float* xrow = mu + ((size_t)s * NN + n0) * 128;
        float2 hr[4];
#pragma unroll
        for (int n = 0; n < 4; n++) hr[n] = *(const float2*)(&hsh[n][lane * 2]);

        float4 bufA[8], bufB[8];
#pragma unroll
        for (int i = 0; i < 8; i++) bufA[i] = pW[i * 256];

        if (s + 1 < SQ) {
#pragma unroll
            for (int n = 0; n < 4; n++) {
                const float* gb = xC + ((size_t)(s + 1) * NN + n0 + n) * 512;
                g1n[n] = gb[t]; g2n[n] = gb[t + 256];
            }
        }

        float acc1[4], acc2[4];
#pragma unroll
        for (int n = 0; n < 4; n++) { acc1[n] = g1[n]; acc2[n] = g2[n]; }

        for (int g = 0; g < 8; g += 2) {
#pragma unroll
            for (int i = 0; i < 8; i++) bufB[i] = pW[((g + 1) * 8 + i) * 256];
            LSTM2_GROUP(bufA, g)
            if (g < 6) {
#pragma unroll
                for (int i = 0; i < 8; i++) bufA[i] = pW[((g + 2) * 8 + i) * 256];
            }
            LSTM2_GROUP(bufB, g + 1)
        }

#pragma unroll
        for (int n = 0; n < 4; n++) { gsh[n][t] = acc1[n]; gsh[n][t + 256] = acc2[n]; }
        __syncthreads();
#pragma unroll
        for (int q = 0; q < 2; q++) {
            int id = t + 256 * q;
            int n = id >> 7, e = id & 127;
            float iv = gsh[n][e], fv = gsh[n][128 + e];
            float gv = gsh[n][256 + e], ov = gsh[n][384 + e];
            float c = sigm(fv) * creg[q] + sigm(iv) * tanh_f(gv);
            float h = sigm(ov) * tanh_f(c);
            creg[q] = c;
            hsh[n][e] = h;
            xrow[n * 128 + e] = h;        // mu <- h_t (scan output)
            if (s == SQ - 1) {
                hT[(size_t)(n0 + n) * 128 + e] = h;
                cT[(size_t)(n0 + n) * 128 + e] = c;
            }
        }
#pragma unroll
        for (int n = 0; n < 4; n++) { g1[n] = g1n[n]; g2[n] = g2n[n]; }
        __syncthreads();
    }
}

// ---------------- head: meanpool -> gs -> A[s] = sum_j relu(gs)*w5[j] ----------------
__global__ __launch_bounds__(256) void meanpool_gs_k(
    const float* __restrict__ mu, const float* __restrict__ W6,
    const float* __restrict__ b6, const float* __restrict__ w5,
    float* __restrict__ A)
{
    const int s = blockIdx.x, t = threadIdx.x;
    const int ch = t & 127, half = t >> 7;
    __shared__ float mp[128];
    __shared__ float red[256];
    float acc = 0.f;
    for (int n = half * 500; n < (half + 1) * 500; n++)
        acc += mu[((size_t)s * NN + n) * 128 + ch];
    red[t] = acc;
    __syncthreads();
    if (t < 128) mp[t] = (red[t] + red[t + 128]) * 0.001f;
    __syncthreads();
    float g = 0.f;
    if (t < 128) {
        g = b6[t];
        for (int k = 0; k < 128; k++) g += mp[k] * W6[(size_t)k * 128 + t];
        g = fmaxf(g, 0.f) * w5[t];
    }
    red[t] = g;
    __syncthreads();
    for (int o = 128; o > 0; o >>= 1) {
        if (t < o) red[t] += red[t + o];
        __syncthreads();
    }
    if (t == 0) A[s] = red[0];
}

// ---------------- head: logit2[row] = A[s] + b5 + sum_j relu(la[row][j]) * w5[128+j] ----------------
__global__ __launch_bounds__(256) void rowdot_k(
    const float* __restrict__ la, const float* __restrict__ w5,
    const float* __restrict__ b5, const float* __restrict__ A,
    float* __restrict__ out)
{
    const int lane = threadIdx.x & 63;
    const int row = blockIdx.x * 4 + (threadIdx.x >> 6);
    float2 v = *(const float2*)(la + (size_t)row * 128 + lane * 2);
    float2 w = *(const float2*)(w5 + 128 + lane * 2);
    float x = fmaxf(v.x, 0.f) * w.x + fmaxf(v.y, 0.f) * w.y;
#pragma unroll
    for (int o = 32; o; o >>= 1) x += __shfl_down(x, o);
    if (lane == 0) out[row] = x + A[row / NN] + b5[0];
}

// ---------------- masked softmax per sequence step ----------------
__device__ __forceinline__ bool reach_at(const void* reach, int mode, int idx) {
    if (mode == 0) return ((const int*)reach)[idx] != 0;
    if (mode == 1) return ((const unsigned char*)reach)[idx] != 0;
    return ((const float*)reach)[idx] != 0.f;
}
__global__ __launch_bounds__(256) void softmax_k(
    const float* __restrict__ lg, const void* __restrict__ reach,
    const int* __restrict__ mode, float* __restrict__ prob)
{
    const int s = blockIdx.x, t = threadIdx.x;
    const int m = *mode;
    __shared__ float red[256];
    float mx = -1e30f;
    for (int i = t; i < NN; i += 256) {
        int idx = s * NN + i;
        if (reach_at(reach, m, idx)) mx = fmaxf(mx, lg[idx]);
    }
    red[t] = mx;
    __syncthreads();
    for (int o = 128; o; o >>= 1) {
        if (t < o) red[t] = fmaxf(red[t], red[t + o]);
        __syncthreads();
    }
    mx = red[0];
    __syncthreads();
    float sum = 0.f;
    for (int i = t; i < NN; i += 256) {
        int idx = s * NN + i;
        float v = reach_at(reach, m, idx) ? __expf(lg[idx] - mx) : 0.f;
        prob[idx] = v;
        sum += v;
    }
    red[t] = sum;
    __syncthreads();
    for (int o = 128; o; o >>= 1) {
        if (t < o) red[t] += red[t + o];
        __syncthreads();
    }
    float inv = 1.f / red[0];
    for (int i = t; i < NN; i += 256) prob[s * NN + i] *= inv;
}

// ---------------- driver ----------------
extern "C" void kernel_launch(void* const* d_in, const int* in_sizes, int n_in,
                              void* d_out, int out_size, void* d_ws, size_t ws_size,
                              hipStream_t stream) {
    const float* nfm   = (const float*)d_in[0];
    const int*   ei    = (const int*)d_in[1];
    const void*  reach = d_in[2];
    const float* h0    = (const float*)d_in[3];
    const float* c0    = (const float*)d_in[4];
    const float* W1    = (const float*)d_in[5];
    const float* b1    = (const float*)d_in[6];
    const float* att1  = (const float*)d_in[7];
    const float* bias1 = (const float*)d_in[8];
    const float* Wl    = (const float*)d_in[9];
    const float* bl    = (const float*)d_in[10];
    const float* attl  = (const float*)d_in[11];
    const float* biasl = (const float*)d_in[12];
    const float* Wih   = (const float*)d_in[13];
    const float* Whh   = (const float*)d_in[14];
    const float* bih   = (const float*)d_in[15];
    const float* bhh   = (const float*)d_in[16];
    const float* W6    = (const float*)d_in[17];
    const float* b6    = (const float*)d_in[18];
    const float* W7    = (const float*)d_in[19];
    const float* b7    = (const float*)d_in[20];
    const float* w5    = (const float*)d_in[21];
    const float* b5    = (const float*)d_in[22];

    char* ws = (char*)d_ws;
    const bool bigws = (ws_size >= WS2_NEED);

    float*  xA     = (float*)(ws + WS_XA);
    float*  xB     = (float*)(ws + WS_XB);
    int*    rowptr = (int*)(ws + WS_ROWPTR);
    int*    cursor = (int*)(ws + WS_CURSOR);
    int*    srcs   = (int*)(ws + WS_SRCS);
    int*    incl   = (int*)(ws + WS_INCL);
    int*    bsum   = (int*)(ws + WS_BSUM);
    int*    boff   = (int*)(ws + WS_BOFF);
    int*    modep  = bigws ? (int*)(ws + WS2_MODE)   : (int*)(ws + WS_MODE);
    float*  As     = bigws ? (float*)(ws + WS2_AS)   : (float*)(ws + WS_AS);
    float*  logit2 = bigws ? (float*)(ws + WS2_LOGIT2) : (float*)(ws + WS_LOGIT2);
    // big-ws extras
    float*  xC     = (float*)(ws + WS2_XC);
    float4* WQ4    = (float4*)(ws + WS2_WQ4);
    float*  WihT   = (float*)(ws + WS2_WIHT);
    float*  b512   = (float*)(ws + WS2_B512);
    // fallback extras
    float4* WQa    = (float4*)(ws + WS_WQA);
    float4* WQb    = (float4*)(ws + WS_WQB);

    float* prob = (float*)d_out;
    float* hT   = (float*)d_out + 64000;
    float* cT   = (float*)d_out + 192000;

    // setup
    detect_mode_k<<<1, 256, 0, stream>>>((const unsigned char*)reach, modep);
    zero_ints_k<<<250, 256, 0, stream>>>(cursor, NT);
    hist_k<<<2250, 256, 0, stream>>>(ei, cursor);
    scan1_k<<<250, 256, 0, stream>>>(cursor, incl, bsum);
    scan2_k<<<1, 256, 0, stream>>>(bsum, boff);
    scan3_k<<<250, 256, 0, stream>>>(incl, boff, rowptr, cursor);
    fill_k<<<2250, 256, 0, stream>>>(ei, cursor, srcs);
    if (bigws) {
        build_wiht_k<<<256, 256, 0, stream>>>(Wih, bih, bhh, WihT, b512);
        build_wq4_k<<<64, 256, 0, stream>>>(Whh, WQ4);
    } else {
        build_wq_k<<<64, 256, 0, stream>>>(Wih, Whh, WQa, WQb);
    }

    // 5 GATv2 layers: gemm (x->xB), fused logits+softmax+aggregate (xB->xA)
    for (int l = 0; l < 5; l++) {
        if (l == 0)
            gemm2<64><<<1000, 256, 0, stream>>>(nfm, W1, b1, xB);
        else
            gemm2<128><<<1000, 256, 0, stream>>>(xA, Wl + (size_t)(l - 1) * 128 * 128,
                                                 bl + (l - 1) * 128, xB);
        const float* att  = (l == 0) ? att1  : attl  + (l - 1) * 128;
        const float* bias = (l == 0) ? bias1 : biasl + (l - 1) * 128;
        gat_fused_k<<<16000, 256, 0, stream>>>(xB, rowptr, srcs, att, bias, xA,
                                               (l < 4) ? 1 : 0);
    }

    // LSTM
    if (bigws) {
        // precompute all gate x-preactivations: xC = mu @ Wih^T + (bih+bhh)
        gemm_proj<<<dim3(1000, 4), 256, 0, stream>>>(xA, WihT, b512, xC);
        lstm2_k<<<250, 256, 0, stream>>>(xA, xC, WQ4, h0, c0, hT, cT);
    } else {
        lstm_k<<<250, 256, 0, stream>>>(xA, WQa, WQb, bih, bhh, h0, c0, hT, cT);
    }

    // head
    meanpool_gs_k<<<64, 256, 0, stream>>>(xA, W6, b6, w5, As);
    gemm2<128><<<1000, 256, 0, stream>>>(xA, W7, b7, xB);      // la
    rowdot_k<<<16000, 256, 0, stream>>>(xB, w5, b5, As, logit2);
    softmax_k<<<64, 256, 0, stream>>>(logit2, reach, modep, prob);
}

// Round 5
// 1119.221 us; speedup vs baseline: 2.8820x; 1.0074x over previous
//
#include <hip/hip_runtime.h>
#include <hip/hip_bf16.h>

// ---------------- problem constants ----------------
#define SQ   64        // seq len
#define NN   1000      // nodes per graph
#define NT   64000     // total nodes
#define EE   128       // emb dim
#define EG   512000    // graph edges (no self loops)
#define ET   576000    // edges + self loops

// ---------------- workspace layout (bytes) ----------------
// common / fallback region (<71 MB)
#define WS_XA      0ull          // 32,768,000  float[NT*128]  x ping (mu lives here)
#define WS_XB      33000000ull   // 32,768,000  float[NT*128]  x pong (xl / la)
#define WS_ROWPTR  66000000ull   // 256,004     int[NT+1]
#define WS_CURSOR  66300000ull   // 256,000     int[NT]   (also used as deg)
#define WS_SRCS    66600000ull   // 2,304,000   int[ET]  (src node id, dst-grouped)
#define WS_INCL    69000000ull   // 256,000     int[NT]
#define WS_BSUM    69300000ull   // 1,024       int[250]
#define WS_BOFF    69302048ull   // 1,024       int[250]
#define WS_MODE    69304096ull   // 4           int
#define WS_WQA     70000000ull   // 262,144     float4[64*256]  (fallback LSTM)
#define WS_WQB     70262144ull   // 262,144     float4[64*256]  (fallback LSTM)
#define WS_AS      70600000ull   // 256         float[64]
#define WS_LOGIT2  70700000ull   // 256,000     float[NT]
// big-ws region: xC aliases xB + CSR (disjoint lifetimes)
#define WS2_XC     33000000ull   // 131,072,000 float[NT*512]  gate preacts (x part)
#define WS2_WQ4    164100000ull  // 262,144     float4[64*256] packed Whh
#define WS2_WIHT   164400000ull  // 262,144     float[128*512] Wih^T
#define WS2_B512   164700000ull  // 2,048       float[512]     bih+bhh
#define WS2_MODE   164710000ull  // 4
#define WS2_AS     164720000ull  // 256
#define WS2_LOGIT2 164800000ull  // 256,000
#define WS2_NEED   165100000ull

// ---------------- helpers ----------------
__device__ __forceinline__ float rdlane(float v, int l) {
    return __int_as_float(__builtin_amdgcn_readlane(__float_as_int(v), l));
}
__device__ __forceinline__ float sigm(float x) { return 1.0f / (1.0f + __expf(-x)); }
__device__ __forceinline__ float tanh_f(float x) {
    x = fminf(fmaxf(x, -30.0f), 30.0f);
    float e = __expf(2.0f * x);
    return (e - 1.0f) / (e + 1.0f);
}

// ---------------- reachable dtype detection ----------------
__global__ void detect_mode_k(const unsigned char* __restrict__ p, int* __restrict__ mode) {
    __shared__ int f0, f3;
    const int t = threadIdx.x;
    if (t == 0) { f0 = 0; f3 = 0; }
    __syncthreads();
    int l0 = 0, l3 = 0;
    for (int i = t; i < 16000; i += 256) {
        if (p[4 * i])     l0 = 1;
        if (p[4 * i + 3]) l3 = 1;
    }
    if (l0) atomicOr(&f0, 1);
    if (l3) atomicOr(&f3, 1);
    __syncthreads();
    if (t == 0) {
        int m;
        if (f0 && f3)      m = 1;  // bool bytes
        else if (f0)       m = 0;  // int32
        else               m = 2;  // float32
        *mode = m;
    }
}

// ---------------- CSR construction (dst-grouped src list; built once) ----------------
__global__ void zero_ints_k(int* __restrict__ p, int n) {
    int i = blockIdx.x * 256 + threadIdx.x;
    if (i < n) p[i] = 0;
}
__global__ void hist_k(const int* __restrict__ ei, int* __restrict__ deg) {
    int e = blockIdx.x * 256 + threadIdx.x;
    if (e < ET) {
        int d = (e < EG) ? ei[EG + e] : (e - EG);
        atomicAdd(deg + d, 1);
    }
}
__global__ void scan1_k(const int* __restrict__ deg, int* __restrict__ incl, int* __restrict__ bsum) {
    __shared__ int sh[256];
    const int t = threadIdx.x;
    const int i = blockIdx.x * 256 + t;
    sh[t] = deg[i];
    __syncthreads();
    for (int o = 1; o < 256; o <<= 1) {
        int add = (t >= o) ? sh[t - o] : 0;
        __syncthreads();
        sh[t] += add;
        __syncthreads();
    }
    incl[i] = sh[t];
    if (t == 255) bsum[blockIdx.x] = sh[255];
}
__global__ void scan2_k(const int* __restrict__ bsum, int* __restrict__ boff) {
    __shared__ int sh[256];
    const int t = threadIdx.x;
    int v = (t < 250) ? bsum[t] : 0;
    sh[t] = v;
    __syncthreads();
    for (int o = 1; o < 256; o <<= 1) {
        int add = (t >= o) ? sh[t - o] : 0;
        __syncthreads();
        sh[t] += add;
        __syncthreads();
    }
    if (t < 250) boff[t] = sh[t] - v;   // exclusive
}
__global__ void scan3_k(const int* __restrict__ incl, const int* __restrict__ boff,
                        int* __restrict__ rowptr, int* __restrict__ cursor_deg) {
    const int i = blockIdx.x * 256 + threadIdx.x;
    int total = incl[i] + boff[blockIdx.x];
    int excl  = total - cursor_deg[i];
    rowptr[i] = excl;
    cursor_deg[i] = excl;                 // becomes fill cursor
    if (i == NT - 1) rowptr[NT] = total;
}
__global__ void fill_k(const int* __restrict__ ei, int* __restrict__ cursor, int* __restrict__ srcs) {
    int e = blockIdx.x * 256 + threadIdx.x;
    if (e < ET) {
        int s_, d_;
        if (e < EG) { s_ = ei[e]; d_ = ei[EG + e]; }
        else        { s_ = e - EG; d_ = s_; }
        int p = atomicAdd(cursor + d_, 1);
        srcs[p] = s_;
    }
}

// ---------------- fp32 GEMM v3: out[M x 128] = x[M x K] @ W[K x 128] + b ----------------
// 128x128 block tile, 8x8 per thread: 0.5 B LDS per FMA -> FMA-bound (was 1.5 B, LDS-bound).
template <int K>
__global__ __launch_bounds__(256) void gemm3(
    const float* __restrict__ x, const float* __restrict__ W,
    const float* __restrict__ b, float* __restrict__ out)
{
    __shared__ float Wsh[64 * 128];     // [k][col]
    __shared__ float xT[64][132];       // [k][row], pad keeps b128 align, breaks strides
    const int t = threadIdx.x;
    const int row0 = blockIdx.x * 128;
    const int cg = t & 15;   // cols cg*8 .. +7
    const int rg = t >> 4;   // rows rg*8 .. +7
    float4 acc[8][2];
#pragma unroll
    for (int r = 0; r < 8; r++) {
        acc[r][0] = make_float4(0.f, 0.f, 0.f, 0.f);
        acc[r][1] = make_float4(0.f, 0.f, 0.f, 0.f);
    }

    for (int k0 = 0; k0 < K; k0 += 64) {
        for (int i = t * 4; i < 64 * 128; i += 1024)
            *(float4*)(Wsh + i) = *(const float4*)(W + (size_t)k0 * 128 + i);
        for (int i = t * 4; i < 128 * 64; i += 1024) {
            int r = i >> 6, k = i & 63;
            float4 v = *(const float4*)(x + (size_t)(row0 + r) * K + k0 + k);
            xT[k + 0][r] = v.x;
            xT[k + 1][r] = v.y;
            xT[k + 2][r] = v.z;
            xT[k + 3][r] = v.w;
        }
        __syncthreads();
#pragma unroll 2
        for (int k = 0; k < 64; k++) {
            float4 w0 = *(const float4*)(Wsh + k * 128 + cg * 8);
            float4 w1 = *(const float4*)(Wsh + k * 128 + cg * 8 + 4);
            float4 x0 = *(const float4*)(&xT[k][rg * 8]);
            float4 x1 = *(const float4*)(&xT[k][rg * 8 + 4]);
            float xv[8] = {x0.x, x0.y, x0.z, x0.w, x1.x, x1.y, x1.z, x1.w};
#pragma unroll
            for (int r = 0; r < 8; r++) {
                acc[r][0].x += xv[r] * w0.x; acc[r][0].y += xv[r] * w0.y;
                acc[r][0].z += xv[r] * w0.z; acc[r][0].w += xv[r] * w0.w;
                acc[r][1].x += xv[r] * w1.x; acc[r][1].y += xv[r] * w1.y;
                acc[r][1].z += xv[r] * w1.z; acc[r][1].w += xv[r] * w1.w;
            }
        }
        __syncthreads();
    }
    float4 bv0 = *(const float4*)(b + cg * 8);
    float4 bv1 = *(const float4*)(b + cg * 8 + 4);
#pragma unroll
    for (int r = 0; r < 8; r++) {
        float4 o0, o1;
        o0.x = acc[r][0].x + bv0.x; o0.y = acc[r][0].y + bv0.y;
        o0.z = acc[r][0].z + bv0.z; o0.w = acc[r][0].w + bv0.w;
        o1.x = acc[r][1].x + bv1.x; o1.y = acc[r][1].y + bv1.y;
        o1.z = acc[r][1].z + bv1.z; o1.w = acc[r][1].w + bv1.w;
        float* op = out + (size_t)(row0 + rg * 8 + r) * 128 + cg * 8;
        *(float4*)(op) = o0;
        *(float4*)(op + 4) = o1;
    }
}

// ---------------- fp32 GEMM v3 (projection): out[M x 512] = x[M x 128] @ WT[128 x 512] + b512 ----------------
__global__ __launch_bounds__(256) void gemm_proj3(
    const float* __restrict__ x, const float* __restrict__ WT,
    const float* __restrict__ b512, float* __restrict__ out)
{
    __shared__ float Wsh[64 * 128];
    __shared__ float xT[64][132];
    const int t = threadIdx.x;
    const int row0 = blockIdx.x * 128;
    const int col0 = blockIdx.y * 128;
    const int cg = t & 15;
    const int rg = t >> 4;
    float4 acc[8][2];
#pragma unroll
    for (int r = 0; r < 8; r++) {
        acc[r][0] = make_float4(0.f, 0.f, 0.f, 0.f);
        acc[r][1] = make_float4(0.f, 0.f, 0.f, 0.f);
    }

    for (int k0 = 0; k0 < 128; k0 += 64) {
        for (int i = t * 4; i < 64 * 128; i += 1024) {
            int k = i >> 7, c = i & 127;
            *(float4*)(Wsh + i) = *(const float4*)(WT + (size_t)(k0 + k) * 512 + col0 + c);
        }
        for (int i = t * 4; i < 128 * 64; i += 1024) {
            int r = i >> 6, k = i & 63;
            float4 v = *(const float4*)(x + (size_t)(row0 + r) * 128 + k0 + k);
            xT[k + 0][r] = v.x;
            xT[k + 1][r] = v.y;
            xT[k + 2][r] = v.z;
            xT[k + 3][r] = v.w;
        }
        __syncthreads();
#pragma unroll 2
        for (int k = 0; k < 64; k++) {
            float4 w0 = *(const float4*)(Wsh + k * 128 + cg * 8);
            float4 w1 = *(const float4*)(Wsh + k * 128 + cg * 8 + 4);
            float4 x0 = *(const float4*)(&xT[k][rg * 8]);
            float4 x1 = *(const float4*)(&xT[k][rg * 8 + 4]);
            float xv[8] = {x0.x, x0.y, x0.z, x0.w, x1.x, x1.y, x1.z, x1.w};
#pragma unroll
            for (int r = 0; r < 8; r++) {
                acc[r][0].x += xv[r] * w0.x; acc[r][0].y += xv[r] * w0.y;
                acc[r][0].z += xv[r] * w0.z; acc[r][0].w += xv[r] * w0.w;
                acc[r][1].x += xv[r] * w1.x; acc[r][1].y += xv[r] * w1.y;
                acc[r][1].z += xv[r] * w1.z; acc[r][1].w += xv[r] * w1.w;
            }
        }
        __syncthreads();
    }
    float4 bv0 = *(const float4*)(b512 + col0 + cg * 8);
    float4 bv1 = *(const float4*)(b512 + col0 + cg * 8 + 4);
#pragma unroll
    for (int r = 0; r < 8; r++) {
        float4 o0, o1;
        o0.x = acc[r][0].x + bv0.x; o0.y = acc[r][0].y + bv0.y;
        o0.z = acc[r][0].z + bv0.z; o0.w = acc[r][0].w + bv0.w;
        o1.x = acc[r][1].x + bv1.x; o1.y = acc[r][1].y + bv1.y;
        o1.z = acc[r][1].z + bv1.z; o1.w = acc[r][1].w + bv1.w;
        float* op = out + (size_t)(row0 + rg * 8 + r) * 512 + col0 + cg * 8;
        *(float4*)(op) = o0;
        *(float4*)(op + 4) = o1;
    }
}

// ---------------- fused GATv2: logits + online softmax + aggregate ----------------
// XCD-aware swizzle: blocks map to XCD blockIdx%8 (round-robin dispatch heuristic);
// graph s is processed only by blocks with blockIdx%8 == s%8, so its 512 KB xl
// working set stays resident in that XCD's 4 MB L2 (8 graphs/XCD = 4 MB).
// Swizzle only affects locality, never correctness.
__global__ __launch_bounds__(256) void gat_fused_k(
    const float* __restrict__ xl, const int* __restrict__ rowptr,
    const int* __restrict__ srcs, const float* __restrict__ att,
    const float* __restrict__ bias, float* __restrict__ out, const int do_relu)
{
    const int lane = threadIdx.x & 63;
    const int b = blockIdx.x;
    const int g = b & 7;
    const int j = b >> 3;           // 0..1999
    const int jq = j / 250;         // 0..7
    const int jj = j - jq * 250;    // 0..249
    const int s = g + 8 * jq;       // graph id, s%8 == g
    const int n = s * NN + jj * 4 + (threadIdx.x >> 6);

    const float2 a = *(const float2*)(att + lane * 2);
    const float2 xd = *(const float2*)(xl + (size_t)n * 128 + lane * 2);
    const int i0 = rowptr[n], i1 = rowptr[n + 1];

    float m = -1e30f, den = 0.f, ax = 0.f, ay = 0.f;
    int sv = srcs[i0];
    for (int i = i0; i < i1; i++) {
        int snx = (i + 1 < i1) ? srcs[i + 1] : 0;   // prefetch next src id
        const float2 xs = *(const float2*)(xl + (size_t)sv * 128 + lane * 2);
        float u = xs.x + xd.x, v = xs.y + xd.y;
        u = (u > 0.f) ? u : 0.2f * u;
        v = (v > 0.f) ? v : 0.2f * v;
        float p = u * a.x + v * a.y;
        p += __shfl_xor(p, 1, 32);
        p += __shfl_xor(p, 2, 32);
        p += __shfl_xor(p, 4, 32);
        p += __shfl_xor(p, 8, 32);
        p += __shfl_xor(p, 16, 32);     // all 32 lanes of the head hold the logit
        float mn = fmaxf(m, p);
        float sc = __expf(m - mn);
        float w  = __expf(p - mn);
        den = den * sc + w;
        ax = ax * sc + w * xs.x;
        ay = ay * sc + w * xs.y;
        m = mn;
        sv = snx;
    }
    float2 bv = *(const float2*)(bias + lane * 2);
    float inv = 1.f / den;
    float ox = ax * inv + bv.x, oy = ay * inv + bv.y;
    if (do_relu) { ox = fmaxf(ox, 0.f); oy = fmaxf(oy, 0.f); }
    *(float2*)(out + (size_t)n * 128 + lane * 2) = make_float2(ox, oy);
}

// ---------------- LSTM weight packing (fallback path: Wih+Whh fused) ----------------
__global__ void build_wq_k(const float* __restrict__ Wih, const float* __restrict__ Whh,
                           float4* __restrict__ WQa, float4* __restrict__ WQb) {
    int id = blockIdx.x * 256 + threadIdx.x;    // 64*256 ids
    if (id < 64 * 256) {
        int kp = id >> 8, t = id & 255;
        int j1 = t, j2 = t + 256;
        WQa[id] = make_float4(Wih[(size_t)j1 * 128 + 2 * kp], Whh[(size_t)j1 * 128 + 2 * kp],
                              Wih[(size_t)j1 * 128 + 2 * kp + 1], Whh[(size_t)j1 * 128 + 2 * kp + 1]);
        WQb[id] = make_float4(Wih[(size_t)j2 * 128 + 2 * kp], Whh[(size_t)j2 * 128 + 2 * kp],
                              Wih[(size_t)j2 * 128 + 2 * kp + 1], Whh[(size_t)j2 * 128 + 2 * kp + 1]);
    }
}

// ---------------- big-ws packing: Wih^T + combined bias, Whh-only quad ----------------
__global__ void build_wiht_k(const float* __restrict__ Wih, const float* __restrict__ bih,
                             const float* __restrict__ bhh,
                             float* __restrict__ WihT, float* __restrict__ b512) {
    int id = blockIdx.x * 256 + threadIdx.x;    // 128*512 ids
    if (id < 128 * 512) {
        int k = id >> 9, j = id & 511;
        WihT[id] = Wih[(size_t)j * 128 + k];
        if (id < 512) b512[id] = bih[id] + bhh[id];
    }
}
// WQ4[kp*256+t] = (Whh[t][2kp], Whh[t][2kp+1], Whh[t+256][2kp], Whh[t+256][2kp+1])
__global__ void build_wq4_k(const float* __restrict__ Whh, float4* __restrict__ WQ4) {
    int id = blockIdx.x * 256 + threadIdx.x;    // 64*256 ids
    if (id < 64 * 256) {
        int kp = id >> 8, t = id & 255;
        WQ4[id] = make_float4(Whh[(size_t)t * 128 + 2 * kp],
                              Whh[(size_t)t * 128 + 2 * kp + 1],
                              Whh[(size_t)(t + 256) * 128 + 2 * kp],
                              Whh[(size_t)(t + 256) * 128 + 2 * kp + 1]);
    }
}

// ---- fallback kernel (round-3 lstm, small-ws only) ----
#define LSTM_GROUP(buf, gbase)                                                     \
    _Pragma("unroll")                                                              \
    for (int i_ = 0; i_ < 4; i_++) {                                               \
        const int kp_ = (gbase) * 4 + i_;                                          \
        const float4 qa_ = buf[i_];                                                \
        const float4 qb_ = buf[4 + i_];                                            \
        _Pragma("unroll")                                                          \
        for (int n_ = 0; n_ < 4; n_++) {                                           \
            const float sx0_ = rdlane(xr[n_].x, kp_);                              \
            const float sh0_ = rdlane(hr[n_].x, kp_);                              \
            const float sx1_ = rdlane(xr[n_].y, kp_);                              \
            const float sh1_ = rdlane(hr[n_].y, kp_);                              \
            acc1[n_] += sx0_ * qa_.x + sh0_ * qa_.y + sx1_ * qa_.z + sh1_ * qa_.w; \
            acc2[n_] += sx0_ * qb_.x + sh0_ * qb_.y + sx1_ * qb_.z + sh1_ * qb_.w; \
        }                                                                          \
    }

__global__ __launch_bounds__(256, 1) void lstm_k(
    float* __restrict__ mu, const float4* __restrict__ WQa, const float4* __restrict__ WQb,
    const float* __restrict__ bih, const float* __restrict__ bhh,
    const float* __restrict__ h0, const float* __restrict__ c0,
    float* __restrict__ hT, float* __restrict__ cT)
{
    const int t = threadIdx.x, lane = t & 63;
    const int n0 = blockIdx.x * 4;
    __shared__ float hsh[4][128];
    __shared__ float gsh[4][512];
    const float b1 = bih[t] + bhh[t];
    const float b2 = bih[t + 256] + bhh[t + 256];
    float creg[2];
#pragma unroll
    for (int q = 0; q < 2; q++) {
        int id = t + 256 * q;
        creg[q] = c0[(size_t)(n0 + (id >> 7)) * 128 + (id & 127)];
    }
    for (int i = t; i < 512; i += 256)
        hsh[i >> 7][i & 127] = h0[(size_t)(n0 + (i >> 7)) * 128 + (i & 127)];

    const float4* pA = WQa + t;
    const float4* pB = WQb + t;

    float2 xr[4], xnx[4];
#pragma unroll
    for (int n = 0; n < 4; n++)
        xr[n] = *(const float2*)(mu + (size_t)n0 * 128 + n * 128 + lane * 2);
    __syncthreads();

    for (int s = 0; s < SQ; s++) {
        float* xrow = mu + ((size_t)s * NN + n0) * 128;
        float2 hr[4];
#pragma unroll
        for (int n = 0; n < 4; n++) hr[n] = *(const float2*)(&hsh[n][lane * 2]);

        float4 bufA[8], bufB[8];
#pragma unroll
        for (int i = 0; i < 4; i++) { bufA[i] = pA[i * 256]; bufA[4 + i] = pB[i * 256]; }

        if (s + 1 < SQ) {
            const float* xrow2 = mu + ((size_t)(s + 1) * NN + n0) * 128;
#pragma unroll
            for (int n = 0; n < 4; n++) xnx[n] = *(const float2*)(xrow2 + n * 128 + lane * 2);
        }

        float acc1[4], acc2[4];
#pragma unroll
        for (int n = 0; n < 4; n++) { acc1[n] = b1; acc2[n] = b2; }

        for (int g = 0; g < 16; g += 2) {
#pragma unroll
            for (int i = 0; i < 4; i++) {
                bufB[i]     = pA[((g + 1) * 4 + i) * 256];
                bufB[4 + i] = pB[((g + 1) * 4 + i) * 256];
            }
            LSTM_GROUP(bufA, g)
            if (g < 14) {
#pragma unroll
                for (int i = 0; i < 4; i++) {
                    bufA[i]     = pA[((g + 2) * 4 + i) * 256];
                    bufA[4 + i] = pB[((g + 2) * 4 + i) * 256];
                }
            }
            LSTM_GROUP(bufB, g + 1)
        }

#pragma unroll
        for (int n = 0; n < 4; n++) { gsh[n][t] = acc1[n]; gsh[n][t + 256] = acc2[n]; }
        __syncthreads();
#pragma unroll
        for (int q = 0; q < 2; q++) {
            int id = t + 256 * q;
            int n = id >> 7, e = id & 127;
            float iv = gsh[n][e], fv = gsh[n][128 + e];
            float gv = gsh[n][256 + e], ov = gsh[n][384 + e];
            float c = sigm(fv) * creg[q] + sigm(iv) * tanh_f(gv);
            float h = sigm(ov) * tanh_f(c);
            creg[q] = c;
            hsh[n][e] = h;
            xrow[n * 128 + e] = h;
            if (s == SQ - 1) {
                hT[(size_t)(n0 + n) * 128 + e] = h;
                cT[(size_t)(n0 + n) * 128 + e] = c;
            }
        }
#pragma unroll
        for (int n = 0; n < 4; n++) xr[n] = xnx[n];
        __syncthreads();
    }
}

// ---------------- recurrent-only LSTM (big-ws path) ----------------
// 500 blocks x 2 nodes: 2 blocks/CU -> 2 waves/SIMD of latency hiding (was 1).
// Per kp: 1 float4 load, 4 readlane, 8 FMA.
#define LSTM2_GROUP(buf, gbase)                                \
    _Pragma("unroll")                                          \
    for (int i_ = 0; i_ < 8; i_++) {                           \
        const int kp_ = (gbase) * 8 + i_;                      \
        const float4 q_ = buf[i_];                             \
        _Pragma("unroll")                                      \
        for (int n_ = 0; n_ < 2; n_++) {                       \
            const float sh0_ = rdlane(hr[n_].x, kp_);          \
            const float sh1_ = rdlane(hr[n_].y, kp_);          \
            acc1[n_] += sh0_ * q_.x + sh1_ * q_.y;             \
            acc2[n_] += sh0_ * q_.z + sh1_ * q_.w;             \
        }                                                      \
    }

__global__ __launch_bounds__(256, 2) void lstm2_k(
    float* __restrict__ mu, const float* __restrict__ xC,
    const float4* __restrict__ WQ4,
    const float* __restrict__ h0, const float* __restrict__ c0,
    float* __restrict__ hT, float* __restrict__ cT)
{
    const int t = threadIdx.x, lane = t & 63;
    const int n0 = blockIdx.x * 2;
    __shared__ float hsh[2][128];
    __shared__ float gsh[2][512];
    const int cn = t >> 7, ce = t & 127;   // this thread's cell (node, channel)
    float creg = c0[(size_t)(n0 + cn) * 128 + ce];
    hsh[cn][ce] = h0[(size_t)(n0 + cn) * 128 + ce];

    const float4* pW = WQ4 + t;

    // prefetch step-0 gate preacts
    float g1[2], g2[2], g1n[2], g2n[2];
#pragma unroll
    for (int n = 0; n < 2; n++) {
        const float* gb = xC + (size_t)(n0 + n) * 512;
        g1[n] = gb[t]; g2[n] = gb[t + 256];
    }
    __syncthreads();

    for (int s = 0; s < SQ; s++) {
        float* xrow = mu + ((size_t)s * NN + n0) * 128;
        float2 hr[2];
#pragma unroll
        for (int n = 0; n < 2; n++) hr[n] = *(const float2*)(&hsh[n][lane * 2]);

        float4 bufA[8], bufB[8];
#pragma unroll
        for (int i = 0; i < 8; i++) bufA[i] = pW[i * 256];

        if (s + 1 < SQ) {
#pragma unroll
            for (int n = 0; n < 2; n++) {
                const float* gb = xC + ((size_t)(s + 1) * NN + n0 + n) * 512;
                g1n[n] = gb[t]; g2n[n] = gb[t + 256];
            }
        }

        float acc1[2], acc2[2];
#pragma unroll
        for (int n = 0; n < 2; n++) { acc1[n] = g1[n]; acc2[n] = g2[n]; }

        for (int g = 0; g < 8; g += 2) {
#pragma unroll
            for (int i = 0; i < 8; i++) bufB[i] = pW[((g + 1) * 8 + i) * 256];
            LSTM2_GROUP(bufA, g)
            if (g < 6) {
#pragma unroll
                for (int i = 0; i < 8; i++) bufA[i] = pW[((g + 2) * 8 + i) * 256];
            }
            LSTM2_GROUP(bufB, g + 1)
        }

#pragma unroll
        for (int n = 0; n < 2; n++) { gsh[n][t] = acc1[n]; gsh[n][t + 256] = acc2[n]; }
        __syncthreads();
        {
            float iv = gsh[cn][ce], fv = gsh[cn][128 + ce];
            float gv = gsh[cn][256 + ce], ov = gsh[cn][384 + ce];
            float c = sigm(fv) * creg + sigm(iv) * tanh_f(gv);
            float h = sigm(ov) * tanh_f(c);
            creg = c;
            hsh[cn][ce] = h;
            xrow[cn * 128 + ce] = h;        // mu <- h_t (scan output)
            if (s == SQ - 1) {
                hT[(size_t)(n0 + cn) * 128 + ce] = h;
                cT[(size_t)(n0 + cn) * 128 + ce] = c;
            }
        }
#pragma unroll
        for (int n = 0; n < 2; n++) { g1[n] = g1n[n]; g2[n] = g2n[n]; }
        __syncthreads();
    }
}

// ---------------- head: meanpool -> gs -> A[s] = sum_j relu(gs)*w5[j] ----------------
__global__ __launch_bounds__(256) void meanpool_gs_k(
    const float* __restrict__ mu, const float* __restrict__ W6,
    const float* __restrict__ b6, const float* __restrict__ w5,
    float* __restrict__ A)
{
    const int s = blockIdx.x, t = threadIdx.x;
    const int ch = t & 127, half = t >> 7;
    __shared__ float mp[128];
    __shared__ float red[256];
    float acc = 0.f;
    for (int n = half * 500; n < (half + 1) * 500; n++)
        acc += mu[((size_t)s * NN + n) * 128 + ch];
    red[t] = acc;
    __syncthreads();
    if (t < 128) mp[t] = (red[t] + red[t + 128]) * 0.001f;
    __syncthreads();
    float g = 0.f;
    if (t < 128) {
        g = b6[t];
        for (int k = 0; k < 128; k++) g += mp[k] * W6[(size_t)k * 128 + t];
        g = fmaxf(g, 0.f) * w5[t];
    }
    red[t] = g;
    __syncthreads();
    for (int o = 128; o > 0; o >>= 1) {
        if (t < o) red[t] += red[t + o];
        __syncthreads();
    }
    if (t == 0) A[s] = red[0];
}

// ---------------- head: logit2[row] = A[s] + b5 + sum_j relu(la[row][j]) * w5[128+j] ----------------
__global__ __launch_bounds__(256) void rowdot_k(
    const float* __restrict__ la, const float* __restrict__ w5,
    const float* __restrict__ b5, const float* __restrict__ A,
    float* __restrict__ out)
{
    const int lane = threadIdx.x & 63;
    const int row = blockIdx.x * 4 + (threadIdx.x >> 6);
    float2 v = *(const float2*)(la + (size_t)row * 128 + lane * 2);
    float2 w = *(const float2*)(w5 + 128 + lane * 2);
    float x = fmaxf(v.x, 0.f) * w.x + fmaxf(v.y, 0.f) * w.y;
#pragma unroll
    for (int o = 32; o; o >>= 1) x += __shfl_down(x, o);
    if (lane == 0) out[row] = x + A[row / NN] + b5[0];
}

// ---------------- masked softmax per sequence step ----------------
__device__ __forceinline__ bool reach_at(const void* reach, int mode, int idx) {
    if (mode == 0) return ((const int*)reach)[idx] != 0;
    if (mode == 1) return ((const unsigned char*)reach)[idx] != 0;
    return ((const float*)reach)[idx] != 0.f;
}
__global__ __launch_bounds__(256) void softmax_k(
    const float* __restrict__ lg, const void* __restrict__ reach,
    const int* __restrict__ mode, float* __restrict__ prob)
{
    const int s = blockIdx.x, t = threadIdx.x;
    const int m = *mode;
    __shared__ float red[256];
    float mx = -1e30f;
    for (int i = t; i < NN; i += 256) {
        int idx = s * NN + i;
        if (reach_at(reach, m, idx)) mx = fmaxf(mx, lg[idx]);
    }
    red[t] = mx;
    __syncthreads();
    for (int o = 128; o; o >>= 1) {
        if (t < o) red[t] = fmaxf(red[t], red[t + o]);
        __syncthreads();
    }
    mx = red[0];
    __syncthreads();
    float sum = 0.f;
    for (int i = t; i < NN; i += 256) {
        int idx = s * NN + i;
        float v = reach_at(reach, m, idx) ? __expf(lg[idx] - mx) : 0.f;
        prob[idx] = v;
        sum += v;
    }
    red[t] = sum;
    __syncthreads();
    for (int o = 128; o; o >>= 1) {
        if (t < o) red[t] += red[t + o];
        __syncthreads();
    }
    float inv = 1.f / red[0];
    for (int i = t; i < NN; i += 256) prob[s * NN + i] *= inv;
}

// ---------------- driver ----------------
extern "C" void kernel_launch(void* const* d_in, const int* in_sizes, int n_in,
                              void* d_out, int out_size, void* d_ws, size_t ws_size,
                              hipStream_t stream) {
    const float* nfm   = (const float*)d_in[0];
    const int*   ei    = (const int*)d_in[1];
    const void*  reach = d_in[2];
    const float* h0    = (const float*)d_in[3];
    const float* c0    = (const float*)d_in[4];
    const float* W1    = (const float*)d_in[5];
    const float* b1    = (const float*)d_in[6];
    const float* att1  = (const float*)d_in[7];
    const float* bias1 = (const float*)d_in[8];
    const float* Wl    = (const float*)d_in[9];
    const float* bl    = (const float*)d_in[10];
    const float* attl  = (const float*)d_in[11];
    const float* biasl = (const float*)d_in[12];
    const float* Wih   = (const float*)d_in[13];
    const float* Whh   = (const float*)d_in[14];
    const float* bih   = (const float*)d_in[15];
    const float* bhh   = (const float*)d_in[16];
    const float* W6    = (const float*)d_in[17];
    const float* b6    = (const float*)d_in[18];
    const float* W7    = (const float*)d_in[19];
    const float* b7    = (const float*)d_in[20];
    const float* w5    = (const float*)d_in[21];
    const float* b5    = (const float*)d_in[22];

    char* ws = (char*)d_ws;
    const bool bigws = (ws_size >= WS2_NEED);

    float*  xA     = (float*)(ws + WS_XA);
    float*  xB     = (float*)(ws + WS_XB);
    int*    rowptr = (int*)(ws + WS_ROWPTR);
    int*    cursor = (int*)(ws + WS_CURSOR);
    int*    srcs   = (int*)(ws + WS_SRCS);
    int*    incl   = (int*)(ws + WS_INCL);
    int*    bsum   = (int*)(ws + WS_BSUM);
    int*    boff   = (int*)(ws + WS_BOFF);
    int*    modep  = bigws ? (int*)(ws + WS2_MODE)   : (int*)(ws + WS_MODE);
    float*  As     = bigws ? (float*)(ws + WS2_AS)   : (float*)(ws + WS_AS);
    float*  logit2 = bigws ? (float*)(ws + WS2_LOGIT2) : (float*)(ws + WS_LOGIT2);
    // big-ws extras
    float*  xC     = (float*)(ws + WS2_XC);
    float4* WQ4    = (float4*)(ws + WS2_WQ4);
    float*  WihT   = (float*)(ws + WS2_WIHT);
    float*  b512   = (float*)(ws + WS2_B512);
    // fallback extras
    float4* WQa    = (float4*)(ws + WS_WQA);
    float4* WQb    = (float4*)(ws + WS_WQB);

    float* prob = (float*)d_out;
    float* hT   = (float*)d_out + 64000;
    float* cT   = (float*)d_out + 192000;

    // setup
    detect_mode_k<<<1, 256, 0, stream>>>((const unsigned char*)reach, modep);
    zero_ints_k<<<250, 256, 0, stream>>>(cursor, NT);
    hist_k<<<2250, 256, 0, stream>>>(ei, cursor);
    scan1_k<<<250, 256, 0, stream>>>(cursor, incl, bsum);
    scan2_k<<<1, 256, 0, stream>>>(bsum, boff);
    scan3_k<<<250, 256, 0, stream>>>(incl, boff, rowptr, cursor);
    fill_k<<<2250, 256, 0, stream>>>(ei, cursor, srcs);
    if (bigws) {
        build_wiht_k<<<256, 256, 0, stream>>>(Wih, bih, bhh, WihT, b512);
        build_wq4_k<<<64, 256, 0, stream>>>(Whh, WQ4);
    } else {
        build_wq_k<<<64, 256, 0, stream>>>(Wih, Whh, WQa, WQb);
    }

    // 5 GATv2 layers: gemm (x->xB), fused logits+softmax+aggregate (xB->xA)
    for (int l = 0; l < 5; l++) {
        if (l == 0)
            gemm3<64><<<500, 256, 0, stream>>>(nfm, W1, b1, xB);
        else
            gemm3<128><<<500, 256, 0, stream>>>(xA, Wl + (size_t)(l - 1) * 128 * 128,
                                                bl + (l - 1) * 128, xB);
        const float* att  = (l == 0) ? att1  : attl  + (l - 1) * 128;
        const float* bias = (l == 0) ? bias1 : biasl + (l - 1) * 128;
        gat_fused_k<<<16000, 256, 0, stream>>>(xB, rowptr, srcs, att, bias, xA,
                                               (l < 4) ? 1 : 0);
    }

    // LSTM
    if (bigws) {
        // precompute all gate x-preactivations: xC = mu @ Wih^T + (bih+bhh)
        gemm_proj3<<<dim3(500, 4), 256, 0, stream>>>(xA, WihT, b512, xC);
        lstm2_k<<<500, 256, 0, stream>>>(xA, xC, WQ4, h0, c0, hT, cT);
    } else {
        lstm_k<<<250, 256, 0, stream>>>(xA, WQa, WQb, bih, bhh, h0, c0, hT, cT);
    }

    // head
    meanpool_gs_k<<<64, 256, 0, stream>>>(xA, W6, b6, w5, As);
    gemm3<128><<<500, 256, 0, stream>>>(xA, W7, b7, xB);       // la
    rowdot_k<<<16000, 256, 0, stream>>>(xB, w5, b5, As, logit2);
    softmax_k<<<64, 256, 0, stream>>>(logit2, reach, modep, prob);
}

// Round 6
// 970.780 us; speedup vs baseline: 3.3227x; 1.1529x over previous
//
#include <hip/hip_runtime.h>
#include <hip/hip_bf16.h>

// ---------------- problem constants ----------------
#define SQ   64        // seq len
#define NN   1000      // nodes per graph
#define NT   64000     // total nodes
#define EE   128       // emb dim
#define EG   512000    // graph edges (no self loops)
#define ET   576000    // edges + self loops

// ---------------- workspace layout (bytes) ----------------
// common / fallback region (<71 MB)
#define WS_XA      0ull          // 32,768,000  float[NT*128]  x ping (mu lives here)
#define WS_XB      33000000ull   // 32,768,000  float[NT*128]  x pong (xl / la)
#define WS_ROWPTR  66000000ull   // 256,004     int[NT+1]
#define WS_CURSOR  66300000ull   // 256,000     int[NT]   (also used as deg)
#define WS_SRCS    66600000ull   // 2,304,000   int[ET]  (src node id, dst-grouped)
#define WS_INCL    69000000ull   // 256,000     int[NT]
#define WS_BSUM    69300000ull   // 1,024       int[250]
#define WS_BOFF    69302048ull   // 1,024       int[250]
#define WS_MODE    69304096ull   // 4           int
#define WS_WQA     70000000ull   // 262,144     float4[64*256]  (fallback LSTM)
#define WS_WQB     70262144ull   // 262,144     float4[64*256]  (fallback LSTM)
#define WS_AS      70600000ull   // 256         float[64]
#define WS_LOGIT2  70700000ull   // 256,000     float[NT]
// big-ws region: xC aliases xB + CSR (disjoint lifetimes)
#define WS2_XC     33000000ull   // 131,072,000 float[NT*512]  gate preacts (x part)
#define WS2_BFRAG  164100000ull  // 131,072     ushort[32*4*64*8] bf16 Whh B-fragments
#define WS2_WIHT   164400000ull  // 262,144     float[128*512] Wih^T
#define WS2_B512   164700000ull  // 2,048       float[512]     bih+bhh
#define WS2_MODE   164710000ull  // 4
#define WS2_AS     164720000ull  // 256
#define WS2_LOGIT2 164800000ull  // 256,000
#define WS2_NEED   165100000ull

typedef __attribute__((ext_vector_type(8))) short short8;   // 8 bf16 (4 VGPRs)
typedef __attribute__((ext_vector_type(4))) float f32x4;

// ---------------- helpers ----------------
__device__ __forceinline__ float rdlane(float v, int l) {
    return __int_as_float(__builtin_amdgcn_readlane(__float_as_int(v), l));
}
__device__ __forceinline__ float sigm(float x) { return 1.0f / (1.0f + __expf(-x)); }
__device__ __forceinline__ float tanh_f(float x) {
    x = fminf(fmaxf(x, -30.0f), 30.0f);
    float e = __expf(2.0f * x);
    return (e - 1.0f) / (e + 1.0f);
}
__device__ __forceinline__ ushort f2bf(float x) {   // round-to-nearest-even bf16
    unsigned u = __float_as_uint(x);
    unsigned r = (u + 0x7FFFu + ((u >> 16) & 1u)) >> 16;
    return (ushort)r;
}
__device__ __forceinline__ float bf2f(ushort h) {
    return __uint_as_float(((unsigned)h) << 16);
}

// ---------------- reachable dtype detection ----------------
__global__ void detect_mode_k(const unsigned char* __restrict__ p, int* __restrict__ mode) {
    __shared__ int f0, f3;
    const int t = threadIdx.x;
    if (t == 0) { f0 = 0; f3 = 0; }
    __syncthreads();
    int l0 = 0, l3 = 0;
    for (int i = t; i < 16000; i += 256) {
        if (p[4 * i])     l0 = 1;
        if (p[4 * i + 3]) l3 = 1;
    }
    if (l0) atomicOr(&f0, 1);
    if (l3) atomicOr(&f3, 1);
    __syncthreads();
    if (t == 0) {
        int m;
        if (f0 && f3)      m = 1;  // bool bytes
        else if (f0)       m = 0;  // int32
        else               m = 2;  // float32
        *mode = m;
    }
}

// ---------------- CSR construction (dst-grouped src list; built once) ----------------
__global__ void zero_ints_k(int* __restrict__ p, int n) {
    int i = blockIdx.x * 256 + threadIdx.x;
    if (i < n) p[i] = 0;
}
__global__ void hist_k(const int* __restrict__ ei, int* __restrict__ deg) {
    int e = blockIdx.x * 256 + threadIdx.x;
    if (e < ET) {
        int d = (e < EG) ? ei[EG + e] : (e - EG);
        atomicAdd(deg + d, 1);
    }
}
__global__ void scan1_k(const int* __restrict__ deg, int* __restrict__ incl, int* __restrict__ bsum) {
    __shared__ int sh[256];
    const int t = threadIdx.x;
    const int i = blockIdx.x * 256 + t;
    sh[t] = deg[i];
    __syncthreads();
    for (int o = 1; o < 256; o <<= 1) {
        int add = (t >= o) ? sh[t - o] : 0;
        __syncthreads();
        sh[t] += add;
        __syncthreads();
    }
    incl[i] = sh[t];
    if (t == 255) bsum[blockIdx.x] = sh[255];
}
__global__ void scan2_k(const int* __restrict__ bsum, int* __restrict__ boff) {
    __shared__ int sh[256];
    const int t = threadIdx.x;
    int v = (t < 250) ? bsum[t] : 0;
    sh[t] = v;
    __syncthreads();
    for (int o = 1; o < 256; o <<= 1) {
        int add = (t >= o) ? sh[t - o] : 0;
        __syncthreads();
        sh[t] += add;
        __syncthreads();
    }
    if (t < 250) boff[t] = sh[t] - v;   // exclusive
}
__global__ void scan3_k(const int* __restrict__ incl, const int* __restrict__ boff,
                        int* __restrict__ rowptr, int* __restrict__ cursor_deg) {
    const int i = blockIdx.x * 256 + threadIdx.x;
    int total = incl[i] + boff[blockIdx.x];
    int excl  = total - cursor_deg[i];
    rowptr[i] = excl;
    cursor_deg[i] = excl;                 // becomes fill cursor
    if (i == NT - 1) rowptr[NT] = total;
}
__global__ void fill_k(const int* __restrict__ ei, int* __restrict__ cursor, int* __restrict__ srcs) {
    int e = blockIdx.x * 256 + threadIdx.x;
    if (e < ET) {
        int s_, d_;
        if (e < EG) { s_ = ei[e]; d_ = ei[EG + e]; }
        else        { s_ = e - EG; d_ = s_; }
        int p = atomicAdd(cursor + d_, 1);
        srcs[p] = s_;
    }
}

// ---------------- fp32 GEMM v3: out[M x 128] = x[M x K] @ W[K x 128] + b ----------------
template <int K>
__global__ __launch_bounds__(256) void gemm3(
    const float* __restrict__ x, const float* __restrict__ W,
    const float* __restrict__ b, float* __restrict__ out)
{
    __shared__ float Wsh[64 * 128];     // [k][col]
    __shared__ float xT[64][132];       // [k][row]
    const int t = threadIdx.x;
    const int row0 = blockIdx.x * 128;
    const int cg = t & 15;
    const int rg = t >> 4;
    float4 acc[8][2];
#pragma unroll
    for (int r = 0; r < 8; r++) {
        acc[r][0] = make_float4(0.f, 0.f, 0.f, 0.f);
        acc[r][1] = make_float4(0.f, 0.f, 0.f, 0.f);
    }

    for (int k0 = 0; k0 < K; k0 += 64) {
        for (int i = t * 4; i < 64 * 128; i += 1024)
            *(float4*)(Wsh + i) = *(const float4*)(W + (size_t)k0 * 128 + i);
        for (int i = t * 4; i < 128 * 64; i += 1024) {
            int r = i >> 6, k = i & 63;
            float4 v = *(const float4*)(x + (size_t)(row0 + r) * K + k0 + k);
            xT[k + 0][r] = v.x;
            xT[k + 1][r] = v.y;
            xT[k + 2][r] = v.z;
            xT[k + 3][r] = v.w;
        }
        __syncthreads();
#pragma unroll 2
        for (int k = 0; k < 64; k++) {
            float4 w0 = *(const float4*)(Wsh + k * 128 + cg * 8);
            float4 w1 = *(const float4*)(Wsh + k * 128 + cg * 8 + 4);
            float4 x0 = *(const float4*)(&xT[k][rg * 8]);
            float4 x1 = *(const float4*)(&xT[k][rg * 8 + 4]);
            float xv[8] = {x0.x, x0.y, x0.z, x0.w, x1.x, x1.y, x1.z, x1.w};
#pragma unroll
            for (int r = 0; r < 8; r++) {
                acc[r][0].x += xv[r] * w0.x; acc[r][0].y += xv[r] * w0.y;
                acc[r][0].z += xv[r] * w0.z; acc[r][0].w += xv[r] * w0.w;
                acc[r][1].x += xv[r] * w1.x; acc[r][1].y += xv[r] * w1.y;
                acc[r][1].z += xv[r] * w1.z; acc[r][1].w += xv[r] * w1.w;
            }
        }
        __syncthreads();
    }
    float4 bv0 = *(const float4*)(b + cg * 8);
    float4 bv1 = *(const float4*)(b + cg * 8 + 4);
#pragma unroll
    for (int r = 0; r < 8; r++) {
        float4 o0, o1;
        o0.x = acc[r][0].x + bv0.x; o0.y = acc[r][0].y + bv0.y;
        o0.z = acc[r][0].z + bv0.z; o0.w = acc[r][0].w + bv0.w;
        o1.x = acc[r][1].x + bv1.x; o1.y = acc[r][1].y + bv1.y;
        o1.z = acc[r][1].z + bv1.z; o1.w = acc[r][1].w + bv1.w;
        float* op = out + (size_t)(row0 + rg * 8 + r) * 128 + cg * 8;
        *(float4*)(op) = o0;
        *(float4*)(op + 4) = o1;
    }
}

// ---------------- fp32 GEMM v3 (projection): out[M x 512] = x[M x 128] @ WT[128 x 512] + b512 ----------------
__global__ __launch_bounds__(256) void gemm_proj3(
    const float* __restrict__ x, const float* __restrict__ WT,
    const float* __restrict__ b512, float* __restrict__ out)
{
    __shared__ float Wsh[64 * 128];
    __shared__ float xT[64][132];
    const int t = threadIdx.x;
    const int row0 = blockIdx.x * 128;
    const int col0 = blockIdx.y * 128;
    const int cg = t & 15;
    const int rg = t >> 4;
    float4 acc[8][2];
#pragma unroll
    for (int r = 0; r < 8; r++) {
        acc[r][0] = make_float4(0.f, 0.f, 0.f, 0.f);
        acc[r][1] = make_float4(0.f, 0.f, 0.f, 0.f);
    }

    for (int k0 = 0; k0 < 128; k0 += 64) {
        for (int i = t * 4; i < 64 * 128; i += 1024) {
            int k = i >> 7, c = i & 127;
            *(float4*)(Wsh + i) = *(const float4*)(WT + (size_t)(k0 + k) * 512 + col0 + c);
        }
        for (int i = t * 4; i < 128 * 64; i += 1024) {
            int r = i >> 6, k = i & 63;
            float4 v = *(const float4*)(x + (size_t)(row0 + r) * 128 + k0 + k);
            xT[k + 0][r] = v.x;
            xT[k + 1][r] = v.y;
            xT[k + 2][r] = v.z;
            xT[k + 3][r] = v.w;
        }
        __syncthreads();
#pragma unroll 2
        for (int k = 0; k < 64; k++) {
            float4 w0 = *(const float4*)(Wsh + k * 128 + cg * 8);
            float4 w1 = *(const float4*)(Wsh + k * 128 + cg * 8 + 4);
            float4 x0 = *(const float4*)(&xT[k][rg * 8]);
            float4 x1 = *(const float4*)(&xT[k][rg * 8 + 4]);
            float xv[8] = {x0.x, x0.y, x0.z, x0.w, x1.x, x1.y, x1.z, x1.w};
#pragma unroll
            for (int r = 0; r < 8; r++) {
                acc[r][0].x += xv[r] * w0.x; acc[r][0].y += xv[r] * w0.y;
                acc[r][0].z += xv[r] * w0.z; acc[r][0].w += xv[r] * w0.w;
                acc[r][1].x += xv[r] * w1.x; acc[r][1].y += xv[r] * w1.y;
                acc[r][1].z += xv[r] * w1.z; acc[r][1].w += xv[r] * w1.w;
            }
        }
        __syncthreads();
    }
    float4 bv0 = *(const float4*)(b512 + col0 + cg * 8);
    float4 bv1 = *(const float4*)(b512 + col0 + cg * 8 + 4);
#pragma unroll
    for (int r = 0; r < 8; r++) {
        float4 o0, o1;
        o0.x = acc[r][0].x + bv0.x; o0.y = acc[r][0].y + bv0.y;
        o0.z = acc[r][0].z + bv0.z; o0.w = acc[r][0].w + bv0.w;
        o1.x = acc[r][1].x + bv1.x; o1.y = acc[r][1].y + bv1.y;
        o1.z = acc[r][1].z + bv1.z; o1.w = acc[r][1].w + bv1.w;
        float* op = out + (size_t)(row0 + rg * 8 + r) * 512 + col0 + cg * 8;
        *(float4*)(op) = o0;
        *(float4*)(op + 4) = o1;
    }
}

// ---------------- fused GATv2: logits + online softmax + aggregate ----------------
__global__ __launch_bounds__(256) void gat_fused_k(
    const float* __restrict__ xl, const int* __restrict__ rowptr,
    const int* __restrict__ srcs, const float* __restrict__ att,
    const float* __restrict__ bias, float* __restrict__ out, const int do_relu)
{
    const int lane = threadIdx.x & 63;
    const int b = blockIdx.x;
    const int g = b & 7;
    const int j = b >> 3;
    const int jq = j / 250;
    const int jj = j - jq * 250;
    const int s = g + 8 * jq;
    const int n = s * NN + jj * 4 + (threadIdx.x >> 6);

    const float2 a = *(const float2*)(att + lane * 2);
    const float2 xd = *(const float2*)(xl + (size_t)n * 128 + lane * 2);
    const int i0 = rowptr[n], i1 = rowptr[n + 1];

    float m = -1e30f, den = 0.f, ax = 0.f, ay = 0.f;
    int sv = srcs[i0];
    for (int i = i0; i < i1; i++) {
        int snx = (i + 1 < i1) ? srcs[i + 1] : 0;
        const float2 xs = *(const float2*)(xl + (size_t)sv * 128 + lane * 2);
        float u = xs.x + xd.x, v = xs.y + xd.y;
        u = (u > 0.f) ? u : 0.2f * u;
        v = (v > 0.f) ? v : 0.2f * v;
        float p = u * a.x + v * a.y;
        p += __shfl_xor(p, 1, 32);
        p += __shfl_xor(p, 2, 32);
        p += __shfl_xor(p, 4, 32);
        p += __shfl_xor(p, 8, 32);
        p += __shfl_xor(p, 16, 32);
        float mn = fmaxf(m, p);
        float sc = __expf(m - mn);
        float w  = __expf(p - mn);
        den = den * sc + w;
        ax = ax * sc + w * xs.x;
        ay = ay * sc + w * xs.y;
        m = mn;
        sv = snx;
    }
    float2 bv = *(const float2*)(bias + lane * 2);
    float inv = 1.f / den;
    float ox = ax * inv + bv.x, oy = ay * inv + bv.y;
    if (do_relu) { ox = fmaxf(ox, 0.f); oy = fmaxf(oy, 0.f); }
    *(float2*)(out + (size_t)n * 128 + lane * 2) = make_float2(ox, oy);
}

// ---------------- LSTM weight packing (fallback path: Wih+Whh fused) ----------------
__global__ void build_wq_k(const float* __restrict__ Wih, const float* __restrict__ Whh,
                           float4* __restrict__ WQa, float4* __restrict__ WQb) {
    int id = blockIdx.x * 256 + threadIdx.x;
    if (id < 64 * 256) {
        int kp = id >> 8, t = id & 255;
        int j1 = t, j2 = t + 256;
        WQa[id] = make_float4(Wih[(size_t)j1 * 128 + 2 * kp], Whh[(size_t)j1 * 128 + 2 * kp],
                              Wih[(size_t)j1 * 128 + 2 * kp + 1], Whh[(size_t)j1 * 128 + 2 * kp + 1]);
        WQb[id] = make_float4(Wih[(size_t)j2 * 128 + 2 * kp], Whh[(size_t)j2 * 128 + 2 * kp],
                              Wih[(size_t)j2 * 128 + 2 * kp + 1], Whh[(size_t)j2 * 128 + 2 * kp + 1]);
    }
}

// ---------------- big-ws packing: Wih^T + combined bias ----------------
__global__ void build_wiht_k(const float* __restrict__ Wih, const float* __restrict__ bih,
                             const float* __restrict__ bhh,
                             float* __restrict__ WihT, float* __restrict__ b512) {
    int id = blockIdx.x * 256 + threadIdx.x;
    if (id < 128 * 512) {
        int k = id >> 9, j = id & 511;
        WihT[id] = Wih[(size_t)j * 128 + k];
        if (id < 512) b512[id] = bih[id] + bhh[id];
    }
}

// ---------------- bf16 B-fragment pack of Whh for mfma_f32_16x16x32_bf16 ----------------
// B[k][n]: lane holds col n=lane&15, k=(lane>>4)*8+j (j=0..7), 32-k window per kt.
// Bfrag[((tile*4+kt)*64+lane)*8+j] = bf16(Whh[tile*16+(lane&15)][kt*32+(lane>>4)*8+j])
__global__ void build_bfrag_k(const float* __restrict__ Whh, ushort* __restrict__ Bfrag) {
    int id = blockIdx.x * 256 + threadIdx.x;    // 65536 ids
    if (id < 65536) {
        int j = id & 7, lane = (id >> 3) & 63, kt = (id >> 9) & 3, tile = id >> 11;
        int gate = tile * 16 + (lane & 15);
        int k = kt * 32 + ((lane >> 4) << 3) + j;
        Bfrag[id] = f2bf(Whh[(size_t)gate * 128 + k]);
    }
}

// ---- fallback kernel (round-3 lstm, small-ws only) ----
#define LSTM_GROUP(buf, gbase)                                                     \
    _Pragma("unroll")                                                              \
    for (int i_ = 0; i_ < 4; i_++) {                                               \
        const int kp_ = (gbase) * 4 + i_;                                          \
        const float4 qa_ = buf[i_];                                                \
        const float4 qb_ = buf[4 + i_];                                            \
        _Pragma("unroll")                                                          \
        for (int n_ = 0; n_ < 4; n_++) {                                           \
            const float sx0_ = rdlane(xr[n_].x, kp_);                              \
            const float sh0_ = rdlane(hr[n_].x, kp_);                              \
            const float sx1_ = rdlane(xr[n_].y, kp_);                              \
            const float sh1_ = rdlane(hr[n_].y, kp_);                              \
            acc1[n_] += sx0_ * qa_.x + sh0_ * qa_.y + sx1_ * qa_.z + sh1_ * qa_.w; \
            acc2[n_] += sx0_ * qb_.x + sh0_ * qb_.y + sx1_ * qb_.z + sh1_ * qb_.w; \
        }                                                                          \
    }

__global__ __launch_bounds__(256, 1) void lstm_k(
    float* __restrict__ mu, const float4* __restrict__ WQa, const float4* __restrict__ WQb,
    const float* __restrict__ bih, const float* __restrict__ bhh,
    const float* __restrict__ h0, const float* __restrict__ c0,
    float* __restrict__ hT, float* __restrict__ cT)
{
    const int t = threadIdx.x, lane = t & 63;
    const int n0 = blockIdx.x * 4;
    __shared__ float hsh[4][128];
    __shared__ float gsh[4][512];
    const float b1 = bih[t] + bhh[t];
    const float b2 = bih[t + 256] + bhh[t + 256];
    float creg[2];
#pragma unroll
    for (int q = 0; q < 2; q++) {
        int id = t + 256 * q;
        creg[q] = c0[(size_t)(n0 + (id >> 7)) * 128 + (id & 127)];
    }
    for (int i = t; i < 512; i += 256)
        hsh[i >> 7][i & 127] = h0[(size_t)(n0 + (i >> 7)) * 128 + (i & 127)];

    const float4* pA = WQa + t;
    const float4* pB = WQb + t;

    float2 xr[4], xnx[4];
#pragma unroll
    for (int n = 0; n < 4; n++)
        xr[n] = *(const float2*)(mu + (size_t)n0 * 128 + n * 128 + lane * 2);
    __syncthreads();

    for (int s = 0; s < SQ; s++) {
        float* xrow = mu + ((size_t)s * NN + n0) * 128;
        float2 hr[4];
#pragma unroll
        for (int n = 0; n < 4; n++) hr[n] = *(const float2*)(&hsh[n][lane * 2]);

        float4 bufA[8], bufB[8];
#pragma unroll
        for (int i = 0; i < 4; i++) { bufA[i] = pA[i * 256]; bufA[4 + i] = pB[i * 256]; }

        if (s + 1 < SQ) {
            const float* xrow2 = mu + ((size_t)(s + 1) * NN + n0) * 128;
#pragma unroll
            for (int n = 0; n < 4; n++) xnx[n] = *(const float2*)(xrow2 + n * 128 + lane * 2);
        }

        float acc1[4], acc2[4];
#pragma unroll
        for (int n = 0; n < 4; n++) { acc1[n] = b1; acc2[n] = b2; }

        for (int g = 0; g < 16; g += 2) {
#pragma unroll
            for (int i = 0; i < 4; i++) {
                bufB[i]     = pA[((g + 1) * 4 + i) * 256];
                bufB[4 + i] = pB[((g + 1) * 4 + i) * 256];
            }
            LSTM_GROUP(bufA, g)
            if (g < 14) {
#pragma unroll
                for (int i = 0; i < 4; i++) {
                    bufA[i]     = pA[((g + 2) * 4 + i) * 256];
                    bufA[4 + i] = pB[((g + 2) * 4 + i) * 256];
                }
            }
            LSTM_GROUP(bufB, g + 1)
        }

#pragma unroll
        for (int n = 0; n < 4; n++) { gsh[n][t] = acc1[n]; gsh[n][t + 256] = acc2[n]; }
        __syncthreads();
#pragma unroll
        for (int q = 0; q < 2; q++) {
            int id = t + 256 * q;
            int n = id >> 7, e = id & 127;
            float iv = gsh[n][e], fv = gsh[n][128 + e];
            float gv = gsh[n][256 + e], ov = gsh[n][384 + e];
            float c = sigm(fv) * creg[q] + sigm(iv) * tanh_f(gv);
            float h = sigm(ov) * tanh_f(c);
            creg[q] = c;
            hsh[n][e] = h;
            xrow[n * 128 + e] = h;
            if (s == SQ - 1) {
                hT[(size_t)(n0 + n) * 128 + e] = h;
                cT[(size_t)(n0 + n) * 128 + e] = c;
            }
        }
#pragma unroll
        for (int n = 0; n < 4; n++) xr[n] = xnx[n];
        __syncthreads();
    }
}

// ---------------- MFMA LSTM (big-ws path) ----------------
// 63 blocks x 16 nodes. Whh bf16 B-fragments live in REGISTERS (32 short8 =
// 128 VGPR, constant across steps -> zero weight traffic in the loop).
// h split hi+lo bf16 (2 MFMA passes) -> only Whh bf16 quantization contributes.
// Wave w owns gate tiles q*4+w => gate = q*64+w*16+col: each lane's acc regs
// hold i/f/g/o (q, q+2, q+4, q+6) of its own cells -> no cross-lane exchange.
__global__ __launch_bounds__(256, 1) void lstm3_k(
    float* __restrict__ mu, const float* __restrict__ xC,
    const ushort* __restrict__ Bfrag,
    const float* __restrict__ h0, const float* __restrict__ c0,
    float* __restrict__ hT, float* __restrict__ cT)
{
    const int t = threadIdx.x;
    const int w = t >> 6, lane = t & 63;
    const int quad = lane >> 4, col = lane & 15;
    const int n0 = blockIdx.x * 16;

    __shared__ __align__(16) ushort hhi[16 * 136];   // stride 136 -> conflict-free b128
    __shared__ __align__(16) ushort hlo[16 * 136];

    // B fragments -> registers (constant all 64 steps)
    short8 bf[8][4];
#pragma unroll
    for (int q = 0; q < 8; q++)
#pragma unroll
        for (int kt = 0; kt < 4; kt++) {
            int tile = q * 4 + w;
            bf[q][kt] = *(const short8*)(Bfrag + (((tile * 4 + kt) * 64 + lane) << 3));
        }

    // init h (split hi/lo) into LDS, c into regs
    for (int i = t; i < 2048; i += 256) {
        int node = i >> 7, e = i & 127;
        float v = (n0 + node < NN) ? h0[(size_t)(n0 + node) * 128 + e] : 0.f;
        ushort hh = f2bf(v);
        hhi[node * 136 + e] = hh;
        hlo[node * 136 + e] = f2bf(v - bf2f(hh));
    }
    float cst[8];
#pragma unroll
    for (int q = 0; q < 2; q++)
#pragma unroll
        for (int r = 0; r < 4; r++) {
            int node = quad * 4 + r;
            int nn = (n0 + node < NN) ? (n0 + node) : (NN - 1);
            cst[q * 4 + r] = c0[(size_t)nn * 128 + (q * 64 + w * 16 + col)];
        }
    __syncthreads();

    for (int s = 0; s < SQ; s++) {
        // prefetch this step's xC gate preacts (consumed in epilogue, latency
        // hidden behind the MFMA block)
        const float* xCs = xC + (size_t)s * (NN * 512);
        float xcr[8][4];
#pragma unroll
        for (int q = 0; q < 8; q++)
#pragma unroll
            for (int r = 0; r < 4; r++) {
                int node = quad * 4 + r;
                int nn = (n0 + node < NN) ? (n0 + node) : (NN - 1);
                xcr[q][r] = xCs[(size_t)nn * 512 + (q * 64 + w * 16 + col)];
            }

        // A fragments: A[m=lane&15][k=quad*8+j] from LDS h tile
        short8 ahi[4], alo[4];
#pragma unroll
        for (int kt = 0; kt < 4; kt++) {
            ahi[kt] = *(const short8*)(hhi + col * 136 + kt * 32 + quad * 8);
            alo[kt] = *(const short8*)(hlo + col * 136 + kt * 32 + quad * 8);
        }

        f32x4 acc[8];
#pragma unroll
        for (int q = 0; q < 8; q++) acc[q] = (f32x4){0.f, 0.f, 0.f, 0.f};
#pragma unroll
        for (int kt = 0; kt < 4; kt++) {
#pragma unroll
            for (int q = 0; q < 8; q++) {
                acc[q] = __builtin_amdgcn_mfma_f32_16x16x32_bf16(ahi[kt], bf[q][kt], acc[q], 0, 0, 0);
                acc[q] = __builtin_amdgcn_mfma_f32_16x16x32_bf16(alo[kt], bf[q][kt], acc[q], 0, 0, 0);
            }
        }
        __syncthreads();   // all waves' A reads done before h rewrite

        // epilogue: D layout col=lane&15, row=(lane>>4)*4+reg -> node=quad*4+r
        float* mus = mu + (size_t)s * (NN * 128);
#pragma unroll
        for (int q = 0; q < 2; q++)
#pragma unroll
            for (int r = 0; r < 4; r++) {
                float iv = acc[q][r]     + xcr[q][r];
                float fv = acc[q + 2][r] + xcr[q + 2][r];
                float gv = acc[q + 4][r] + xcr[q + 4][r];
                float ov = acc[q + 6][r] + xcr[q + 6][r];
                float c = sigm(fv) * cst[q * 4 + r] + sigm(iv) * tanh_f(gv);
                float h = sigm(ov) * tanh_f(c);
                cst[q * 4 + r] = c;
                int node = quad * 4 + r;
                int e = q * 64 + w * 16 + col;
                ushort hh = f2bf(h);
                hhi[node * 136 + e] = hh;
                hlo[node * 136 + e] = f2bf(h - bf2f(hh));
                if (n0 + node < NN) {
                    mus[(size_t)(n0 + node) * 128 + e] = h;
                    if (s == SQ - 1) {
                        hT[(size_t)(n0 + node) * 128 + e] = h;
                        cT[(size_t)(n0 + node) * 128 + e] = c;
                    }
                }
            }
        __syncthreads();
    }
}

// ---------------- head: meanpool -> gs -> A[s] = sum_j relu(gs)*w5[j] ----------------
__global__ __launch_bounds__(256) void meanpool_gs_k(
    const float* __restrict__ mu, const float* __restrict__ W6,
    const float* __restrict__ b6, const float* __restrict__ w5,
    float* __restrict__ A)
{
    const int s = blockIdx.x, t = threadIdx.x;
    const int ch = t & 127, half = t >> 7;
    __shared__ float mp[128];
    __shared__ float red[256];
    float acc = 0.f;
    for (int n = half * 500; n < (half + 1) * 500; n++)
        acc += mu[((size_t)s * NN + n) * 128 + ch];
    red[t] = acc;
    __syncthreads();
    if (t < 128) mp[t] = (red[t] + red[t + 128]) * 0.001f;
    __syncthreads();
    float g = 0.f;
    if (t < 128) {
        g = b6[t];
        for (int k = 0; k < 128; k++) g += mp[k] * W6[(size_t)k * 128 + t];
        g = fmaxf(g, 0.f) * w5[t];
    }
    red[t] = g;
    __syncthreads();
    for (int o = 128; o > 0; o >>= 1) {
        if (t < o) red[t] += red[t + o];
        __syncthreads();
    }
    if (t == 0) A[s] = red[0];
}

// ---------------- head: logit2[row] = A[s] + b5 + sum_j relu(la[row][j]) * w5[128+j] ----------------
__global__ __launch_bounds__(256) void rowdot_k(
    const float* __restrict__ la, const float* __restrict__ w5,
    const float* __restrict__ b5, const float* __restrict__ A,
    float* __restrict__ out)
{
    const int lane = threadIdx.x & 63;
    const int row = blockIdx.x * 4 + (threadIdx.x >> 6);
    float2 v = *(const float2*)(la + (size_t)row * 128 + lane * 2);
    float2 w = *(const float2*)(w5 + 128 + lane * 2);
    float x = fmaxf(v.x, 0.f) * w.x + fmaxf(v.y, 0.f) * w.y;
#pragma unroll
    for (int o = 32; o; o >>= 1) x += __shfl_down(x, o);
    if (lane == 0) out[row] = x + A[row / NN] + b5[0];
}

// ---------------- masked softmax per sequence step ----------------
__device__ __forceinline__ bool reach_at(const void* reach, int mode, int idx) {
    if (mode == 0) return ((const int*)reach)[idx] != 0;
    if (mode == 1) return ((const unsigned char*)reach)[idx] != 0;
    return ((const float*)reach)[idx] != 0.f;
}
__global__ __launch_bounds__(256) void softmax_k(
    const float* __restrict__ lg, const void* __restrict__ reach,
    const int* __restrict__ mode, float* __restrict__ prob)
{
    const int s = blockIdx.x, t = threadIdx.x;
    const int m = *mode;
    __shared__ float red[256];
    float mx = -1e30f;
    for (int i = t; i < NN; i += 256) {
        int idx = s * NN + i;
        if (reach_at(reach, m, idx)) mx = fmaxf(mx, lg[idx]);
    }
    red[t] = mx;
    __syncthreads();
    for (int o = 128; o; o >>= 1) {
        if (t < o) red[t] = fmaxf(red[t], red[t + o]);
        __syncthreads();
    }
    mx = red[0];
    __syncthreads();
    float sum = 0.f;
    for (int i = t; i < NN; i += 256) {
        int idx = s * NN + i;
        float v = reach_at(reach, m, idx) ? __expf(lg[idx] - mx) : 0.f;
        prob[idx] = v;
        sum += v;
    }
    red[t] = sum;
    __syncthreads();
    for (int o = 128; o; o >>= 1) {
        if (t < o) red[t] += red[t + o];
        __syncthreads();
    }
    float inv = 1.f / red[0];
    for (int i = t; i < NN; i += 256) prob[s * NN + i] *= inv;
}

// ---------------- driver ----------------
extern "C" void kernel_launch(void* const* d_in, const int* in_sizes, int n_in,
                              void* d_out, int out_size, void* d_ws, size_t ws_size,
                              hipStream_t stream) {
    const float* nfm   = (const float*)d_in[0];
    const int*   ei    = (const int*)d_in[1];
    const void*  reach = d_in[2];
    const float* h0    = (const float*)d_in[3];
    const float* c0    = (const float*)d_in[4];
    const float* W1    = (const float*)d_in[5];
    const float* b1    = (const float*)d_in[6];
    const float* att1  = (const float*)d_in[7];
    const float* bias1 = (const float*)d_in[8];
    const float* Wl    = (const float*)d_in[9];
    const float* bl    = (const float*)d_in[10];
    const float* attl  = (const float*)d_in[11];
    const float* biasl = (const float*)d_in[12];
    const float* Wih   = (const float*)d_in[13];
    const float* Whh   = (const float*)d_in[14];
    const float* bih   = (const float*)d_in[15];
    const float* bhh   = (const float*)d_in[16];
    const float* W6    = (const float*)d_in[17];
    const float* b6    = (const float*)d_in[18];
    const float* W7    = (const float*)d_in[19];
    const float* b7    = (const float*)d_in[20];
    const float* w5    = (const float*)d_in[21];
    const float* b5    = (const float*)d_in[22];

    char* ws = (char*)d_ws;
    const bool bigws = (ws_size >= WS2_NEED);

    float*  xA     = (float*)(ws + WS_XA);
    float*  xB     = (float*)(ws + WS_XB);
    int*    rowptr = (int*)(ws + WS_ROWPTR);
    int*    cursor = (int*)(ws + WS_CURSOR);
    int*    srcs   = (int*)(ws + WS_SRCS);
    int*    incl   = (int*)(ws + WS_INCL);
    int*    bsum   = (int*)(ws + WS_BSUM);
    int*    boff   = (int*)(ws + WS_BOFF);
    int*    modep  = bigws ? (int*)(ws + WS2_MODE)   : (int*)(ws + WS_MODE);
    float*  As     = bigws ? (float*)(ws + WS2_AS)   : (float*)(ws + WS_AS);
    float*  logit2 = bigws ? (float*)(ws + WS2_LOGIT2) : (float*)(ws + WS_LOGIT2);
    // big-ws extras
    float*  xC     = (float*)(ws + WS2_XC);
    ushort* Bfrag  = (ushort*)(ws + WS2_BFRAG);
    float*  WihT   = (float*)(ws + WS2_WIHT);
    float*  b512   = (float*)(ws + WS2_B512);
    // fallback extras
    float4* WQa    = (float4*)(ws + WS_WQA);
    float4* WQb    = (float4*)(ws + WS_WQB);

    float* prob = (float*)d_out;
    float* hT   = (float*)d_out + 64000;
    float* cT   = (float*)d_out + 192000;

    // setup
    detect_mode_k<<<1, 256, 0, stream>>>((const unsigned char*)reach, modep);
    zero_ints_k<<<250, 256, 0, stream>>>(cursor, NT);
    hist_k<<<2250, 256, 0, stream>>>(ei, cursor);
    scan1_k<<<250, 256, 0, stream>>>(cursor, incl, bsum);
    scan2_k<<<1, 256, 0, stream>>>(bsum, boff);
    scan3_k<<<250, 256, 0, stream>>>(incl, boff, rowptr, cursor);
    fill_k<<<2250, 256, 0, stream>>>(ei, cursor, srcs);
    if (bigws) {
        build_wiht_k<<<256, 256, 0, stream>>>(Wih, bih, bhh, WihT, b512);
        build_bfrag_k<<<256, 256, 0, stream>>>(Whh, Bfrag);
    } else {
        build_wq_k<<<64, 256, 0, stream>>>(Wih, Whh, WQa, WQb);
    }

    // 5 GATv2 layers: gemm (x->xB), fused logits+softmax+aggregate (xB->xA)
    for (int l = 0; l < 5; l++) {
        if (l == 0)
            gemm3<64><<<500, 256, 0, stream>>>(nfm, W1, b1, xB);
        else
            gemm3<128><<<500, 256, 0, stream>>>(xA, Wl + (size_t)(l - 1) * 128 * 128,
                                                bl + (l - 1) * 128, xB);
        const float* att  = (l == 0) ? att1  : attl  + (l - 1) * 128;
        const float* bias = (l == 0) ? bias1 : biasl + (l - 1) * 128;
        gat_fused_k<<<16000, 256, 0, stream>>>(xB, rowptr, srcs, att, bias, xA,
                                               (l < 4) ? 1 : 0);
    }

    // LSTM
    if (bigws) {
        // xC = mu @ Wih^T + (bih+bhh), then MFMA recurrence
        gemm_proj3<<<dim3(500, 4), 256, 0, stream>>>(xA, WihT, b512, xC);
        lstm3_k<<<63, 256, 0, stream>>>(xA, xC, Bfrag, h0, c0, hT, cT);
    } else {
        lstm_k<<<250, 256, 0, stream>>>(xA, WQa, WQb, bih, bhh, h0, c0, hT, cT);
    }

    // head
    meanpool_gs_k<<<64, 256, 0, stream>>>(xA, W6, b6, w5, As);
    gemm3<128><<<500, 256, 0, stream>>>(xA, W7, b7, xB);       // la
    rowdot_k<<<16000, 256, 0, stream>>>(xB, w5, b5, As, logit2);
    softmax_k<<<64, 256, 0, stream>>>(logit2, reach, modep, prob);
}

// Round 7
// 902.218 us; speedup vs baseline: 3.5752x; 1.0760x over previous
//
#include <hip/hip_runtime.h>
#include <hip/hip_bf16.h>

// ---------------- problem constants ----------------
#define SQ   64        // seq len
#define NN   1000      // nodes per graph
#define NT   64000     // total nodes
#define EE   128       // emb dim
#define EG   512000    // graph edges (no self loops)
#define ET   576000    // edges + self loops

// ---------------- workspace layout (bytes) ----------------
// common / fallback region (<71 MB)
#define WS_XA      0ull          // 32,768,000  float[NT*128]  x ping (mu lives here)
#define WS_XB      33000000ull   // 32,768,000  float[NT*128]  x pong (xl / la)
#define WS_ROWPTR  66000000ull   // 256,004     int[NT+1]
#define WS_CURSOR  66300000ull   // 256,000     int[NT]   (also used as deg)
#define WS_SRCS    66600000ull   // 2,304,000   int[ET]  (src node id, dst-grouped)
#define WS_INCL    69000000ull   // 256,000     int[NT]
#define WS_BSUM    69300000ull   // 1,024       int[250]
#define WS_BOFF    69302048ull   // 1,024       int[250]
#define WS_MODE    69304096ull   // 4           int
#define WS_WQA     70000000ull   // 262,144     float4[64*256]  (fallback LSTM)
#define WS_WQB     70262144ull   // 262,144     float4[64*256]  (fallback LSTM)
#define WS_AS      70600000ull   // 256         float[64]
#define WS_LOGIT2  70700000ull   // 256,000     float[NT]
// big-ws region: xC aliases xB + CSR (disjoint lifetimes: CSR/xB dead before
// gemm_proj writes xC; xB reused for la only after lstm consumed xC)
#define WS2_XC     33000000ull   // 131,072,000 float[NT*512]  gate preacts (x part)
#define WS2_BFRAG  164100000ull  // 131,072     ushort bf16 Whh B-fragments (LSTM)
#define WS2_GHI    164300000ull  // 311,296     ushort GEMM W fragments (hi)
#define WS2_GLO    164650000ull  // 311,296     ushort GEMM W fragments (lo)
#define WS2_B512   165000000ull  // 2,048       float[512]     bih+bhh
#define WS2_MODE   165010000ull  // 4
#define WS2_AS     165020000ull  // 256
#define WS2_LOGIT2 165100000ull  // 256,000
#define WS2_NEED   165360000ull
// GEMM fragment sub-offsets (ushort elements within GHI/GLO)
#define G_W1    0        // 64x128  -> 8192
#define G_WL    8192     // 4 x 128x128 -> 16384 each
#define G_PROJ  73728    // 128x512 -> 65536
#define G_W7    139264   // 128x128 -> 16384

typedef __attribute__((ext_vector_type(8))) short short8;   // 8 bf16 (4 VGPRs)
typedef __attribute__((ext_vector_type(4))) float f32x4;

// ---------------- helpers ----------------
__device__ __forceinline__ float rdlane(float v, int l) {
    return __int_as_float(__builtin_amdgcn_readlane(__float_as_int(v), l));
}
__device__ __forceinline__ float sigm(float x) { return 1.0f / (1.0f + __expf(-x)); }
__device__ __forceinline__ float tanh_f(float x) {
    x = fminf(fmaxf(x, -30.0f), 30.0f);
    float e = __expf(2.0f * x);
    return (e - 1.0f) / (e + 1.0f);
}
__device__ __forceinline__ float tanh2(float x) {   // 2*sigmoid(2x)-1, inf-safe
    return 2.0f / (1.0f + __expf(-2.0f * x)) - 1.0f;
}
__device__ __forceinline__ ushort f2bf(float x) {   // round-to-nearest-even bf16
    unsigned u = __float_as_uint(x);
    unsigned r = (u + 0x7FFFu + ((u >> 16) & 1u)) >> 16;
    return (ushort)r;
}
__device__ __forceinline__ float bf2f(ushort h) {
    return __uint_as_float(((unsigned)h) << 16);
}

// ---------------- reachable dtype detection ----------------
__global__ void detect_mode_k(const unsigned char* __restrict__ p, int* __restrict__ mode) {
    __shared__ int f0, f3;
    const int t = threadIdx.x;
    if (t == 0) { f0 = 0; f3 = 0; }
    __syncthreads();
    int l0 = 0, l3 = 0;
    for (int i = t; i < 16000; i += 256) {
        if (p[4 * i])     l0 = 1;
        if (p[4 * i + 3]) l3 = 1;
    }
    if (l0) atomicOr(&f0, 1);
    if (l3) atomicOr(&f3, 1);
    __syncthreads();
    if (t == 0) {
        int m;
        if (f0 && f3)      m = 1;  // bool bytes
        else if (f0)       m = 0;  // int32
        else               m = 2;  // float32
        *mode = m;
    }
}

// ---------------- CSR construction (dst-grouped src list; built once) ----------------
__global__ void zero_ints_k(int* __restrict__ p, int n) {
    int i = blockIdx.x * 256 + threadIdx.x;
    if (i < n) p[i] = 0;
}
__global__ void hist_k(const int* __restrict__ ei, int* __restrict__ deg) {
    int e = blockIdx.x * 256 + threadIdx.x;
    if (e < ET) {
        int d = (e < EG) ? ei[EG + e] : (e - EG);
        atomicAdd(deg + d, 1);
    }
}
__global__ void scan1_k(const int* __restrict__ deg, int* __restrict__ incl, int* __restrict__ bsum) {
    __shared__ int sh[256];
    const int t = threadIdx.x;
    const int i = blockIdx.x * 256 + t;
    sh[t] = deg[i];
    __syncthreads();
    for (int o = 1; o < 256; o <<= 1) {
        int add = (t >= o) ? sh[t - o] : 0;
        __syncthreads();
        sh[t] += add;
        __syncthreads();
    }
    incl[i] = sh[t];
    if (t == 255) bsum[blockIdx.x] = sh[255];
}
__global__ void scan2_k(const int* __restrict__ bsum, int* __restrict__ boff) {
    __shared__ int sh[256];
    const int t = threadIdx.x;
    int v = (t < 250) ? bsum[t] : 0;
    sh[t] = v;
    __syncthreads();
    for (int o = 1; o < 256; o <<= 1) {
        int add = (t >= o) ? sh[t - o] : 0;
        __syncthreads();
        sh[t] += add;
        __syncthreads();
    }
    if (t < 250) boff[t] = sh[t] - v;   // exclusive
}
__global__ void scan3_k(const int* __restrict__ incl, const int* __restrict__ boff,
                        int* __restrict__ rowptr, int* __restrict__ cursor_deg) {
    const int i = blockIdx.x * 256 + threadIdx.x;
    int total = incl[i] + boff[blockIdx.x];
    int excl  = total - cursor_deg[i];
    rowptr[i] = excl;
    cursor_deg[i] = excl;                 // becomes fill cursor
    if (i == NT - 1) rowptr[NT] = total;
}
__global__ void fill_k(const int* __restrict__ ei, int* __restrict__ cursor, int* __restrict__ srcs) {
    int e = blockIdx.x * 256 + threadIdx.x;
    if (e < ET) {
        int s_, d_;
        if (e < EG) { s_ = ei[e]; d_ = ei[EG + e]; }
        else        { s_ = e - EG; d_ = s_; }
        int p = atomicAdd(cursor + d_, 1);
        srcs[p] = s_;
    }
}

// ---------------- bf16 split-precision W fragments for MFMA GEMM ----------------
// B-frag convention (validated by lstm3): n = nt*16+(lane&15), k = kt*32+(lane>>4)*8+j.
// src element [k][n] at src[k*ks + n*ns].
__global__ void build_gfrag_k(const float* __restrict__ src, const int ks, const int ns,
                              const int K, ushort* __restrict__ dhi, ushort* __restrict__ dlo,
                              const int total) {
    int id = blockIdx.x * 256 + threadIdx.x;
    if (id < total) {
        int j = id & 7, lane = (id >> 3) & 63;
        int f = id >> 9;
        int KT = K >> 5;
        int nt = f / KT, kt = f - nt * KT;
        int n = nt * 16 + (lane & 15);
        int k = kt * 32 + ((lane >> 4) << 3) + j;
        float v = src[(size_t)k * ks + (size_t)n * ns];
        ushort h = f2bf(v);
        dhi[id] = h;
        dlo[id] = f2bf(v - bf2f(h));
    }
}
__global__ void bias512_k(const float* __restrict__ bih, const float* __restrict__ bhh,
                          float* __restrict__ b512) {
    int i = blockIdx.x * 256 + threadIdx.x;
    if (i < 512) b512[i] = bih[i] + bhh[i];
}

// ---------------- MFMA GEMM: out[M x N] = x[M x K] @ W + bias, split bf16 hi/lo ----------------
// K = KT*32. grid = (M/64, N/128). Per block: 64-row tile; wave w owns rows w*16..+15,
// iterates 8 n-tiles of its 128-col group. 3 MFMA per (q,kt): hh + lh + hl (lo*lo dropped,
// rel err ~2^-18).
template <int KT>
__global__ __launch_bounds__(256) void gemm_mf(
    const float* __restrict__ x, const ushort* __restrict__ bhi,
    const ushort* __restrict__ blo, const float* __restrict__ bias,
    float* __restrict__ out, const int ldout)
{
    constexpr int K = KT * 32;
    __shared__ __align__(16) ushort ahi_s[64 * 136];
    __shared__ __align__(16) ushort alo_s[64 * 136];
    const int t = threadIdx.x;
    const int w = t >> 6, lane = t & 63;
    const int quad = lane >> 4, col = lane & 15;
    const int row0 = blockIdx.x * 64;
    const int col0 = blockIdx.y * 128;

    // stage x tile -> bf16 hi/lo in LDS
    {
        const int r  = t >> 2;
        const int kc = (t & 3) * (K / 4);
        const float* xr = x + (size_t)(row0 + r) * K + kc;
        ushort* dh = ahi_s + r * 136 + kc;
        ushort* dl = alo_s + r * 136 + kc;
#pragma unroll
        for (int k = 0; k < K / 4; k += 4) {
            float4 v = *(const float4*)(xr + k);
            ushort h0_ = f2bf(v.x), h1_ = f2bf(v.y), h2_ = f2bf(v.z), h3_ = f2bf(v.w);
            ushort l0_ = f2bf(v.x - bf2f(h0_)), l1_ = f2bf(v.y - bf2f(h1_));
            ushort l2_ = f2bf(v.z - bf2f(h2_)), l3_ = f2bf(v.w - bf2f(h3_));
            *(uint2*)(dh + k) = make_uint2((uint)h0_ | ((uint)h1_ << 16),
                                           (uint)h2_ | ((uint)h3_ << 16));
            *(uint2*)(dl + k) = make_uint2((uint)l0_ | ((uint)l1_ << 16),
                                           (uint)l2_ | ((uint)l3_ << 16));
        }
    }
    __syncthreads();

    // A fragments for this wave's 16 rows
    short8 ah[KT], al[KT];
#pragma unroll
    for (int kt = 0; kt < KT; kt++) {
        const int off = (w * 16 + col) * 136 + kt * 32 + quad * 8;
        ah[kt] = *(const short8*)(ahi_s + off);
        al[kt] = *(const short8*)(alo_s + off);
    }

    f32x4 acc[8];
#pragma unroll
    for (int q = 0; q < 8; q++) acc[q] = (f32x4){0.f, 0.f, 0.f, 0.f};

#pragma unroll
    for (int q = 0; q < 8; q++) {
#pragma unroll
        for (int kt = 0; kt < KT; kt++) {
            const int f = ((((col0 >> 4) + q) * KT + kt) * 64 + lane) * 8;
            short8 bh = *(const short8*)(bhi + f);
            short8 bl = *(const short8*)(blo + f);
            acc[q] = __builtin_amdgcn_mfma_f32_16x16x32_bf16(ah[kt], bh, acc[q], 0, 0, 0);
            acc[q] = __builtin_amdgcn_mfma_f32_16x16x32_bf16(al[kt], bh, acc[q], 0, 0, 0);
            acc[q] = __builtin_amdgcn_mfma_f32_16x16x32_bf16(ah[kt], bl, acc[q], 0, 0, 0);
        }
    }

    // epilogue: D col=lane&15 (n), row=(lane>>4)*4+reg (m)
#pragma unroll
    for (int q = 0; q < 8; q++) {
        float bv = bias[col0 + q * 16 + col];
#pragma unroll
        for (int r = 0; r < 4; r++) {
            out[(size_t)(row0 + w * 16 + quad * 4 + r) * ldout + col0 + q * 16 + col]
                = acc[q][r] + bv;
        }
    }
}

// ---------------- fp32 GEMM (fallback path only) ----------------
template <int K>
__global__ __launch_bounds__(256) void gemm3(
    const float* __restrict__ x, const float* __restrict__ W,
    const float* __restrict__ b, float* __restrict__ out)
{
    __shared__ float Wsh[64 * 128];
    __shared__ float xT[64][132];
    const int t = threadIdx.x;
    const int row0 = blockIdx.x * 128;
    const int cg = t & 15;
    const int rg = t >> 4;
    float4 acc[8][2];
#pragma unroll
    for (int r = 0; r < 8; r++) {
        acc[r][0] = make_float4(0.f, 0.f, 0.f, 0.f);
        acc[r][1] = make_float4(0.f, 0.f, 0.f, 0.f);
    }
    for (int k0 = 0; k0 < K; k0 += 64) {
        for (int i = t * 4; i < 64 * 128; i += 1024)
            *(float4*)(Wsh + i) = *(const float4*)(W + (size_t)k0 * 128 + i);
        for (int i = t * 4; i < 128 * 64; i += 1024) {
            int r = i >> 6, k = i & 63;
            float4 v = *(const float4*)(x + (size_t)(row0 + r) * K + k0 + k);
            xT[k + 0][r] = v.x; xT[k + 1][r] = v.y;
            xT[k + 2][r] = v.z; xT[k + 3][r] = v.w;
        }
        __syncthreads();
#pragma unroll 2
        for (int k = 0; k < 64; k++) {
            float4 w0 = *(const float4*)(Wsh + k * 128 + cg * 8);
            float4 w1 = *(const float4*)(Wsh + k * 128 + cg * 8 + 4);
            float4 x0 = *(const float4*)(&xT[k][rg * 8]);
            float4 x1 = *(const float4*)(&xT[k][rg * 8 + 4]);
            float xv[8] = {x0.x, x0.y, x0.z, x0.w, x1.x, x1.y, x1.z, x1.w};
#pragma unroll
            for (int r = 0; r < 8; r++) {
                acc[r][0].x += xv[r] * w0.x; acc[r][0].y += xv[r] * w0.y;
                acc[r][0].z += xv[r] * w0.z; acc[r][0].w += xv[r] * w0.w;
                acc[r][1].x += xv[r] * w1.x; acc[r][1].y += xv[r] * w1.y;
                acc[r][1].z += xv[r] * w1.z; acc[r][1].w += xv[r] * w1.w;
            }
        }
        __syncthreads();
    }
    float4 bv0 = *(const float4*)(b + cg * 8);
    float4 bv1 = *(const float4*)(b + cg * 8 + 4);
#pragma unroll
    for (int r = 0; r < 8; r++) {
        float4 o0, o1;
        o0.x = acc[r][0].x + bv0.x; o0.y = acc[r][0].y + bv0.y;
        o0.z = acc[r][0].z + bv0.z; o0.w = acc[r][0].w + bv0.w;
        o1.x = acc[r][1].x + bv1.x; o1.y = acc[r][1].y + bv1.y;
        o1.z = acc[r][1].z + bv1.z; o1.w = acc[r][1].w + bv1.w;
        float* op = out + (size_t)(row0 + rg * 8 + r) * 128 + cg * 8;
        *(float4*)(op) = o0;
        *(float4*)(op + 4) = o1;
    }
}

// ---------------- fused GATv2: logits + online softmax + aggregate ----------------
// XCD-aware swizzle: graph s handled by blocks with blockIdx%8==s%8 for L2 residency.
__global__ __launch_bounds__(256) void gat_fused_k(
    const float* __restrict__ xl, const int* __restrict__ rowptr,
    const int* __restrict__ srcs, const float* __restrict__ att,
    const float* __restrict__ bias, float* __restrict__ out, const int do_relu)
{
    const int lane = threadIdx.x & 63;
    const int b = blockIdx.x;
    const int g = b & 7;
    const int j = b >> 3;
    const int jq = j / 250;
    const int jj = j - jq * 250;
    const int s = g + 8 * jq;
    const int n = s * NN + jj * 4 + (threadIdx.x >> 6);

    const float2 a = *(const float2*)(att + lane * 2);
    const float2 xd = *(const float2*)(xl + (size_t)n * 128 + lane * 2);
    const int i0 = rowptr[n], i1 = rowptr[n + 1];

    float m = -1e30f, den = 0.f, ax = 0.f, ay = 0.f;
    int sv = srcs[i0];
    for (int i = i0; i < i1; i++) {
        int snx = (i + 1 < i1) ? srcs[i + 1] : 0;
        const float2 xs = *(const float2*)(xl + (size_t)sv * 128 + lane * 2);
        float u = xs.x + xd.x, v = xs.y + xd.y;
        u = (u > 0.f) ? u : 0.2f * u;
        v = (v > 0.f) ? v : 0.2f * v;
        float p = u * a.x + v * a.y;
        p += __shfl_xor(p, 1, 32);
        p += __shfl_xor(p, 2, 32);
        p += __shfl_xor(p, 4, 32);
        p += __shfl_xor(p, 8, 32);
        p += __shfl_xor(p, 16, 32);
        float mn = fmaxf(m, p);
        float sc = __expf(m - mn);
        float wgt = __expf(p - mn);
        den = den * sc + wgt;
        ax = ax * sc + wgt * xs.x;
        ay = ay * sc + wgt * xs.y;
        m = mn;
        sv = snx;
    }
    float2 bv = *(const float2*)(bias + lane * 2);
    float inv = 1.f / den;
    float ox = ax * inv + bv.x, oy = ay * inv + bv.y;
    if (do_relu) { ox = fmaxf(ox, 0.f); oy = fmaxf(oy, 0.f); }
    *(float2*)(out + (size_t)n * 128 + lane * 2) = make_float2(ox, oy);
}

// ---------------- LSTM weight packing (fallback path) ----------------
__global__ void build_wq_k(const float* __restrict__ Wih, const float* __restrict__ Whh,
                           float4* __restrict__ WQa, float4* __restrict__ WQb) {
    int id = blockIdx.x * 256 + threadIdx.x;
    if (id < 64 * 256) {
        int kp = id >> 8, t = id & 255;
        int j1 = t, j2 = t + 256;
        WQa[id] = make_float4(Wih[(size_t)j1 * 128 + 2 * kp], Whh[(size_t)j1 * 128 + 2 * kp],
                              Wih[(size_t)j1 * 128 + 2 * kp + 1], Whh[(size_t)j1 * 128 + 2 * kp + 1]);
        WQb[id] = make_float4(Wih[(size_t)j2 * 128 + 2 * kp], Whh[(size_t)j2 * 128 + 2 * kp],
                              Wih[(size_t)j2 * 128 + 2 * kp + 1], Whh[(size_t)j2 * 128 + 2 * kp + 1]);
    }
}

// ---------------- bf16 B-fragment pack of Whh (LSTM MFMA) ----------------
__global__ void build_bfrag_k(const float* __restrict__ Whh, ushort* __restrict__ Bfrag) {
    int id = blockIdx.x * 256 + threadIdx.x;    // 65536 ids
    if (id < 65536) {
        int j = id & 7, lane = (id >> 3) & 63, kt = (id >> 9) & 3, tile = id >> 11;
        int gate = tile * 16 + (lane & 15);
        int k = kt * 32 + ((lane >> 4) << 3) + j;
        Bfrag[id] = f2bf(Whh[(size_t)gate * 128 + k]);
    }
}

// ---- fallback LSTM (round-3, small-ws only) ----
#define LSTM_GROUP(buf, gbase)                                                     \
    _Pragma("unroll")                                                              \
    for (int i_ = 0; i_ < 4; i_++) {                                               \
        const int kp_ = (gbase) * 4 + i_;                                          \
        const float4 qa_ = buf[i_];                                                \
        const float4 qb_ = buf[4 + i_];                                            \
        _Pragma("unroll")                                                          \
        for (int n_ = 0; n_ < 4; n_++) {                                           \
            const float sx0_ = rdlane(xr[n_].x, kp_);                              \
            const float sh0_ = rdlane(hr[n_].x, kp_);                              \
            const float sx1_ = rdlane(xr[n_].y, kp_);                              \
            const float sh1_ = rdlane(hr[n_].y, kp_);                              \
            acc1[n_] += sx0_ * qa_.x + sh0_ * qa_.y + sx1_ * qa_.z + sh1_ * qa_.w; \
            acc2[n_] += sx0_ * qb_.x + sh0_ * qb_.y + sx1_ * qb_.z + sh1_ * qb_.w; \
        }                                                                          \
    }

__global__ __launch_bounds__(256, 1) void lstm_k(
    float* __restrict__ mu, const float4* __restrict__ WQa, const float4* __restrict__ WQb,
    const float* __restrict__ bih, const float* __restrict__ bhh,
    const float* __restrict__ h0, const float* __restrict__ c0,
    float* __restrict__ hT, float* __restrict__ cT)
{
    const int t = threadIdx.x, lane = t & 63;
    const int n0 = blockIdx.x * 4;
    __shared__ float hsh[4][128];
    __shared__ float gsh[4][512];
    const float b1 = bih[t] + bhh[t];
    const float b2 = bih[t + 256] + bhh[t + 256];
    float creg[2];
#pragma unroll
    for (int q = 0; q < 2; q++) {
        int id = t + 256 * q;
        creg[q] = c0[(size_t)(n0 + (id >> 7)) * 128 + (id & 127)];
    }
    for (int i = t; i < 512; i += 256)
        hsh[i >> 7][i & 127] = h0[(size_t)(n0 + (i >> 7)) * 128 + (i & 127)];

    const float4* pA = WQa + t;
    const float4* pB = WQb + t;

    float2 xr[4], xnx[4];
#pragma unroll
    for (int n = 0; n < 4; n++)
        xr[n] = *(const float2*)(mu + (size_t)n0 * 128 + n * 128 + lane * 2);
    __syncthreads();

    for (int s = 0; s < SQ; s++) {
        float* xrow = mu + ((size_t)s * NN + n0) * 128;
        float2 hr[4];
#pragma unroll
        for (int n = 0; n < 4; n++) hr[n] = *(const float2*)(&hsh[n][lane * 2]);

        float4 bufA[8], bufB[8];
#pragma unroll
        for (int i = 0; i < 4; i++) { bufA[i] = pA[i * 256]; bufA[4 + i] = pB[i * 256]; }

        if (s + 1 < SQ) {
            const float* xrow2 = mu + ((size_t)(s + 1) * NN + n0) * 128;
#pragma unroll
            for (int n = 0; n < 4; n++) xnx[n] = *(const float2*)(xrow2 + n * 128 + lane * 2);
        }

        float acc1[4], acc2[4];
#pragma unroll
        for (int n = 0; n < 4; n++) { acc1[n] = b1; acc2[n] = b2; }

        for (int g = 0; g < 16; g += 2) {
#pragma unroll
            for (int i = 0; i < 4; i++) {
                bufB[i]     = pA[((g + 1) * 4 + i) * 256];
                bufB[4 + i] = pB[((g + 1) * 4 + i) * 256];
            }
            LSTM_GROUP(bufA, g)
            if (g < 14) {
#pragma unroll
                for (int i = 0; i < 4; i++) {
                    bufA[i]     = pA[((g + 2) * 4 + i) * 256];
                    bufA[4 + i] = pB[((g + 2) * 4 + i) * 256];
                }
            }
            LSTM_GROUP(bufB, g + 1)
        }

#pragma unroll
        for (int n = 0; n < 4; n++) { gsh[n][t] = acc1[n]; gsh[n][t + 256] = acc2[n]; }
        __syncthreads();
#pragma unroll
        for (int q = 0; q < 2; q++) {
            int id = t + 256 * q;
            int n = id >> 7, e = id & 127;
            float iv = gsh[n][e], fv = gsh[n][128 + e];
            float gv = gsh[n][256 + e], ov = gsh[n][384 + e];
            float c = sigm(fv) * creg[q] + sigm(iv) * tanh_f(gv);
            float h = sigm(ov) * tanh_f(c);
            creg[q] = c;
            hsh[n][e] = h;
            xrow[n * 128 + e] = h;
            if (s == SQ - 1) {
                hT[(size_t)(n0 + n) * 128 + e] = h;
                cT[(size_t)(n0 + n) * 128 + e] = c;
            }
        }
#pragma unroll
        for (int n = 0; n < 4; n++) xr[n] = xnx[n];
        __syncthreads();
    }
}

// ---------------- MFMA LSTM v2 (big-ws path) ----------------
// 125 blocks x 8 nodes (2x CU coverage vs r6). Whh bf16 B-frags in registers.
// Ping-pong LDS h buffers -> ONE barrier/step (no WAR hazard: epilogue writes
// the other buffer). xC for step s+1 prefetched during step s (full-step cover).
// MFMA rows 8..15 are zeros (discarded outputs) — epilogue/xC cost halves/block.
__global__ __launch_bounds__(256, 1) void lstm3_k(
    float* __restrict__ mu, const float* __restrict__ xC,
    const ushort* __restrict__ Bfrag,
    const float* __restrict__ h0, const float* __restrict__ c0,
    float* __restrict__ hT, float* __restrict__ cT)
{
    const int t = threadIdx.x;
    const int w = t >> 6, lane = t & 63;
    const int quad = lane >> 4, col = lane & 15;
    const int n0 = blockIdx.x * 8;

    __shared__ __align__(16) ushort hbuf[2][2][16 * 136];   // [pingpong][hi/lo]

    // B fragments -> registers (constant all 64 steps)
    short8 bf[8][4];
#pragma unroll
    for (int q = 0; q < 8; q++)
#pragma unroll
        for (int kt = 0; kt < 4; kt++) {
            int tile = q * 4 + w;
            bf[q][kt] = *(const short8*)(Bfrag + (((tile * 4 + kt) * 64 + lane) << 3));
        }

    // init h into both buffers (rows 8..15 = 0 forever), c into regs
    for (int i = t; i < 2048; i += 256) {
        int node = i >> 7, e = i & 127;
        float v = (node < 8) ? h0[(size_t)(n0 + node) * 128 + e] : 0.f;
        ushort hh = f2bf(v), hl = f2bf(v - bf2f(hh));
        hbuf[0][0][node * 136 + e] = hh; hbuf[0][1][node * 136 + e] = hl;
        hbuf[1][0][node * 136 + e] = hh; hbuf[1][1][node * 136 + e] = hl;
    }
    float cst[8];
#pragma unroll
    for (int q = 0; q < 2; q++)
#pragma unroll
        for (int r = 0; r < 4; r++) {
            int node = quad * 4 + r;
            cst[q * 4 + r] = (quad < 2)
                ? c0[(size_t)(n0 + node) * 128 + (q * 64 + w * 16 + col)] : 0.f;
        }

    // preload step-0 xC
    float xcr[8][4], xcn[8][4];
#pragma unroll
    for (int q = 0; q < 8; q++)
#pragma unroll
        for (int r = 0; r < 4; r++) {
            int node = quad * 4 + r;
            xcr[q][r] = (quad < 2)
                ? xC[(size_t)(n0 + node) * 512 + (q * 64 + w * 16 + col)] : 0.f;
        }
    __syncthreads();

    int p = 0;
    for (int s = 0; s < SQ; s++) {
        // prefetch next step's xC (consumed next iteration, after this step's barrier)
        if (s + 1 < SQ) {
            const float* xn = xC + (size_t)(s + 1) * (NN * 512);
#pragma unroll
            for (int q = 0; q < 8; q++)
#pragma unroll
                for (int r = 0; r < 4; r++) {
                    int node = quad * 4 + r;
                    xcn[q][r] = (quad < 2)
                        ? xn[(size_t)(n0 + node) * 512 + (q * 64 + w * 16 + col)] : 0.f;
                }
        }

        // A fragments from current buffer
        short8 ahi[4], alo[4];
#pragma unroll
        for (int kt = 0; kt < 4; kt++) {
            ahi[kt] = *(const short8*)(&hbuf[p][0][col * 136 + kt * 32 + quad * 8]);
            alo[kt] = *(const short8*)(&hbuf[p][1][col * 136 + kt * 32 + quad * 8]);
        }

        f32x4 acc[8];
#pragma unroll
        for (int q = 0; q < 8; q++) acc[q] = (f32x4){0.f, 0.f, 0.f, 0.f};
#pragma unroll
        for (int kt = 0; kt < 4; kt++) {
#pragma unroll
            for (int q = 0; q < 8; q++) {
                acc[q] = __builtin_amdgcn_mfma_f32_16x16x32_bf16(ahi[kt], bf[q][kt], acc[q], 0, 0, 0);
                acc[q] = __builtin_amdgcn_mfma_f32_16x16x32_bf16(alo[kt], bf[q][kt], acc[q], 0, 0, 0);
            }
        }

        // epilogue -> other buffer (no barrier needed before: different buffer)
        float* mus = mu + (size_t)s * (NN * 128);
        const int pn = p ^ 1;
#pragma unroll
        for (int q = 0; q < 2; q++)
#pragma unroll
            for (int r = 0; r < 4; r++) {
                float iv = acc[q][r]     + xcr[q][r];
                float fv = acc[q + 2][r] + xcr[q + 2][r];
                float gv = acc[q + 4][r] + xcr[q + 4][r];
                float ov = acc[q + 6][r] + xcr[q + 6][r];
                float c = sigm(fv) * cst[q * 4 + r] + sigm(iv) * tanh2(gv);
                float h = sigm(ov) * tanh2(c);
                cst[q * 4 + r] = c;
                if (quad < 2) {
                    int node = quad * 4 + r;
                    int e = q * 64 + w * 16 + col;
                    ushort hh = f2bf(h);
                    hbuf[pn][0][node * 136 + e] = hh;
                    hbuf[pn][1][node * 136 + e] = f2bf(h - bf2f(hh));
                    mus[(size_t)(n0 + node) * 128 + e] = h;
                    if (s == SQ - 1) {
                        hT[(size_t)(n0 + node) * 128 + e] = h;
                        cT[(size_t)(n0 + node) * 128 + e] = c;
                    }
                }
            }
#pragma unroll
        for (int q = 0; q < 8; q++)
#pragma unroll
            for (int r = 0; r < 4; r++) xcr[q][r] = xcn[q][r];
        p = pn;
        __syncthreads();
    }
}

// ---------------- head: meanpool -> gs -> A[s] = sum_j relu(gs)*w5[j] ----------------
__global__ __launch_bounds__(256) void meanpool_gs_k(
    const float* __restrict__ mu, const float* __restrict__ W6,
    const float* __restrict__ b6, const float* __restrict__ w5,
    float* __restrict__ A)
{
    const int s = blockIdx.x, t = threadIdx.x;
    const int ch = t & 127, half = t >> 7;
    __shared__ float mp[128];
    __shared__ float red[256];
    float acc = 0.f;
    for (int n = half * 500; n < (half + 1) * 500; n++)
        acc += mu[((size_t)s * NN + n) * 128 + ch];
    red[t] = acc;
    __syncthreads();
    if (t < 128) mp[t] = (red[t] + red[t + 128]) * 0.001f;
    __syncthreads();
    float g = 0.f;
    if (t < 128) {
        g = b6[t];
        for (int k = 0; k < 128; k++) g += mp[k] * W6[(size_t)k * 128 + t];
        g = fmaxf(g, 0.f) * w5[t];
    }
    red[t] = g;
    __syncthreads();
    for (int o = 128; o > 0; o >>= 1) {
        if (t < o) red[t] += red[t + o];
        __syncthreads();
    }
    if (t == 0) A[s] = red[0];
}

// ---------------- head: logit2[row] ----------------
__global__ __launch_bounds__(256) void rowdot_k(
    const float* __restrict__ la, const float* __restrict__ w5,
    const float* __restrict__ b5, const float* __restrict__ A,
    float* __restrict__ out)
{
    const int lane = threadIdx.x & 63;
    const int row = blockIdx.x * 4 + (threadIdx.x >> 6);
    float2 v = *(const float2*)(la + (size_t)row * 128 + lane * 2);
    float2 w = *(const float2*)(w5 + 128 + lane * 2);
    float x = fmaxf(v.x, 0.f) * w.x + fmaxf(v.y, 0.f) * w.y;
#pragma unroll
    for (int o = 32; o; o >>= 1) x += __shfl_down(x, o);
    if (lane == 0) out[row] = x + A[row / NN] + b5[0];
}

// ---------------- masked softmax per sequence step ----------------
__device__ __forceinline__ bool reach_at(const void* reach, int mode, int idx) {
    if (mode == 0) return ((const int*)reach)[idx] != 0;
    if (mode == 1) return ((const unsigned char*)reach)[idx] != 0;
    return ((const float*)reach)[idx] != 0.f;
}
__global__ __launch_bounds__(256) void softmax_k(
    const float* __restrict__ lg, const void* __restrict__ reach,
    const int* __restrict__ mode, float* __restrict__ prob)
{
    const int s = blockIdx.x, t = threadIdx.x;
    const int m = *mode;
    __shared__ float red[256];
    float mx = -1e30f;
    for (int i = t; i < NN; i += 256) {
        int idx = s * NN + i;
        if (reach_at(reach, m, idx)) mx = fmaxf(mx, lg[idx]);
    }
    red[t] = mx;
    __syncthreads();
    for (int o = 128; o; o >>= 1) {
        if (t < o) red[t] = fmaxf(red[t], red[t + o]);
        __syncthreads();
    }
    mx = red[0];
    __syncthreads();
    float sum = 0.f;
    for (int i = t; i < NN; i += 256) {
        int idx = s * NN + i;
        float v = reach_at(reach, m, idx) ? __expf(lg[idx] - mx) : 0.f;
        prob[idx] = v;
        sum += v;
    }
    red[t] = sum;
    __syncthreads();
    for (int o = 128; o; o >>= 1) {
        if (t < o) red[t] += red[t + o];
        __syncthreads();
    }
    float inv = 1.f / red[0];
    for (int i = t; i < NN; i += 256) prob[s * NN + i] *= inv;
}

// ---------------- driver ----------------
extern "C" void kernel_launch(void* const* d_in, const int* in_sizes, int n_in,
                              void* d_out, int out_size, void* d_ws, size_t ws_size,
                              hipStream_t stream) {
    const float* nfm   = (const float*)d_in[0];
    const int*   ei    = (const int*)d_in[1];
    const void*  reach = d_in[2];
    const float* h0    = (const float*)d_in[3];
    const float* c0    = (const float*)d_in[4];
    const float* W1    = (const float*)d_in[5];
    const float* b1    = (const float*)d_in[6];
    const float* att1  = (const float*)d_in[7];
    const float* bias1 = (const float*)d_in[8];
    const float* Wl    = (const float*)d_in[9];
    const float* bl    = (const float*)d_in[10];
    const float* attl  = (const float*)d_in[11];
    const float* biasl = (const float*)d_in[12];
    const float* Wih   = (const float*)d_in[13];
    const float* Whh   = (const float*)d_in[14];
    const float* bih   = (const float*)d_in[15];
    const float* bhh   = (const float*)d_in[16];
    const float* W6    = (const float*)d_in[17];
    const float* b6    = (const float*)d_in[18];
    const float* W7    = (const float*)d_in[19];
    const float* b7    = (const float*)d_in[20];
    const float* w5    = (const float*)d_in[21];
    const float* b5    = (const float*)d_in[22];

    char* ws = (char*)d_ws;
    const bool bigws = (ws_size >= WS2_NEED);

    float*  xA     = (float*)(ws + WS_XA);
    float*  xB     = (float*)(ws + WS_XB);
    int*    rowptr = (int*)(ws + WS_ROWPTR);
    int*    cursor = (int*)(ws + WS_CURSOR);
    int*    srcs   = (int*)(ws + WS_SRCS);
    int*    incl   = (int*)(ws + WS_INCL);
    int*    bsum   = (int*)(ws + WS_BSUM);
    int*    boff   = (int*)(ws + WS_BOFF);
    int*    modep  = bigws ? (int*)(ws + WS2_MODE)     : (int*)(ws + WS_MODE);
    float*  As     = bigws ? (float*)(ws + WS2_AS)     : (float*)(ws + WS_AS);
    float*  logit2 = bigws ? (float*)(ws + WS2_LOGIT2) : (float*)(ws + WS_LOGIT2);
    // big-ws extras
    float*  xC     = (float*)(ws + WS2_XC);
    ushort* Bfrag  = (ushort*)(ws + WS2_BFRAG);
    ushort* ghi    = (ushort*)(ws + WS2_GHI);
    ushort* glo    = (ushort*)(ws + WS2_GLO);
    float*  b512   = (float*)(ws + WS2_B512);
    // fallback extras
    float4* WQa    = (float4*)(ws + WS_WQA);
    float4* WQb    = (float4*)(ws + WS_WQB);

    float* prob = (float*)d_out;
    float* hT   = (float*)d_out + 64000;
    float* cT   = (float*)d_out + 192000;

    // setup
    detect_mode_k<<<1, 256, 0, stream>>>((const unsigned char*)reach, modep);
    zero_ints_k<<<250, 256, 0, stream>>>(cursor, NT);
    hist_k<<<2250, 256, 0, stream>>>(ei, cursor);
    scan1_k<<<250, 256, 0, stream>>>(cursor, incl, bsum);
    scan2_k<<<1, 256, 0, stream>>>(bsum, boff);
    scan3_k<<<250, 256, 0, stream>>>(incl, boff, rowptr, cursor);
    fill_k<<<2250, 256, 0, stream>>>(ei, cursor, srcs);
    if (bigws) {
        build_bfrag_k<<<256, 256, 0, stream>>>(Whh, Bfrag);
        bias512_k<<<2, 256, 0, stream>>>(bih, bhh, b512);
        build_gfrag_k<<<32, 256, 0, stream>>>(W1, 128, 1, 64, ghi + G_W1, glo + G_W1, 8192);
        for (int i = 0; i < 4; i++)
            build_gfrag_k<<<64, 256, 0, stream>>>(Wl + (size_t)i * 16384, 128, 1, 128,
                                                  ghi + G_WL + i * 16384, glo + G_WL + i * 16384, 16384);
        build_gfrag_k<<<256, 256, 0, stream>>>(Wih, 1, 128, 128, ghi + G_PROJ, glo + G_PROJ, 65536);
        build_gfrag_k<<<64, 256, 0, stream>>>(W7, 128, 1, 128, ghi + G_W7, glo + G_W7, 16384);
    } else {
        build_wq_k<<<64, 256, 0, stream>>>(Wih, Whh, WQa, WQb);
    }

    // 5 GATv2 layers: gemm (x->xB), fused logits+softmax+aggregate (xB->xA)
    for (int l = 0; l < 5; l++) {
        if (bigws) {
            if (l == 0)
                gemm_mf<2><<<dim3(1000, 1), 256, 0, stream>>>(nfm, ghi + G_W1, glo + G_W1, b1, xB, 128);
            else
                gemm_mf<4><<<dim3(1000, 1), 256, 0, stream>>>(xA, ghi + G_WL + (l - 1) * 16384,
                                                              glo + G_WL + (l - 1) * 16384,
                                                              bl + (l - 1) * 128, xB, 128);
        } else {
            if (l == 0)
                gemm3<64><<<500, 256, 0, stream>>>(nfm, W1, b1, xB);
            else
                gemm3<128><<<500, 256, 0, stream>>>(xA, Wl + (size_t)(l - 1) * 128 * 128,
                                                    bl + (l - 1) * 128, xB);
        }
        const float* att  = (l == 0) ? att1  : attl  + (l - 1) * 128;
        const float* bias = (l == 0) ? bias1 : biasl + (l - 1) * 128;
        gat_fused_k<<<16000, 256, 0, stream>>>(xB, rowptr, srcs, att, bias, xA,
                                               (l < 4) ? 1 : 0);
    }

    // LSTM
    if (bigws) {
        gemm_mf<4><<<dim3(1000, 4), 256, 0, stream>>>(xA, ghi + G_PROJ, glo + G_PROJ, b512, xC, 512);
        lstm3_k<<<125, 256, 0, stream>>>(xA, xC, Bfrag, h0, c0, hT, cT);
    } else {
        lstm_k<<<250, 256, 0, stream>>>(xA, WQa, WQb, bih, bhh, h0, c0, hT, cT);
    }

    // head
    meanpool_gs_k<<<64, 256, 0, stream>>>(xA, W6, b6, w5, As);
    if (bigws)
        gemm_mf<4><<<dim3(1000, 1), 256, 0, stream>>>(xA, ghi + G_W7, glo + G_W7, b7, xB, 128);
    else
        gemm3<128><<<500, 256, 0, stream>>>(xA, W7, b7, xB);
    rowdot_k<<<16000, 256, 0, stream>>>(xB, w5, b5, As, logit2);
    softmax_k<<<64, 256, 0, stream>>>(logit2, reach, modep, prob);
}